// Round 5
// baseline (1819.420 us; speedup 1.0000x reference)
//
#include <hip/hip_runtime.h>
#include <hip/hip_bf16.h>

constexpr int BB = 4, HH = 64, WW = 64, DMv = 96;
constexpr int DSn = 16, DIv = 192, DTRv = 6, KKv = 4, HIDv = 768;
constexpr int LL = 4096;
constexpr int NC = 32, CHK = LL / NC;       // 32 chunks of 128
constexpr int NDB = DIv / 16;               // 12 d-blocks of 16 channels

constexpr size_t S_xi   = (size_t)BB * LL * DIv;          // 3,145,728
constexpr size_t S_xdbl = (size_t)BB * KKv * LL * 38;     // 2,490,368
constexpr size_t S_big  = (size_t)BB * KKv * LL * DIv;    // 12,582,912
constexpr size_t S_sp   = (size_t)BB * KKv * NC * DIv * DSn;  // 1,572,864 (= S_xi/2)

__device__ __forceinline__ float sigf(float x) { return 1.f / (1.f + expf(-x)); }
__device__ __forceinline__ float dot4(float4 a, float4 b) {
  return a.x * b.x + a.y * b.y + a.z * b.z + a.w * b.w;
}

__device__ __forceinline__ int lmap(int k, int l) {
  int lr = (k & 2) ? (LL - 1 - l) : l;
  return (k & 1) ? (((lr & 63) << 6) | (lr >> 6)) : lr;
}

// K1: xz = x @ in_proj_w.T ; 4 rows/block, float4 K-loop (K=96 -> 24 f4).
__global__ void k_inproj(const float* __restrict__ x, const float* __restrict__ w,
                         float* __restrict__ xi, float* __restrict__ z) {
  int tile = blockIdx.x;  // 4096 blocks, 4 rows each
  int t = threadIdx.x;    // 256
  __shared__ float4 xr[4 * 24];
  const float4* x4 = (const float4*)x;
  for (int i = t; i < 4 * 24; i += 256) xr[i] = x4[(size_t)tile * 4 * 24 + i];
  __syncthreads();
  int row = t >> 6;        // wave = one row -> broadcast LDS reads
  int lane = t & 63;
  const float4* w4 = (const float4*)w;
  float acc[6] = {0.f, 0.f, 0.f, 0.f, 0.f, 0.f};
  for (int dq = 0; dq < 24; ++dq) {
    float4 yv = xr[row * 24 + dq];
#pragma unroll
    for (int cc = 0; cc < 6; ++cc) {
      float4 wv = w4[(size_t)(lane + cc * 64) * 24 + dq];
      acc[cc] += dot4(wv, yv);
    }
  }
  size_t bl = (size_t)tile * 4 + row;
#pragma unroll
  for (int cc = 0; cc < 6; ++cc) {
    int co = lane + cc * 64;
    if (co < DIv) xi[bl * DIv + co] = acc[cc];
    else          z[bl * DIv + (co - DIv)] = acc[cc];
  }
}

// K2: xc = silu(dwconv3x3(xi) + conv_b), channel-last
__global__ void k_dwconv(const float* __restrict__ xi, const float* __restrict__ cw,
                         const float* __restrict__ cb, float* __restrict__ xc) {
  size_t idx = (size_t)blockIdx.x * 256 + threadIdx.x;  // B*L*DI
  int d = (int)(idx % DIv);
  int l = (int)((idx / DIv) % LL);
  int b = (int)(idx / ((size_t)DIv * LL));
  int i = l >> 6, j = l & 63;
  float s = cb[d];
#pragma unroll
  for (int di = 0; di < 3; ++di) {
    int ii = i + di - 1;
    if ((unsigned)ii >= (unsigned)HH) continue;
#pragma unroll
    for (int dj = 0; dj < 3; ++dj) {
      int jj = j + dj - 1;
      if ((unsigned)jj >= (unsigned)WW) continue;
      s += xi[((size_t)b * LL + ii * WW + jj) * DIv + d] * cw[d * 9 + di * 3 + dj];
    }
  }
  xc[idx] = s * sigf(s);
}

// K3a: x_dbl[b,k,l,c] = sum_d xs[b,k,d,l] * x_proj_w[k,c,d]
__global__ void k_xdbl(const float* __restrict__ xc, const float* __restrict__ xpw,
                       float* __restrict__ xdbl) {
  int l = blockIdx.x, k = blockIdx.y, b = blockIdx.z;
  int t = threadIdx.x;  // 64
  __shared__ float4 col[48];
  int lc = lmap(k, l);
  const float4* xc4 = (const float4*)(xc + ((size_t)b * LL + lc) * DIv);
  if (t < 48) col[t] = xc4[t];
  __syncthreads();
  const float4* xpw4 = (const float4*)xpw;
  for (int c = t; c < 38; c += 64) {
    const float4* wr = xpw4 + ((size_t)k * 38 + c) * 48;
    float s = 0.f;
    for (int dq = 0; dq < 48; ++dq) s += dot4(col[dq], wr[dq]);
    xdbl[((size_t)(b * KKv + k) * LL + l) * 38 + c] = s;
  }
}

// K3b: delta[b,k,l,d] = softplus(dts @ dt_projs_w + dt_projs_b)
__global__ void k_delta(const float* __restrict__ xdbl, const float* __restrict__ dtw,
                        const float* __restrict__ dtb, float* __restrict__ delta) {
  size_t idx = (size_t)blockIdx.x * 256 + threadIdx.x;  // B*K*L*DI
  int d = (int)(idx % DIv);
  size_t bkl = idx / DIv;              // (b*K+k)*L + l
  int k = (int)((bkl / LL) % KKv);
  const float* xr = xdbl + bkl * 38;
  const float* wr = dtw + ((size_t)k * DIv + d) * DTRv;
  float s = dtb[k * DIv + d];
#pragma unroll
  for (int r = 0; r < DTRv; ++r) s += xr[r] * wr[r];
  delta[idx] = (s > 20.f) ? s : log1pf(expf(s));
}

// K4a: chunked scan pass 1 — per-chunk local final state S and decay product P.
__global__ void k_scan1(const float* __restrict__ delta, const float* __restrict__ xdbl,
                        const float* __restrict__ xc, const float* __restrict__ alogs,
                        float* __restrict__ S, float* __restrict__ P) {
  int bx = blockIdx.x;
  int c = bx / NDB, dblk = bx % NDB;
  int k = blockIdx.y, b = blockIdx.z;
  int t = threadIdx.x, dl = t >> 4, n = t & 15;
  int d = dblk * 16 + dl;
  float A = -expf(alogs[(size_t)(k * DIv + d) * DSn + n]);
  size_t bkL = (size_t)(b * KKv + k) * LL;
  const float* dp = delta + bkL * DIv + d;
  const float* xq = xdbl + bkL * 38;
  const float* xcb = xc + (size_t)b * LL * DIv + d;
  float h = 0.f, sA = 0.f;
  int l0 = c * CHK;
  for (int i = 0; i < CHK; ++i) {
    int l = l0 + i;
    float de = dp[(size_t)l * DIv];
    float Bv = xq[(size_t)l * 38 + 6 + n];
    float xv = xcb[(size_t)lmap(k, l) * DIv];
    float u = de * A;
    sA += u;
    h = h * expf(u) + de * xv * Bv;
  }
  size_t o = (((size_t)(b * KKv + k) * NC + c) * NDB + dblk) * 256 + t;
  S[o] = h;
  P[o] = expf(sA);
}

// K4b: sequential chunk combine. Rewrites S[c] <- Hin[c] (state entering chunk c).
__global__ void k_scan2(float* __restrict__ S, const float* __restrict__ P) {
  int dblk = blockIdx.x, k = blockIdx.y, b = blockIdx.z;
  int t = threadIdx.x;  // 256
  size_t base = ((size_t)(b * KKv + k) * NC) * (NDB * 256) + (size_t)dblk * 256 + t;
  float h = 0.f;
  for (int c = 0; c < NC; ++c) {
    size_t o = base + (size_t)c * (NDB * 256);
    float s = S[o], p = P[o];
    S[o] = h;  // Hin for chunk c
    h = s + p * h;
  }
}

// K4c: chunked scan pass 3 — exact recurrence from Hin, emit y.
__global__ void k_scan3(const float* __restrict__ delta, const float* __restrict__ xdbl,
                        const float* __restrict__ xc, const float* __restrict__ alogs,
                        const float* __restrict__ Hin, float* __restrict__ ys) {
  int bx = blockIdx.x;
  int c = bx / NDB, dblk = bx % NDB;
  int k = blockIdx.y, b = blockIdx.z;
  int t = threadIdx.x, dl = t >> 4, n = t & 15;
  int d = dblk * 16 + dl;
  float A = -expf(alogs[(size_t)(k * DIv + d) * DSn + n]);
  size_t bkL = (size_t)(b * KKv + k) * LL;
  const float* dp = delta + bkL * DIv + d;
  const float* xq = xdbl + bkL * 38;
  const float* xcb = xc + (size_t)b * LL * DIv + d;
  float* yp = ys + bkL * DIv + d;
  size_t o = (((size_t)(b * KKv + k) * NC + c) * NDB + dblk) * 256 + t;
  float h = Hin[o];
  int l0 = c * CHK;
  for (int i = 0; i < CHK; ++i) {
    int l = l0 + i;
    float de = dp[(size_t)l * DIv];
    float Bv = xq[(size_t)l * 38 + 6 + n];
    float Cv = xq[(size_t)l * 38 + 22 + n];
    float xv = xcb[(size_t)lmap(k, l) * DIv];
    h = h * expf(de * A) + de * xv * Bv;
    float p = h * Cv;
    p += __shfl_down(p, 8, 16);
    p += __shfl_down(p, 4, 16);
    p += __shfl_down(p, 2, 16);
    p += __shfl_down(p, 1, 16);
    if (n == 0) yp[(size_t)l * DIv] = p;
  }
}

// K5: merge 4 directions + D*x skip, output yg[b,l,d]
__global__ void k_combine(const float* __restrict__ ys, const float* __restrict__ xc,
                          const float* __restrict__ Ds, float* __restrict__ yg) {
  size_t idx = (size_t)blockIdx.x * 256 + threadIdx.x;  // B*L*DI
  int d = (int)(idx % DIv);
  int l = (int)((idx / DIv) % LL);
  int b = (int)(idx / ((size_t)DIv * LL));
  int lT = ((l & 63) << 6) | (l >> 6);
  size_t base = (size_t)b * KKv * LL * DIv;
  float v = ys[base + ((size_t)0 * LL + l) * DIv + d]
          + ys[base + ((size_t)2 * LL + (LL - 1 - l)) * DIv + d]
          + ys[base + ((size_t)1 * LL + lT) * DIv + d]
          + ys[base + ((size_t)3 * LL + (LL - 1 - lT)) * DIv + d];
  float sd = Ds[d] + Ds[DIv + d] + Ds[2 * DIv + d] + Ds[3 * DIv + d];
  v += sd * xc[((size_t)b * LL + l) * DIv + d];
  yg[idx] = v;
}

// K6: LayerNorm(DI) * silu(z)
__global__ void k_lngate(const float* __restrict__ yg, const float* __restrict__ z,
                         const float* __restrict__ g, const float* __restrict__ be,
                         float* __restrict__ out) {
  int bl = blockIdx.x;
  int t = threadIdx.x;  // 64
  const float* yr = yg + (size_t)bl * DIv;
  float v[3];
  float s = 0.f, q = 0.f;
#pragma unroll
  for (int cc = 0; cc < 3; ++cc) { v[cc] = yr[t + cc * 64]; s += v[cc]; q += v[cc] * v[cc]; }
#pragma unroll
  for (int o = 32; o > 0; o >>= 1) { s += __shfl_xor(s, o, 64); q += __shfl_xor(q, o, 64); }
  float m = s / DIv;
  float var = q / DIv - m * m;
  float rs = rsqrtf(var + 1e-5f);
  const float* zr = z + (size_t)bl * DIv;
  float* orow = out + (size_t)bl * DIv;
#pragma unroll
  for (int cc = 0; cc < 3; ++cc) {
    int d = t + cc * 64;
    float zz = zr[d];
    float val = (v[cc] - m) * rs * g[d] + be[d];
    orow[d] = val * zz * sigf(zz);
  }
}

// K7: out0 = ygated @ out_proj_w.T   (8 rows/block, float4 K-loop, K=192 -> 48 f4)
__global__ void k_outproj(const float* __restrict__ yq, const float* __restrict__ w,
                          float* __restrict__ out0) {
  int tile = blockIdx.x;  // 2048 blocks
  int t = threadIdx.x;    // 256
  __shared__ float4 yr[8 * 48];
  const float4* yq4 = (const float4*)yq;
  for (int i = t; i < 8 * 48; i += 256) yr[i] = yq4[(size_t)tile * 8 * 48 + i];
  __syncthreads();
  int c = t & 127, rh = t >> 7;  // rows rh*4..rh*4+3
  if (c < DMv) {
    const float4* wr = (const float4*)w + (size_t)c * 48;
    float a[4] = {0.f, 0.f, 0.f, 0.f};
    for (int dq = 0; dq < 48; ++dq) {
      float4 wv = wr[dq];
#pragma unroll
      for (int li = 0; li < 4; ++li) a[li] += dot4(yr[(rh * 4 + li) * 48 + dq], wv);
    }
#pragma unroll
    for (int li = 0; li < 4; ++li)
      out0[((size_t)tile * 8 + rh * 4 + li) * DMv + c] = a[li];
  }
}

// K8: hcl = silu(ygated @ ffn_in_w.T + b)   (8 rows x 768 cols/block, float4 K-loop)
__global__ void k_ffnin(const float* __restrict__ yq, const float* __restrict__ w,
                        const float* __restrict__ bias, float* __restrict__ hcl) {
  int tile = blockIdx.x;  // 2048
  int t = threadIdx.x;    // 256
  __shared__ float4 yr[8 * 48];
  const float4* yq4 = (const float4*)yq;
  for (int i = t; i < 8 * 48; i += 256) yr[i] = yq4[(size_t)tile * 8 * 48 + i];
  __syncthreads();
  const float4* w4 = (const float4*)w;
  float acc[3][8];
#pragma unroll
  for (int cc = 0; cc < 3; ++cc)
#pragma unroll
    for (int li = 0; li < 8; ++li) acc[cc][li] = 0.f;
  for (int dq = 0; dq < 48; ++dq) {
    float4 yv[8];
#pragma unroll
    for (int li = 0; li < 8; ++li) yv[li] = yr[li * 48 + dq];
#pragma unroll
    for (int cc = 0; cc < 3; ++cc) {
      float4 wv = w4[(size_t)(t + cc * 256) * 48 + dq];
#pragma unroll
      for (int li = 0; li < 8; ++li) acc[cc][li] += dot4(wv, yv[li]);
    }
  }
#pragma unroll
  for (int cc = 0; cc < 3; ++cc) {
    int c = t + cc * 256;
    float bv = bias[c];
#pragma unroll
    for (int li = 0; li < 8; ++li) {
      float s = acc[cc][li] + bv;
      hcl[((size_t)tile * 8 + li) * HIDv + c] = s * sigf(s);
    }
  }
}

// K9 (tiled): hc2 = (1 + w1)*hc(center) + dwconv3(hc) + dwconv5(hc), fused 5x5 stencil.
constexpr int TS = 16, CG = 32, TW = TS + 4;  // TW=20
__global__ void k_ffnconv(const float* __restrict__ hcl, const float* __restrict__ w1,
                          const float* __restrict__ w3, const float* __restrict__ w5,
                          float* __restrict__ hc2) {
  int tile = blockIdx.x;            // 0..15 (4x4 spatial tiles)
  int cg = blockIdx.y, b = blockIdx.z;
  int t = threadIdx.x;              // 256
  int ti0 = (tile >> 2) * TS, tj0 = (tile & 3) * TS;
  __shared__ float sm[TW * TW * CG];

  for (int e = t; e < TW * TW * CG; e += 256) {
    int ec = e & 31;
    int sp = e >> 5;                // 0..399
    int hi = sp / TW, hj = sp % TW;
    int gi = ti0 + hi - 2, gj = tj0 + hj - 2;
    float v = 0.f;
    if ((unsigned)gi < (unsigned)HH && (unsigned)gj < (unsigned)WW)
      v = hcl[((size_t)b * LL + gi * WW + gj) * HIDv + cg * CG + ec];
    sm[e] = v;
  }

  int c = t & 31;
  int cglob = cg * CG + c;
  float wc[25];
#pragma unroll
  for (int di = 0; di < 5; ++di)
#pragma unroll
    for (int dj = 0; dj < 5; ++dj) {
      float w = w5[cglob * 25 + di * 5 + dj];
      if (di >= 1 && di <= 3 && dj >= 1 && dj <= 3)
        w += w3[cglob * 9 + (di - 1) * 3 + (dj - 1)];
      if (di == 2 && dj == 2) w += 1.f + w1[cglob];
      wc[di * 5 + dj] = w;
    }
  __syncthreads();

  int s0 = t >> 5;  // 0..7
  for (int i = 0; i < 32; ++i) {
    int p = s0 + (i << 3);          // 0..255
    int r = p >> 4, q = p & 15;
    float s = 0.f;
#pragma unroll
    for (int di = 0; di < 5; ++di)
#pragma unroll
      for (int dj = 0; dj < 5; ++dj)
        s += sm[((r + di) * TW + (q + dj)) * CG + c] * wc[di * 5 + dj];
    hc2[((size_t)b * LL + (ti0 + r) * WW + (tj0 + q)) * HIDv + cglob] = s;
  }
}

// K10: LayerNorm over HID
__global__ void k_ln2(const float* __restrict__ hc2, const float* __restrict__ g,
                      const float* __restrict__ be, float* __restrict__ hn) {
  int bl = blockIdx.x;
  int t = threadIdx.x;  // 256
  const float* xr = hc2 + (size_t)bl * HIDv;
  float v[3];
  float s = 0.f, q = 0.f;
#pragma unroll
  for (int cc = 0; cc < 3; ++cc) { v[cc] = xr[t + cc * 256]; s += v[cc]; q += v[cc] * v[cc]; }
#pragma unroll
  for (int o = 32; o > 0; o >>= 1) { s += __shfl_xor(s, o, 64); q += __shfl_xor(q, o, 64); }
  __shared__ float rs_[4], rq_[4];
  int wid = t >> 6;
  if ((t & 63) == 0) { rs_[wid] = s; rq_[wid] = q; }
  __syncthreads();
  s = rs_[0] + rs_[1] + rs_[2] + rs_[3];
  q = rq_[0] + rq_[1] + rq_[2] + rq_[3];
  float m = s / HIDv;
  float var = q / HIDv - m * m;
  float r = rsqrtf(var + 1e-5f);
#pragma unroll
  for (int cc = 0; cc < 3; ++cc) {
    int c = t + cc * 256;
    hn[(size_t)bl * HIDv + c] = (v[cc] - m) * r * g[c] + be[c];
  }
}

// K11: d_out = out0 + skip * (hn @ ffn_out_w.T + b)  (8 rows/block, float4 K=768 -> 192 f4)
__global__ void k_final(const float* __restrict__ hn, const float* __restrict__ w,
                        const float* __restrict__ bias, const float* __restrict__ out0,
                        const float* __restrict__ skip, float* __restrict__ dout) {
  int tile = blockIdx.x;  // 2048
  int t = threadIdx.x;    // 256
  __shared__ float4 xr[8 * 192];  // 24 KB
  const float4* hn4 = (const float4*)hn;
  for (int i = t; i < 8 * 192; i += 256) xr[i] = hn4[(size_t)tile * 8 * 192 + i];
  __syncthreads();
  int c = t & 127, rh = t >> 7;
  if (c < DMv) {
    const float4* wr = (const float4*)w + (size_t)c * 192;
    float a[4] = {0.f, 0.f, 0.f, 0.f};
    for (int dq = 0; dq < 192; ++dq) {
      float4 wv = wr[dq];
#pragma unroll
      for (int li = 0; li < 4; ++li) a[li] += dot4(xr[(rh * 4 + li) * 192 + dq], wv);
    }
    float sk = skip[0];
    float bv = bias[c];
#pragma unroll
    for (int li = 0; li < 4; ++li) {
      size_t o = ((size_t)tile * 8 + rh * 4 + li) * DMv + c;
      dout[o] = out0[o] + sk * (a[li] + bv);
    }
  }
}

extern "C" void kernel_launch(void* const* d_in, const int* in_sizes, int n_in,
                              void* d_out, int out_size, void* d_ws, size_t ws_size,
                              hipStream_t stream) {
  const float* x        = (const float*)d_in[0];
  const float* in_w     = (const float*)d_in[1];
  const float* conv_w   = (const float*)d_in[2];
  const float* conv_b   = (const float*)d_in[3];
  const float* xpw      = (const float*)d_in[4];
  const float* dtw      = (const float*)d_in[5];
  const float* dtb      = (const float*)d_in[6];
  const float* alogs    = (const float*)d_in[7];
  const float* Ds       = (const float*)d_in[8];
  const float* ong      = (const float*)d_in[9];
  const float* onb      = (const float*)d_in[10];
  const float* opw      = (const float*)d_in[11];
  const float* fiw      = (const float*)d_in[12];
  const float* fib      = (const float*)d_in[13];
  const float* dw1      = (const float*)d_in[14];
  const float* dw3      = (const float*)d_in[15];
  const float* dw5      = (const float*)d_in[16];
  const float* flg      = (const float*)d_in[17];
  const float* flb      = (const float*)d_in[18];
  const float* fow      = (const float*)d_in[19];
  const float* fob      = (const float*)d_in[20];
  const float* skip     = (const float*)d_in[21];

  // Workspace layout (aliased; total = 3*S_xi + S_xdbl + 2*S_big floats ≈ 148 MB)
  float* ws    = (float*)d_ws;
  float* xi    = ws;                 // dead after k_dwconv -> S/P during scan -> yg
  float* z     = xi + S_xi;
  float* xc    = z + S_xi;           // dead after k_combine -> reused as ygt
  float* xdbl  = xc + S_xi;          // dead after k_scan3   -> reused as out0
  float* delta = xdbl + S_xdbl;      // dead after k_scan3   -> reused as hcl, then hn
  float* ys    = delta + S_big;      // dead after k_combine -> reused as hc2

  k_inproj<<<BB * LL / 4, 256, 0, stream>>>(x, in_w, xi, z);
  k_dwconv<<<(BB * LL * DIv) / 256, 256, 0, stream>>>(xi, conv_w, conv_b, xc);
  dim3 g3(LL, KKv, BB);
  k_xdbl<<<g3, 64, 0, stream>>>(xc, xpw, xdbl);
  k_delta<<<(BB * KKv * LL * DIv) / 256, 256, 0, stream>>>(xdbl, dtw, dtb, delta);

  // Chunked scan: S/P buffers alias xi (dead until k_combine writes yg there)
  float* Sbuf = xi;                  // S_sp floats
  float* Pbuf = xi + S_sp;           // S_sp floats (S_sp*2 == S_xi exactly)
  dim3 gs13(NC * NDB, KKv, BB);      // 6144 blocks
  dim3 gs2(NDB, KKv, BB);            // 192 blocks (tiny)
  k_scan1<<<gs13, 256, 0, stream>>>(delta, xdbl, xc, alogs, Sbuf, Pbuf);
  k_scan2<<<gs2, 256, 0, stream>>>(Sbuf, Pbuf);  // S <- Hin
  k_scan3<<<gs13, 256, 0, stream>>>(delta, xdbl, xc, alogs, Sbuf, ys);

  float* yg = xi;  // overwrites S/P (dead after k_scan3)
  k_combine<<<(BB * LL * DIv) / 256, 256, 0, stream>>>(ys, xc, Ds, yg);
  float* ygt = xc;
  k_lngate<<<BB * LL, 64, 0, stream>>>(yg, z, ong, onb, ygt);
  float* out0 = xdbl;
  k_outproj<<<BB * LL / 8, 256, 0, stream>>>(ygt, opw, out0);
  float* hcl = delta;
  k_ffnin<<<BB * LL / 8, 256, 0, stream>>>(ygt, fiw, fib, hcl);
  float* hc2 = ys;
  dim3 gc(16, HIDv / CG, BB);        // 16 spatial tiles x 24 ch-groups x 4
  k_ffnconv<<<gc, 256, 0, stream>>>(hcl, dw1, dw3, dw5, hc2);
  float* hn = delta;  // hcl dead after k_ffnconv
  k_ln2<<<BB * LL, 256, 0, stream>>>(hc2, flg, flb, hn);
  k_final<<<BB * LL / 8, 256, 0, stream>>>(hn, fow, fob, out0, skip, (float*)d_out);
}

// Round 6
// 1362.817 us; speedup vs baseline: 1.3350x; 1.3350x over previous
//
#include <hip/hip_runtime.h>
#include <hip/hip_bf16.h>

constexpr int BB = 4, HH = 64, WW = 64, DMv = 96;
constexpr int DSn = 16, DIv = 192, DTRv = 6, KKv = 4, HIDv = 768;
constexpr int LL = 4096;
constexpr int NC = 32, CHK = LL / NC;       // 32 chunks of 128
constexpr int NDB = DIv / 16;               // 12 d-blocks of 16 channels
constexpr int NR = BB * LL;                 // 16384 rows

constexpr size_t S_xi   = (size_t)BB * LL * DIv;          // 3,145,728
constexpr size_t S_xdbl = (size_t)BB * KKv * LL * 38;     // 2,490,368
constexpr size_t S_big  = (size_t)BB * KKv * LL * DIv;    // 12,582,912
constexpr size_t S_sp   = (size_t)BB * KKv * NC * DIv * DSn;  // 1,572,864 (= S_xi/2)

__device__ __forceinline__ float sigf(float x) { return 1.f / (1.f + expf(-x)); }
__device__ __forceinline__ float dot4(float4 a, float4 b) {
  return a.x * b.x + a.y * b.y + a.z * b.z + a.w * b.w;
}

__device__ __forceinline__ int lmap(int k, int l) {
  int lr = (k & 2) ? (LL - 1 - l) : l;
  return (k & 1) ? (((lr & 63) << 6) | (lr >> 6)) : lr;
}

// K0a: wt[k][c] = in_proj_w[c][k]  (96 x 384)
__global__ void k_wt(const float* __restrict__ w, float* __restrict__ wt) {
  int idx = blockIdx.x * 256 + threadIdx.x;  // 36864
  if (idx < 96 * 384) {
    int k = idx / 384, c = idx % 384;
    wt[idx] = w[c * 96 + k];
  }
}

// K0b: xt[k][row] = x[row][k]  (96 x 16384), 64x32 LDS tile transpose
__global__ void k_xt(const float* __restrict__ x, float* __restrict__ xt) {
  __shared__ float tile[32][65];
  int r0 = blockIdx.x * 64, k0 = blockIdx.y * 32;
  int t = threadIdx.x;  // 256
#pragma unroll
  for (int ii = 0; ii < 8; ++ii) {
    int i = (t >> 5) + ii * 8, j = t & 31;
    tile[j][i] = x[(size_t)(r0 + i) * 96 + k0 + j];
  }
  __syncthreads();
#pragma unroll
  for (int jj = 0; jj < 8; ++jj) {
    int j = (t >> 6) + jj * 4, i = t & 63;
    xt[(size_t)(k0 + j) * NR + r0 + i] = tile[j][i];
  }
}

// K1: xz = x @ in_proj_w.T via xt/wt. Lane = 4 rows (f4, coalesced), wave-uniform
// scalar weight loads. Grid (16 row-blocks, 48 col-groups of 8), block 256.
__global__ void k_inproj(const float* __restrict__ xt, const float* __restrict__ wt,
                         float* __restrict__ xi, float* __restrict__ z) {
  int t = threadIdx.x;
  int wv = t >> 6, lane = t & 63;
  int rq = blockIdx.x * 256 + wv * 64 + lane;   // float4-row index (row = rq*4)
  int c0 = blockIdx.y * 8;
  const float4* xt4 = (const float4*)xt;
  float4 acc[8];
#pragma unroll
  for (int c = 0; c < 8; ++c) acc[c] = make_float4(0.f, 0.f, 0.f, 0.f);
  for (int k = 0; k < 96; ++k) {
    float4 xv = xt4[(size_t)k * (NR / 4) + rq];
    const float* wr = wt + k * 384 + c0;  // wave-uniform -> s_load
#pragma unroll
    for (int c = 0; c < 8; ++c) {
      float w = wr[c];
      acc[c].x += w * xv.x; acc[c].y += w * xv.y;
      acc[c].z += w * xv.z; acc[c].w += w * xv.w;
    }
  }
  float* dst; int cc;
  if (c0 < DIv) { dst = xi; cc = c0; } else { dst = z; cc = c0 - DIv; }
#pragma unroll
  for (int li = 0; li < 4; ++li) {
    size_t row = (size_t)rq * 4 + li;
    float4 v0, v1;
    v0.x = (&acc[0].x)[li]; v0.y = (&acc[1].x)[li];
    v0.z = (&acc[2].x)[li]; v0.w = (&acc[3].x)[li];
    v1.x = (&acc[4].x)[li]; v1.y = (&acc[5].x)[li];
    v1.z = (&acc[6].x)[li]; v1.w = (&acc[7].x)[li];
    float4* o4 = (float4*)(dst + row * DIv + cc);
    o4[0] = v0; o4[1] = v1;
  }
}

// K2: xc = silu(dwconv3x3(xi) + conv_b), channel-last
__global__ void k_dwconv(const float* __restrict__ xi, const float* __restrict__ cw,
                         const float* __restrict__ cb, float* __restrict__ xc) {
  size_t idx = (size_t)blockIdx.x * 256 + threadIdx.x;  // B*L*DI
  int d = (int)(idx % DIv);
  int l = (int)((idx / DIv) % LL);
  int b = (int)(idx / ((size_t)DIv * LL));
  int i = l >> 6, j = l & 63;
  float s = cb[d];
#pragma unroll
  for (int di = 0; di < 3; ++di) {
    int ii = i + di - 1;
    if ((unsigned)ii >= (unsigned)HH) continue;
#pragma unroll
    for (int dj = 0; dj < 3; ++dj) {
      int jj = j + dj - 1;
      if ((unsigned)jj >= (unsigned)WW) continue;
      s += xi[((size_t)b * LL + ii * WW + jj) * DIv + d] * cw[d * 9 + di * 3 + dj];
    }
  }
  xc[idx] = s * sigf(s);
}

// K3a: x_dbl[b,k,l,c] = sum_d xs[b,k,d,l] * x_proj_w[k,c,d]
__global__ void k_xdbl(const float* __restrict__ xc, const float* __restrict__ xpw,
                       float* __restrict__ xdbl) {
  int l = blockIdx.x, k = blockIdx.y, b = blockIdx.z;
  int t = threadIdx.x;  // 64
  __shared__ float4 col[48];
  int lc = lmap(k, l);
  const float4* xc4 = (const float4*)(xc + ((size_t)b * LL + lc) * DIv);
  if (t < 48) col[t] = xc4[t];
  __syncthreads();
  const float4* xpw4 = (const float4*)xpw;
  for (int c = t; c < 38; c += 64) {
    const float4* wr = xpw4 + ((size_t)k * 38 + c) * 48;
    float s = 0.f;
    for (int dq = 0; dq < 48; ++dq) s += dot4(col[dq], wr[dq]);
    xdbl[((size_t)(b * KKv + k) * LL + l) * 38 + c] = s;
  }
}

// K3b: delta[b,k,l,d] = softplus(dts @ dt_projs_w + dt_projs_b)
__global__ void k_delta(const float* __restrict__ xdbl, const float* __restrict__ dtw,
                        const float* __restrict__ dtb, float* __restrict__ delta) {
  size_t idx = (size_t)blockIdx.x * 256 + threadIdx.x;  // B*K*L*DI
  int d = (int)(idx % DIv);
  size_t bkl = idx / DIv;              // (b*K+k)*L + l
  int k = (int)((bkl / LL) % KKv);
  const float* xr = xdbl + bkl * 38;
  const float* wr = dtw + ((size_t)k * DIv + d) * DTRv;
  float s = dtb[k * DIv + d];
#pragma unroll
  for (int r = 0; r < DTRv; ++r) s += xr[r] * wr[r];
  delta[idx] = (s > 20.f) ? s : log1pf(expf(s));
}

// K4a: chunked scan pass 1 — per-chunk local final state S and decay product P.
__global__ void k_scan1(const float* __restrict__ delta, const float* __restrict__ xdbl,
                        const float* __restrict__ xc, const float* __restrict__ alogs,
                        float* __restrict__ S, float* __restrict__ P) {
  int bx = blockIdx.x;
  int c = bx / NDB, dblk = bx % NDB;
  int k = blockIdx.y, b = blockIdx.z;
  int t = threadIdx.x, dl = t >> 4, n = t & 15;
  int d = dblk * 16 + dl;
  float A = -expf(alogs[(size_t)(k * DIv + d) * DSn + n]);
  size_t bkL = (size_t)(b * KKv + k) * LL;
  const float* dp = delta + bkL * DIv + d;
  const float* xq = xdbl + bkL * 38;
  const float* xcb = xc + (size_t)b * LL * DIv + d;
  float h = 0.f, sA = 0.f;
  int l0 = c * CHK;
  for (int i = 0; i < CHK; ++i) {
    int l = l0 + i;
    float de = dp[(size_t)l * DIv];
    float Bv = xq[(size_t)l * 38 + 6 + n];
    float xv = xcb[(size_t)lmap(k, l) * DIv];
    float u = de * A;
    sA += u;
    h = h * expf(u) + de * xv * Bv;
  }
  size_t o = (((size_t)(b * KKv + k) * NC + c) * NDB + dblk) * 256 + t;
  S[o] = h;
  P[o] = expf(sA);
}

// K4b: sequential chunk combine. Rewrites S[c] <- Hin[c] (state entering chunk c).
__global__ void k_scan2(float* __restrict__ S, const float* __restrict__ P) {
  int dblk = blockIdx.x, k = blockIdx.y, b = blockIdx.z;
  int t = threadIdx.x;  // 256
  size_t base = ((size_t)(b * KKv + k) * NC) * (NDB * 256) + (size_t)dblk * 256 + t;
  float h = 0.f;
  for (int c = 0; c < NC; ++c) {
    size_t o = base + (size_t)c * (NDB * 256);
    float s = S[o], p = P[o];
    S[o] = h;  // Hin for chunk c
    h = s + p * h;
  }
}

// K4c: chunked scan pass 3 — exact recurrence from Hin, emit y.
__global__ void k_scan3(const float* __restrict__ delta, const float* __restrict__ xdbl,
                        const float* __restrict__ xc, const float* __restrict__ alogs,
                        const float* __restrict__ Hin, float* __restrict__ ys) {
  int bx = blockIdx.x;
  int c = bx / NDB, dblk = bx % NDB;
  int k = blockIdx.y, b = blockIdx.z;
  int t = threadIdx.x, dl = t >> 4, n = t & 15;
  int d = dblk * 16 + dl;
  float A = -expf(alogs[(size_t)(k * DIv + d) * DSn + n]);
  size_t bkL = (size_t)(b * KKv + k) * LL;
  const float* dp = delta + bkL * DIv + d;
  const float* xq = xdbl + bkL * 38;
  const float* xcb = xc + (size_t)b * LL * DIv + d;
  float* yp = ys + bkL * DIv + d;
  size_t o = (((size_t)(b * KKv + k) * NC + c) * NDB + dblk) * 256 + t;
  float h = Hin[o];
  int l0 = c * CHK;
  for (int i = 0; i < CHK; ++i) {
    int l = l0 + i;
    float de = dp[(size_t)l * DIv];
    float Bv = xq[(size_t)l * 38 + 6 + n];
    float Cv = xq[(size_t)l * 38 + 22 + n];
    float xv = xcb[(size_t)lmap(k, l) * DIv];
    h = h * expf(de * A) + de * xv * Bv;
    float p = h * Cv;
    p += __shfl_down(p, 8, 16);
    p += __shfl_down(p, 4, 16);
    p += __shfl_down(p, 2, 16);
    p += __shfl_down(p, 1, 16);
    if (n == 0) yp[(size_t)l * DIv] = p;
  }
}

// K5: merge 4 directions + D*x skip, output yg[b,l,d]
__global__ void k_combine(const float* __restrict__ ys, const float* __restrict__ xc,
                          const float* __restrict__ Ds, float* __restrict__ yg) {
  size_t idx = (size_t)blockIdx.x * 256 + threadIdx.x;  // B*L*DI
  int d = (int)(idx % DIv);
  int l = (int)((idx / DIv) % LL);
  int b = (int)(idx / ((size_t)DIv * LL));
  int lT = ((l & 63) << 6) | (l >> 6);
  size_t base = (size_t)b * KKv * LL * DIv;
  float v = ys[base + ((size_t)0 * LL + l) * DIv + d]
          + ys[base + ((size_t)2 * LL + (LL - 1 - l)) * DIv + d]
          + ys[base + ((size_t)1 * LL + lT) * DIv + d]
          + ys[base + ((size_t)3 * LL + (LL - 1 - lT)) * DIv + d];
  float sd = Ds[d] + Ds[DIv + d] + Ds[2 * DIv + d] + Ds[3 * DIv + d];
  v += sd * xc[((size_t)b * LL + l) * DIv + d];
  yg[idx] = v;
}

// K6: LayerNorm(DI) * silu(z)
__global__ void k_lngate(const float* __restrict__ yg, const float* __restrict__ z,
                         const float* __restrict__ g, const float* __restrict__ be,
                         float* __restrict__ out) {
  int bl = blockIdx.x;
  int t = threadIdx.x;  // 64
  const float* yr = yg + (size_t)bl * DIv;
  float v[3];
  float s = 0.f, q = 0.f;
#pragma unroll
  for (int cc = 0; cc < 3; ++cc) { v[cc] = yr[t + cc * 64]; s += v[cc]; q += v[cc] * v[cc]; }
#pragma unroll
  for (int o = 32; o > 0; o >>= 1) { s += __shfl_xor(s, o, 64); q += __shfl_xor(q, o, 64); }
  float m = s / DIv;
  float var = q / DIv - m * m;
  float rs = rsqrtf(var + 1e-5f);
  const float* zr = z + (size_t)bl * DIv;
  float* orow = out + (size_t)bl * DIv;
#pragma unroll
  for (int cc = 0; cc < 3; ++cc) {
    int d = t + cc * 64;
    float zz = zr[d];
    float val = (v[cc] - m) * rs * g[d] + be[d];
    orow[d] = val * zz * sigf(zz);
  }
}

// K7: out0 = ygated @ out_proj_w.T   (8 rows/block, float4 K-loop, K=192 -> 48 f4)
__global__ void k_outproj(const float* __restrict__ yq, const float* __restrict__ w,
                          float* __restrict__ out0) {
  int tile = blockIdx.x;  // 2048 blocks
  int t = threadIdx.x;    // 256
  __shared__ float4 yr[8 * 48];
  const float4* yq4 = (const float4*)yq;
  for (int i = t; i < 8 * 48; i += 256) yr[i] = yq4[(size_t)tile * 8 * 48 + i];
  __syncthreads();
  int c = t & 127, rh = t >> 7;  // rows rh*4..rh*4+3
  if (c < DMv) {
    const float4* wr = (const float4*)w + (size_t)c * 48;
    float a[4] = {0.f, 0.f, 0.f, 0.f};
    for (int dq = 0; dq < 48; ++dq) {
      float4 wv = wr[dq];
#pragma unroll
      for (int li = 0; li < 4; ++li) a[li] += dot4(yr[(rh * 4 + li) * 48 + dq], wv);
    }
#pragma unroll
    for (int li = 0; li < 4; ++li)
      out0[((size_t)tile * 8 + rh * 4 + li) * DMv + c] = a[li];
  }
}

// K8: hcl = silu(ygated @ ffn_in_w.T + b)   (8 rows x 768 cols/block, float4 K-loop)
__global__ void k_ffnin(const float* __restrict__ yq, const float* __restrict__ w,
                        const float* __restrict__ bias, float* __restrict__ hcl) {
  int tile = blockIdx.x;  // 2048
  int t = threadIdx.x;    // 256
  __shared__ float4 yr[8 * 48];
  const float4* yq4 = (const float4*)yq;
  for (int i = t; i < 8 * 48; i += 256) yr[i] = yq4[(size_t)tile * 8 * 48 + i];
  __syncthreads();
  const float4* w4 = (const float4*)w;
  float acc[3][8];
#pragma unroll
  for (int cc = 0; cc < 3; ++cc)
#pragma unroll
    for (int li = 0; li < 8; ++li) acc[cc][li] = 0.f;
  for (int dq = 0; dq < 48; ++dq) {
    float4 yv[8];
#pragma unroll
    for (int li = 0; li < 8; ++li) yv[li] = yr[li * 48 + dq];
#pragma unroll
    for (int cc = 0; cc < 3; ++cc) {
      float4 wv = w4[(size_t)(t + cc * 256) * 48 + dq];
#pragma unroll
      for (int li = 0; li < 8; ++li) acc[cc][li] += dot4(wv, yv[li]);
    }
  }
#pragma unroll
  for (int cc = 0; cc < 3; ++cc) {
    int c = t + cc * 256;
    float bv = bias[c];
#pragma unroll
    for (int li = 0; li < 8; ++li) {
      float s = acc[cc][li] + bv;
      hcl[((size_t)tile * 8 + li) * HIDv + c] = s * sigf(s);
    }
  }
}

// K9 (tiled): hc2 = (1 + w1)*hc(center) + dwconv3(hc) + dwconv5(hc), fused 5x5 stencil.
constexpr int TS = 16, CG = 32, TW = TS + 4;  // TW=20
__global__ void k_ffnconv(const float* __restrict__ hcl, const float* __restrict__ w1,
                          const float* __restrict__ w3, const float* __restrict__ w5,
                          float* __restrict__ hc2) {
  int tile = blockIdx.x;            // 0..15 (4x4 spatial tiles)
  int cg = blockIdx.y, b = blockIdx.z;
  int t = threadIdx.x;              // 256
  int ti0 = (tile >> 2) * TS, tj0 = (tile & 3) * TS;
  __shared__ float sm[TW * TW * CG];

  for (int e = t; e < TW * TW * CG; e += 256) {
    int ec = e & 31;
    int sp = e >> 5;                // 0..399
    int hi = sp / TW, hj = sp % TW;
    int gi = ti0 + hi - 2, gj = tj0 + hj - 2;
    float v = 0.f;
    if ((unsigned)gi < (unsigned)HH && (unsigned)gj < (unsigned)WW)
      v = hcl[((size_t)b * LL + gi * WW + gj) * HIDv + cg * CG + ec];
    sm[e] = v;
  }

  int c = t & 31;
  int cglob = cg * CG + c;
  float wc[25];
#pragma unroll
  for (int di = 0; di < 5; ++di)
#pragma unroll
    for (int dj = 0; dj < 5; ++dj) {
      float w = w5[cglob * 25 + di * 5 + dj];
      if (di >= 1 && di <= 3 && dj >= 1 && dj <= 3)
        w += w3[cglob * 9 + (di - 1) * 3 + (dj - 1)];
      if (di == 2 && dj == 2) w += 1.f + w1[cglob];
      wc[di * 5 + dj] = w;
    }
  __syncthreads();

  int s0 = t >> 5;  // 0..7
  for (int i = 0; i < 32; ++i) {
    int p = s0 + (i << 3);          // 0..255
    int r = p >> 4, q = p & 15;
    float s = 0.f;
#pragma unroll
    for (int di = 0; di < 5; ++di)
#pragma unroll
      for (int dj = 0; dj < 5; ++dj)
        s += sm[((r + di) * TW + (q + dj)) * CG + c] * wc[di * 5 + dj];
    hc2[((size_t)b * LL + (ti0 + r) * WW + (tj0 + q)) * HIDv + cglob] = s;
  }
}

// K10: LayerNorm over HID
__global__ void k_ln2(const float* __restrict__ hc2, const float* __restrict__ g,
                      const float* __restrict__ be, float* __restrict__ hn) {
  int bl = blockIdx.x;
  int t = threadIdx.x;  // 256
  const float* xr = hc2 + (size_t)bl * HIDv;
  float v[3];
  float s = 0.f, q = 0.f;
#pragma unroll
  for (int cc = 0; cc < 3; ++cc) { v[cc] = xr[t + cc * 256]; s += v[cc]; q += v[cc] * v[cc]; }
#pragma unroll
  for (int o = 32; o > 0; o >>= 1) { s += __shfl_xor(s, o, 64); q += __shfl_xor(q, o, 64); }
  __shared__ float rs_[4], rq_[4];
  int wid = t >> 6;
  if ((t & 63) == 0) { rs_[wid] = s; rq_[wid] = q; }
  __syncthreads();
  s = rs_[0] + rs_[1] + rs_[2] + rs_[3];
  q = rq_[0] + rq_[1] + rq_[2] + rq_[3];
  float m = s / HIDv;
  float var = q / HIDv - m * m;
  float r = rsqrtf(var + 1e-5f);
#pragma unroll
  for (int cc = 0; cc < 3; ++cc) {
    int c = t + cc * 256;
    hn[(size_t)bl * HIDv + c] = (v[cc] - m) * r * g[c] + be[c];
  }
}

// K11: d_out = out0 + skip * (hn @ ffn_out_w.T + b)  (8 rows/block, float4 K=768 -> 192 f4)
__global__ void k_final(const float* __restrict__ hn, const float* __restrict__ w,
                        const float* __restrict__ bias, const float* __restrict__ out0,
                        const float* __restrict__ skip, float* __restrict__ dout) {
  int tile = blockIdx.x;  // 2048
  int t = threadIdx.x;    // 256
  __shared__ float4 xr[8 * 192];  // 24 KB
  const float4* hn4 = (const float4*)hn;
  for (int i = t; i < 8 * 192; i += 256) xr[i] = hn4[(size_t)tile * 8 * 192 + i];
  __syncthreads();
  int c = t & 127, rh = t >> 7;
  if (c < DMv) {
    const float4* wr = (const float4*)w + (size_t)c * 192;
    float a[4] = {0.f, 0.f, 0.f, 0.f};
    for (int dq = 0; dq < 192; ++dq) {
      float4 wv = wr[dq];
#pragma unroll
      for (int li = 0; li < 4; ++li) a[li] += dot4(xr[(rh * 4 + li) * 192 + dq], wv);
    }
    float sk = skip[0];
    float bv = bias[c];
#pragma unroll
    for (int li = 0; li < 4; ++li) {
      size_t o = ((size_t)tile * 8 + rh * 4 + li) * DMv + c;
      dout[o] = out0[o] + sk * (a[li] + bv);
    }
  }
}

extern "C" void kernel_launch(void* const* d_in, const int* in_sizes, int n_in,
                              void* d_out, int out_size, void* d_ws, size_t ws_size,
                              hipStream_t stream) {
  const float* x        = (const float*)d_in[0];
  const float* in_w     = (const float*)d_in[1];
  const float* conv_w   = (const float*)d_in[2];
  const float* conv_b   = (const float*)d_in[3];
  const float* xpw      = (const float*)d_in[4];
  const float* dtw      = (const float*)d_in[5];
  const float* dtb      = (const float*)d_in[6];
  const float* alogs    = (const float*)d_in[7];
  const float* Ds       = (const float*)d_in[8];
  const float* ong      = (const float*)d_in[9];
  const float* onb      = (const float*)d_in[10];
  const float* opw      = (const float*)d_in[11];
  const float* fiw      = (const float*)d_in[12];
  const float* fib      = (const float*)d_in[13];
  const float* dw1      = (const float*)d_in[14];
  const float* dw3      = (const float*)d_in[15];
  const float* dw5      = (const float*)d_in[16];
  const float* flg      = (const float*)d_in[17];
  const float* flb      = (const float*)d_in[18];
  const float* fow      = (const float*)d_in[19];
  const float* fob      = (const float*)d_in[20];
  const float* skip     = (const float*)d_in[21];

  // Workspace layout (aliased; total = 3*S_xi + S_xdbl + 2*S_big floats ≈ 148 MB)
  float* ws    = (float*)d_ws;
  float* xi    = ws;                 // dead after k_dwconv -> S/P during scan -> yg
  float* z     = xi + S_xi;
  float* xc    = z + S_xi;           // dead after k_combine -> reused as ygt
  float* xdbl  = xc + S_xi;          // dead after k_scan3   -> reused as out0
  float* delta = xdbl + S_xdbl;      // scratch for xt/wt now; delta after k_delta
  float* ys    = delta + S_big;      // dead after k_combine -> reused as hc2

  // In-proj via transposed operands (xt, wt live in the not-yet-used delta region)
  float* xt = delta;                       // 96*16384 = 1,572,864 floats
  float* wt = delta + 1600000;             // 36,864 floats (within S_big)
  k_wt<<<(96 * 384 + 255) / 256, 256, 0, stream>>>(in_w, wt);
  dim3 gxt(NR / 64, 3);
  k_xt<<<gxt, 256, 0, stream>>>(x, xt);
  dim3 gip(NR / 1024, 48);
  k_inproj<<<gip, 256, 0, stream>>>(xt, wt, xi, z);

  k_dwconv<<<(BB * LL * DIv) / 256, 256, 0, stream>>>(xi, conv_w, conv_b, xc);
  dim3 g3(LL, KKv, BB);
  k_xdbl<<<g3, 64, 0, stream>>>(xc, xpw, xdbl);
  k_delta<<<(BB * KKv * LL * DIv) / 256, 256, 0, stream>>>(xdbl, dtw, dtb, delta);

  // Chunked scan: S/P buffers alias xi (dead until k_combine writes yg there)
  float* Sbuf = xi;                  // S_sp floats
  float* Pbuf = xi + S_sp;           // S_sp floats (S_sp*2 == S_xi exactly)
  dim3 gs13(NC * NDB, KKv, BB);      // 6144 blocks
  dim3 gs2(NDB, KKv, BB);            // 192 blocks (tiny)
  k_scan1<<<gs13, 256, 0, stream>>>(delta, xdbl, xc, alogs, Sbuf, Pbuf);
  k_scan2<<<gs2, 256, 0, stream>>>(Sbuf, Pbuf);  // S <- Hin
  k_scan3<<<gs13, 256, 0, stream>>>(delta, xdbl, xc, alogs, Sbuf, ys);

  float* yg = xi;  // overwrites S/P (dead after k_scan3)
  k_combine<<<(BB * LL * DIv) / 256, 256, 0, stream>>>(ys, xc, Ds, yg);
  float* ygt = xc;
  k_lngate<<<BB * LL, 64, 0, stream>>>(yg, z, ong, onb, ygt);
  float* out0 = xdbl;
  k_outproj<<<BB * LL / 8, 256, 0, stream>>>(ygt, opw, out0);
  float* hcl = delta;
  k_ffnin<<<BB * LL / 8, 256, 0, stream>>>(ygt, fiw, fib, hcl);
  float* hc2 = ys;
  dim3 gc(16, HIDv / CG, BB);        // 16 spatial tiles x 24 ch-groups x 4
  k_ffnconv<<<gc, 256, 0, stream>>>(hcl, dw1, dw3, dw5, hc2);
  float* hn = delta;  // hcl dead after k_ffnconv
  k_ln2<<<BB * LL, 256, 0, stream>>>(hc2, flg, flb, hn);
  k_final<<<BB * LL / 8, 256, 0, stream>>>(hn, fow, fob, out0, skip, (float*)d_out);
}

// Round 7
// 1071.945 us; speedup vs baseline: 1.6973x; 1.2713x over previous
//
#include <hip/hip_runtime.h>
#include <hip/hip_bf16.h>

constexpr int BB = 4, HH = 64, WW = 64, DMv = 96;
constexpr int DSn = 16, DIv = 192, DTRv = 6, KKv = 4, HIDv = 768;
constexpr int LL = 4096;
constexpr int NC = 32, CHK = LL / NC;       // 32 chunks of 128
constexpr int NDB = DIv / 16;               // 12 d-blocks of 16 channels
constexpr int NR = BB * LL;                 // 16384 rows

constexpr size_t S_xi   = (size_t)BB * LL * DIv;          // 3,145,728
constexpr size_t S_xdbl = (size_t)BB * KKv * LL * 38;     // 2,490,368
constexpr size_t S_big  = (size_t)BB * KKv * LL * DIv;    // 12,582,912
constexpr size_t S_sp   = (size_t)BB * KKv * NC * DIv * DSn;  // 1,572,864 (= S_xi/2)

__device__ __forceinline__ float sigf(float x) { return 1.f / (1.f + expf(-x)); }
__device__ __forceinline__ float dot4(float4 a, float4 b) {
  return a.x * b.x + a.y * b.y + a.z * b.z + a.w * b.w;
}

__device__ __forceinline__ int lmap(int k, int l) {
  int lr = (k & 2) ? (LL - 1 - l) : l;
  return (k & 1) ? (((lr & 63) << 6) | (lr >> 6)) : lr;
}

// Generic 32x32 LDS tile transpose: src[R][C] -> dst[C][R], both coalesced.
__global__ void k_transp(const float* __restrict__ src, float* __restrict__ dst,
                         int R, int C) {
  __shared__ float tile[32][33];
  int r0 = blockIdx.x * 32, c0 = blockIdx.y * 32;
  int t = threadIdx.x;            // 256
  int tc = t & 31, tr = t >> 5;   // tr 0..7
#pragma unroll
  for (int i = 0; i < 4; ++i) {
    int r = r0 + tr + i * 8;
    if (r < R && c0 + tc < C) tile[tr + i * 8][tc] = src[(size_t)r * C + c0 + tc];
  }
  __syncthreads();
#pragma unroll
  for (int i = 0; i < 4; ++i) {
    int c = c0 + tr + i * 8;
    int r = r0 + tc;
    if (c < C && r < R) dst[(size_t)c * R + r] = tile[tc][tr + i * 8];
  }
}

// K0a: wt[k][c] = in_proj_w[c][k]  (96 x 384)
__global__ void k_wt(const float* __restrict__ w, float* __restrict__ wt) {
  int idx = blockIdx.x * 256 + threadIdx.x;  // 36864
  if (idx < 96 * 384) {
    int k = idx / 384, c = idx % 384;
    wt[idx] = w[c * 96 + k];
  }
}

// K0b: xt[k][row] = x[row][k]  (96 x 16384), 64x32 LDS tile transpose
__global__ void k_xt(const float* __restrict__ x, float* __restrict__ xt) {
  __shared__ float tile[32][65];
  int r0 = blockIdx.x * 64, k0 = blockIdx.y * 32;
  int t = threadIdx.x;  // 256
#pragma unroll
  for (int ii = 0; ii < 8; ++ii) {
    int i = (t >> 5) + ii * 8, j = t & 31;
    tile[j][i] = x[(size_t)(r0 + i) * 96 + k0 + j];
  }
  __syncthreads();
#pragma unroll
  for (int jj = 0; jj < 8; ++jj) {
    int j = (t >> 6) + jj * 4, i = t & 63;
    xt[(size_t)(k0 + j) * NR + r0 + i] = tile[j][i];
  }
}

// K1: xz = x @ in_proj_w.T via xt/wt. Lane = 4 rows (f4, coalesced), wave-uniform
// scalar weight loads. Grid (16 row-blocks, 48 col-groups of 8), block 256.
__global__ void k_inproj(const float* __restrict__ xt, const float* __restrict__ wt,
                         float* __restrict__ xi, float* __restrict__ z) {
  int t = threadIdx.x;
  int wv = t >> 6, lane = t & 63;
  int rq = blockIdx.x * 256 + wv * 64 + lane;   // float4-row index (row = rq*4)
  int c0 = blockIdx.y * 8;
  const float4* xt4 = (const float4*)xt;
  float4 acc[8];
#pragma unroll
  for (int c = 0; c < 8; ++c) acc[c] = make_float4(0.f, 0.f, 0.f, 0.f);
  for (int k = 0; k < 96; ++k) {
    float4 xv = xt4[(size_t)k * (NR / 4) + rq];
    const float* wr = wt + k * 384 + c0;  // wave-uniform -> s_load
#pragma unroll
    for (int c = 0; c < 8; ++c) {
      float w = wr[c];
      acc[c].x += w * xv.x; acc[c].y += w * xv.y;
      acc[c].z += w * xv.z; acc[c].w += w * xv.w;
    }
  }
  float* dst; int cc;
  if (c0 < DIv) { dst = xi; cc = c0; } else { dst = z; cc = c0 - DIv; }
#pragma unroll
  for (int li = 0; li < 4; ++li) {
    size_t row = (size_t)rq * 4 + li;
    float4 v0, v1;
    v0.x = (&acc[0].x)[li]; v0.y = (&acc[1].x)[li];
    v0.z = (&acc[2].x)[li]; v0.w = (&acc[3].x)[li];
    v1.x = (&acc[4].x)[li]; v1.y = (&acc[5].x)[li];
    v1.z = (&acc[6].x)[li]; v1.w = (&acc[7].x)[li];
    float4* o4 = (float4*)(dst + row * DIv + cc);
    o4[0] = v0; o4[1] = v1;
  }
}

// K2: xc = silu(dwconv3x3(xi) + conv_b), channel-last
__global__ void k_dwconv(const float* __restrict__ xi, const float* __restrict__ cw,
                         const float* __restrict__ cb, float* __restrict__ xc) {
  size_t idx = (size_t)blockIdx.x * 256 + threadIdx.x;  // B*L*DI
  int d = (int)(idx % DIv);
  int l = (int)((idx / DIv) % LL);
  int b = (int)(idx / ((size_t)DIv * LL));
  int i = l >> 6, j = l & 63;
  float s = cb[d];
#pragma unroll
  for (int di = 0; di < 3; ++di) {
    int ii = i + di - 1;
    if ((unsigned)ii >= (unsigned)HH) continue;
#pragma unroll
    for (int dj = 0; dj < 3; ++dj) {
      int jj = j + dj - 1;
      if ((unsigned)jj >= (unsigned)WW) continue;
      s += xi[((size_t)b * LL + ii * WW + jj) * DIv + d] * cw[d * 9 + di * 3 + dj];
    }
  }
  xc[idx] = s * sigf(s);
}

// K3a: x_dbl[b,k,l,c] = sum_d xs[b,k,d,l] * x_proj_w[k,c,d]
__global__ void k_xdbl(const float* __restrict__ xc, const float* __restrict__ xpw,
                       float* __restrict__ xdbl) {
  int l = blockIdx.x, k = blockIdx.y, b = blockIdx.z;
  int t = threadIdx.x;  // 64
  __shared__ float4 col[48];
  int lc = lmap(k, l);
  const float4* xc4 = (const float4*)(xc + ((size_t)b * LL + lc) * DIv);
  if (t < 48) col[t] = xc4[t];
  __syncthreads();
  const float4* xpw4 = (const float4*)xpw;
  for (int c = t; c < 38; c += 64) {
    const float4* wr = xpw4 + ((size_t)k * 38 + c) * 48;
    float s = 0.f;
    for (int dq = 0; dq < 48; ++dq) s += dot4(col[dq], wr[dq]);
    xdbl[((size_t)(b * KKv + k) * LL + l) * 38 + c] = s;
  }
}

// K3b: delta[b,k,l,d] = softplus(dts @ dt_projs_w + dt_projs_b)
__global__ void k_delta(const float* __restrict__ xdbl, const float* __restrict__ dtw,
                        const float* __restrict__ dtb, float* __restrict__ delta) {
  size_t idx = (size_t)blockIdx.x * 256 + threadIdx.x;  // B*K*L*DI
  int d = (int)(idx % DIv);
  size_t bkl = idx / DIv;              // (b*K+k)*L + l
  int k = (int)((bkl / LL) % KKv);
  const float* xr = xdbl + bkl * 38;
  const float* wr = dtw + ((size_t)k * DIv + d) * DTRv;
  float s = dtb[k * DIv + d];
#pragma unroll
  for (int r = 0; r < DTRv; ++r) s += xr[r] * wr[r];
  delta[idx] = (s > 20.f) ? s : log1pf(expf(s));
}

// K4a: chunked scan pass 1 — per-chunk local final state S and decay product P.
__global__ void k_scan1(const float* __restrict__ delta, const float* __restrict__ xdbl,
                        const float* __restrict__ xc, const float* __restrict__ alogs,
                        float* __restrict__ S, float* __restrict__ P) {
  int bx = blockIdx.x;
  int c = bx / NDB, dblk = bx % NDB;
  int k = blockIdx.y, b = blockIdx.z;
  int t = threadIdx.x, dl = t >> 4, n = t & 15;
  int d = dblk * 16 + dl;
  float A = -expf(alogs[(size_t)(k * DIv + d) * DSn + n]);
  size_t bkL = (size_t)(b * KKv + k) * LL;
  const float* dp = delta + bkL * DIv + d;
  const float* xq = xdbl + bkL * 38;
  const float* xcb = xc + (size_t)b * LL * DIv + d;
  float h = 0.f, sA = 0.f;
  int l0 = c * CHK;
  for (int i = 0; i < CHK; ++i) {
    int l = l0 + i;
    float de = dp[(size_t)l * DIv];
    float Bv = xq[(size_t)l * 38 + 6 + n];
    float xv = xcb[(size_t)lmap(k, l) * DIv];
    float u = de * A;
    sA += u;
    h = h * expf(u) + de * xv * Bv;
  }
  size_t o = (((size_t)(b * KKv + k) * NC + c) * NDB + dblk) * 256 + t;
  S[o] = h;
  P[o] = expf(sA);
}

// K4b: sequential chunk combine. Rewrites S[c] <- Hin[c] (state entering chunk c).
__global__ void k_scan2(float* __restrict__ S, const float* __restrict__ P) {
  int dblk = blockIdx.x, k = blockIdx.y, b = blockIdx.z;
  int t = threadIdx.x;  // 256
  size_t base = ((size_t)(b * KKv + k) * NC) * (NDB * 256) + (size_t)dblk * 256 + t;
  float h = 0.f;
  for (int c = 0; c < NC; ++c) {
    size_t o = base + (size_t)c * (NDB * 256);
    float s = S[o], p = P[o];
    S[o] = h;  // Hin for chunk c
    h = s + p * h;
  }
}

// K4c: chunked scan pass 3 — exact recurrence from Hin, emit y.
__global__ void k_scan3(const float* __restrict__ delta, const float* __restrict__ xdbl,
                        const float* __restrict__ xc, const float* __restrict__ alogs,
                        const float* __restrict__ Hin, float* __restrict__ ys) {
  int bx = blockIdx.x;
  int c = bx / NDB, dblk = bx % NDB;
  int k = blockIdx.y, b = blockIdx.z;
  int t = threadIdx.x, dl = t >> 4, n = t & 15;
  int d = dblk * 16 + dl;
  float A = -expf(alogs[(size_t)(k * DIv + d) * DSn + n]);
  size_t bkL = (size_t)(b * KKv + k) * LL;
  const float* dp = delta + bkL * DIv + d;
  const float* xq = xdbl + bkL * 38;
  const float* xcb = xc + (size_t)b * LL * DIv + d;
  float* yp = ys + bkL * DIv + d;
  size_t o = (((size_t)(b * KKv + k) * NC + c) * NDB + dblk) * 256 + t;
  float h = Hin[o];
  int l0 = c * CHK;
  for (int i = 0; i < CHK; ++i) {
    int l = l0 + i;
    float de = dp[(size_t)l * DIv];
    float Bv = xq[(size_t)l * 38 + 6 + n];
    float Cv = xq[(size_t)l * 38 + 22 + n];
    float xv = xcb[(size_t)lmap(k, l) * DIv];
    h = h * expf(de * A) + de * xv * Bv;
    float p = h * Cv;
    p += __shfl_down(p, 8, 16);
    p += __shfl_down(p, 4, 16);
    p += __shfl_down(p, 2, 16);
    p += __shfl_down(p, 1, 16);
    if (n == 0) yp[(size_t)l * DIv] = p;
  }
}

// K5: merge 4 directions + D*x skip, output yg[b,l,d]
__global__ void k_combine(const float* __restrict__ ys, const float* __restrict__ xc,
                          const float* __restrict__ Ds, float* __restrict__ yg) {
  size_t idx = (size_t)blockIdx.x * 256 + threadIdx.x;  // B*L*DI
  int d = (int)(idx % DIv);
  int l = (int)((idx / DIv) % LL);
  int b = (int)(idx / ((size_t)DIv * LL));
  int lT = ((l & 63) << 6) | (l >> 6);
  size_t base = (size_t)b * KKv * LL * DIv;
  float v = ys[base + ((size_t)0 * LL + l) * DIv + d]
          + ys[base + ((size_t)2 * LL + (LL - 1 - l)) * DIv + d]
          + ys[base + ((size_t)1 * LL + lT) * DIv + d]
          + ys[base + ((size_t)3 * LL + (LL - 1 - lT)) * DIv + d];
  float sd = Ds[d] + Ds[DIv + d] + Ds[2 * DIv + d] + Ds[3 * DIv + d];
  v += sd * xc[((size_t)b * LL + l) * DIv + d];
  yg[idx] = v;
}

// K6: LayerNorm(DI) * silu(z)
__global__ void k_lngate(const float* __restrict__ yg, const float* __restrict__ z,
                         const float* __restrict__ g, const float* __restrict__ be,
                         float* __restrict__ out) {
  int bl = blockIdx.x;
  int t = threadIdx.x;  // 64
  const float* yr = yg + (size_t)bl * DIv;
  float v[3];
  float s = 0.f, q = 0.f;
#pragma unroll
  for (int cc = 0; cc < 3; ++cc) { v[cc] = yr[t + cc * 64]; s += v[cc]; q += v[cc] * v[cc]; }
#pragma unroll
  for (int o = 32; o > 0; o >>= 1) { s += __shfl_xor(s, o, 64); q += __shfl_xor(q, o, 64); }
  float m = s / DIv;
  float var = q / DIv - m * m;
  float rs = rsqrtf(var + 1e-5f);
  const float* zr = z + (size_t)bl * DIv;
  float* orow = out + (size_t)bl * DIv;
#pragma unroll
  for (int cc = 0; cc < 3; ++cc) {
    int d = t + cc * 64;
    float zz = zr[d];
    float val = (v[cc] - m) * rs * g[d] + be[d];
    orow[d] = val * zz * sigf(zz);
  }
}

// K7: out0 = ygated @ out_proj_w.T via ygtT/opwT. 4 cols/block, lanes = rows.
__global__ void k_outproj2(const float* __restrict__ ygtT, const float* __restrict__ opwT,
                           float* __restrict__ out0) {
  int t = threadIdx.x;                    // 256
  int rq = blockIdx.x * 256 + t;          // f4-row index
  int c0 = blockIdx.y * 4;
  const float4* x4 = (const float4*)ygtT;
  float4 acc[4];
#pragma unroll
  for (int c = 0; c < 4; ++c) acc[c] = make_float4(0.f, 0.f, 0.f, 0.f);
  for (int k = 0; k < DIv; ++k) {
    float4 xv = x4[(size_t)k * (NR / 4) + rq];
    const float* wr = opwT + k * DMv + c0;  // wave-uniform
#pragma unroll
    for (int c = 0; c < 4; ++c) {
      float w = wr[c];
      acc[c].x += w * xv.x; acc[c].y += w * xv.y;
      acc[c].z += w * xv.z; acc[c].w += w * xv.w;
    }
  }
#pragma unroll
  for (int li = 0; li < 4; ++li) {
    float4 v;
    v.x = (&acc[0].x)[li]; v.y = (&acc[1].x)[li];
    v.z = (&acc[2].x)[li]; v.w = (&acc[3].x)[li];
    *(float4*)(out0 + ((size_t)rq * 4 + li) * DMv + c0) = v;
  }
}

// K8: hcl = silu(ygated @ ffn_in_w.T + b) via ygtT/fiwT. 16 cols/block.
__global__ void k_ffnin2(const float* __restrict__ ygtT, const float* __restrict__ fiwT,
                         const float* __restrict__ bias, float* __restrict__ hcl) {
  int t = threadIdx.x;                    // 256
  int rq = blockIdx.x * 256 + t;
  int c0 = blockIdx.y * 16;
  const float4* x4 = (const float4*)ygtT;
  float4 acc[16];
#pragma unroll
  for (int c = 0; c < 16; ++c) acc[c] = make_float4(0.f, 0.f, 0.f, 0.f);
  for (int k = 0; k < DIv; ++k) {
    float4 xv = x4[(size_t)k * (NR / 4) + rq];
    const float* wr = fiwT + k * HIDv + c0;  // wave-uniform
#pragma unroll
    for (int c = 0; c < 16; ++c) {
      float w = wr[c];
      acc[c].x += w * xv.x; acc[c].y += w * xv.y;
      acc[c].z += w * xv.z; acc[c].w += w * xv.w;
    }
  }
#pragma unroll
  for (int li = 0; li < 4; ++li) {
    size_t row = (size_t)rq * 4 + li;
#pragma unroll
    for (int cc = 0; cc < 4; ++cc) {
      float4 v;
#pragma unroll
      for (int j = 0; j < 4; ++j) {
        float s = (&acc[cc * 4 + j].x)[li] + bias[c0 + cc * 4 + j];
        (&v.x)[j] = s * sigf(s);
      }
      *(float4*)(hcl + row * HIDv + c0 + cc * 4) = v;
    }
  }
}

// K9 (tiled): hc2 = (1 + w1)*hc(center) + dwconv3(hc) + dwconv5(hc), fused 5x5 stencil.
constexpr int TS = 16, CG = 32, TW = TS + 4;  // TW=20
__global__ void k_ffnconv(const float* __restrict__ hcl, const float* __restrict__ w1,
                          const float* __restrict__ w3, const float* __restrict__ w5,
                          float* __restrict__ hc2) {
  int tile = blockIdx.x;            // 0..15 (4x4 spatial tiles)
  int cg = blockIdx.y, b = blockIdx.z;
  int t = threadIdx.x;              // 256
  int ti0 = (tile >> 2) * TS, tj0 = (tile & 3) * TS;
  __shared__ float sm[TW * TW * CG];

  for (int e = t; e < TW * TW * CG; e += 256) {
    int ec = e & 31;
    int sp = e >> 5;                // 0..399
    int hi = sp / TW, hj = sp % TW;
    int gi = ti0 + hi - 2, gj = tj0 + hj - 2;
    float v = 0.f;
    if ((unsigned)gi < (unsigned)HH && (unsigned)gj < (unsigned)WW)
      v = hcl[((size_t)b * LL + gi * WW + gj) * HIDv + cg * CG + ec];
    sm[e] = v;
  }

  int c = t & 31;
  int cglob = cg * CG + c;
  float wc[25];
#pragma unroll
  for (int di = 0; di < 5; ++di)
#pragma unroll
    for (int dj = 0; dj < 5; ++dj) {
      float w = w5[cglob * 25 + di * 5 + dj];
      if (di >= 1 && di <= 3 && dj >= 1 && dj <= 3)
        w += w3[cglob * 9 + (di - 1) * 3 + (dj - 1)];
      if (di == 2 && dj == 2) w += 1.f + w1[cglob];
      wc[di * 5 + dj] = w;
    }
  __syncthreads();

  int s0 = t >> 5;  // 0..7
  for (int i = 0; i < 32; ++i) {
    int p = s0 + (i << 3);          // 0..255
    int r = p >> 4, q = p & 15;
    float s = 0.f;
#pragma unroll
    for (int di = 0; di < 5; ++di)
#pragma unroll
      for (int dj = 0; dj < 5; ++dj)
        s += sm[((r + di) * TW + (q + dj)) * CG + c] * wc[di * 5 + dj];
    hc2[((size_t)b * LL + (ti0 + r) * WW + (tj0 + q)) * HIDv + cglob] = s;
  }
}

// K10: LayerNorm over HID
__global__ void k_ln2(const float* __restrict__ hc2, const float* __restrict__ g,
                      const float* __restrict__ be, float* __restrict__ hn) {
  int bl = blockIdx.x;
  int t = threadIdx.x;  // 256
  const float* xr = hc2 + (size_t)bl * HIDv;
  float v[3];
  float s = 0.f, q = 0.f;
#pragma unroll
  for (int cc = 0; cc < 3; ++cc) { v[cc] = xr[t + cc * 256]; s += v[cc]; q += v[cc] * v[cc]; }
#pragma unroll
  for (int o = 32; o > 0; o >>= 1) { s += __shfl_xor(s, o, 64); q += __shfl_xor(q, o, 64); }
  __shared__ float rs_[4], rq_[4];
  int wid = t >> 6;
  if ((t & 63) == 0) { rs_[wid] = s; rq_[wid] = q; }
  __syncthreads();
  s = rs_[0] + rs_[1] + rs_[2] + rs_[3];
  q = rq_[0] + rq_[1] + rq_[2] + rq_[3];
  float m = s / HIDv;
  float var = q / HIDv - m * m;
  float r = rsqrtf(var + 1e-5f);
#pragma unroll
  for (int cc = 0; cc < 3; ++cc) {
    int c = t + cc * 256;
    hn[(size_t)bl * HIDv + c] = (v[cc] - m) * r * g[c] + be[c];
  }
}

// K11: d_out = out0 + skip * (hn @ ffn_out_w.T + b) via hnT/fowT. 8 cols/block, block 128.
__global__ void k_final2(const float* __restrict__ hnT, const float* __restrict__ fowT,
                         const float* __restrict__ bias, const float* __restrict__ out0,
                         const float* __restrict__ skip, float* __restrict__ dout) {
  int t = threadIdx.x;                    // 128
  int rq = blockIdx.x * 128 + t;          // f4-row
  int c0 = blockIdx.y * 8;
  const float4* x4 = (const float4*)hnT;
  float4 acc[8];
#pragma unroll
  for (int c = 0; c < 8; ++c) acc[c] = make_float4(0.f, 0.f, 0.f, 0.f);
  for (int k = 0; k < HIDv; ++k) {
    float4 xv = x4[(size_t)k * (NR / 4) + rq];
    const float* wr = fowT + k * DMv + c0;  // wave-uniform
#pragma unroll
    for (int c = 0; c < 8; ++c) {
      float w = wr[c];
      acc[c].x += w * xv.x; acc[c].y += w * xv.y;
      acc[c].z += w * xv.z; acc[c].w += w * xv.w;
    }
  }
  float sk = skip[0];
#pragma unroll
  for (int li = 0; li < 4; ++li) {
    size_t row = (size_t)rq * 4 + li;
#pragma unroll
    for (int cc = 0; cc < 2; ++cc) {
      float4 v;
#pragma unroll
      for (int j = 0; j < 4; ++j) {
        int c = c0 + cc * 4 + j;
        (&v.x)[j] = out0[row * DMv + c] + sk * ((&acc[cc * 4 + j].x)[li] + bias[c]);
      }
      *(float4*)(dout + row * DMv + c0 + cc * 4) = v;
    }
  }
}

extern "C" void kernel_launch(void* const* d_in, const int* in_sizes, int n_in,
                              void* d_out, int out_size, void* d_ws, size_t ws_size,
                              hipStream_t stream) {
  const float* x        = (const float*)d_in[0];
  const float* in_w     = (const float*)d_in[1];
  const float* conv_w   = (const float*)d_in[2];
  const float* conv_b   = (const float*)d_in[3];
  const float* xpw      = (const float*)d_in[4];
  const float* dtw      = (const float*)d_in[5];
  const float* dtb      = (const float*)d_in[6];
  const float* alogs    = (const float*)d_in[7];
  const float* Ds       = (const float*)d_in[8];
  const float* ong      = (const float*)d_in[9];
  const float* onb      = (const float*)d_in[10];
  const float* opw      = (const float*)d_in[11];
  const float* fiw      = (const float*)d_in[12];
  const float* fib      = (const float*)d_in[13];
  const float* dw1      = (const float*)d_in[14];
  const float* dw3      = (const float*)d_in[15];
  const float* dw5      = (const float*)d_in[16];
  const float* flg      = (const float*)d_in[17];
  const float* flb      = (const float*)d_in[18];
  const float* fow      = (const float*)d_in[19];
  const float* fob      = (const float*)d_in[20];
  const float* skip     = (const float*)d_in[21];

  // Workspace layout (aliased; ~149.3 MB; round-1 proved ws >= 180 MB)
  float* ws    = (float*)d_ws;
  float* xi    = ws;                 // -> S/P during scan -> yg -> ygtT
  float* z     = xi + S_xi;
  float* xc    = z + S_xi;           // -> ygt
  float* xdbl  = xc + S_xi;          // -> out0
  float* delta = xdbl + S_xdbl;      // xt/wt scratch -> delta -> hcl -> hn
  float* ys    = delta + S_big;      // -> hc2 -> hnT
  float* wtiny = ys + S_big;         // persistent small weight transposes
  float* fiwT  = wtiny;              // 192*768 = 147456
  float* opwT  = fiwT + 147456;      // 192*96  = 18432
  float* fowT  = opwT + 18432;       // 768*96  = 73728

  // Small weight transposes (persist whole launch)
  k_transp<<<dim3(24, 6), 256, 0, stream>>>(fiw, fiwT, HIDv, DIv);   // 768x192 -> 192x768
  k_transp<<<dim3(3, 6), 256, 0, stream>>>(opw, opwT, DMv, DIv);     // 96x192  -> 192x96
  k_transp<<<dim3(3, 24), 256, 0, stream>>>(fow, fowT, DMv, HIDv);   // 96x768  -> 768x96

  // In-proj via transposed operands (xt, wt live in the not-yet-used delta region)
  float* xt = delta;                       // 96*16384 floats
  float* wt = delta + 1600000;             // 36,864 floats (within S_big)
  k_wt<<<(96 * 384 + 255) / 256, 256, 0, stream>>>(in_w, wt);
  dim3 gxt(NR / 64, 3);
  k_xt<<<gxt, 256, 0, stream>>>(x, xt);
  dim3 gip(NR / 1024, 48);
  k_inproj<<<gip, 256, 0, stream>>>(xt, wt, xi, z);

  k_dwconv<<<(BB * LL * DIv) / 256, 256, 0, stream>>>(xi, conv_w, conv_b, xc);
  dim3 g3(LL, KKv, BB);
  k_xdbl<<<g3, 64, 0, stream>>>(xc, xpw, xdbl);
  k_delta<<<(BB * KKv * LL * DIv) / 256, 256, 0, stream>>>(xdbl, dtw, dtb, delta);

  // Chunked scan: S/P buffers alias xi (dead until k_combine writes yg there)
  float* Sbuf = xi;                  // S_sp floats
  float* Pbuf = xi + S_sp;           // S_sp floats (S_sp*2 == S_xi exactly)
  dim3 gs13(NC * NDB, KKv, BB);      // 6144 blocks
  dim3 gs2(NDB, KKv, BB);            // 192 blocks (tiny)
  k_scan1<<<gs13, 256, 0, stream>>>(delta, xdbl, xc, alogs, Sbuf, Pbuf);
  k_scan2<<<gs2, 256, 0, stream>>>(Sbuf, Pbuf);  // S <- Hin
  k_scan3<<<gs13, 256, 0, stream>>>(delta, xdbl, xc, alogs, Sbuf, ys);

  float* yg = xi;  // overwrites S/P (dead after k_scan3)
  k_combine<<<(BB * LL * DIv) / 256, 256, 0, stream>>>(ys, xc, Ds, yg);
  float* ygt = xc;
  k_lngate<<<BB * LL, 64, 0, stream>>>(yg, z, ong, onb, ygt);

  // Transpose ygt (16384x192 -> 192x16384) into xi (yg dead)
  float* ygtT = xi;
  k_transp<<<dim3(512, 6), 256, 0, stream>>>(ygt, ygtT, NR, DIv);

  float* out0 = xdbl;
  dim3 gop(NR / 1024, DMv / 4);      // (16, 24)
  k_outproj2<<<gop, 256, 0, stream>>>(ygtT, opwT, out0);
  float* hcl = delta;
  dim3 gfi(NR / 1024, HIDv / 16);    // (16, 48)
  k_ffnin2<<<gfi, 256, 0, stream>>>(ygtT, fiwT, fib, hcl);
  float* hc2 = ys;
  dim3 gc(16, HIDv / CG, BB);        // 16 spatial tiles x 24 ch-groups x 4
  k_ffnconv<<<gc, 256, 0, stream>>>(hcl, dw1, dw3, dw5, hc2);
  float* hn = delta;  // hcl dead after k_ffnconv
  k_ln2<<<BB * LL, 256, 0, stream>>>(hc2, flg, flb, hn);

  // Transpose hn (16384x768 -> 768x16384) into ys (hc2 dead)
  float* hnT = ys;
  k_transp<<<dim3(512, 24), 256, 0, stream>>>(hn, hnT, NR, HIDv);

  dim3 gfn(NR / 512, DMv / 8);       // (32, 12), block 128
  k_final2<<<gfn, 128, 0, stream>>>(hnT, fowT, fob, out0, skip, (float*)d_out);
}

// Round 8
// 919.695 us; speedup vs baseline: 1.9783x; 1.1655x over previous
//
#include <hip/hip_runtime.h>
#include <hip/hip_bf16.h>

constexpr int BB = 4, HH = 64, WW = 64, DMv = 96;
constexpr int DSn = 16, DIv = 192, DTRv = 6, KKv = 4, HIDv = 768;
constexpr int LL = 4096;
constexpr int NC = 32, CHK = LL / NC;       // 32 chunks of 128
constexpr int NDB = DIv / 16;               // 12 d-blocks of 16 channels
constexpr int NR = BB * LL;                 // 16384 rows

constexpr size_t S_xi   = (size_t)BB * LL * DIv;          // 3,145,728
constexpr size_t S_xdbl = (size_t)BB * KKv * LL * 38;     // 2,490,368
constexpr size_t S_big  = (size_t)BB * KKv * LL * DIv;    // 12,582,912
constexpr size_t S_sp   = (size_t)BB * KKv * NC * DIv * DSn;  // 1,572,864 (= S_xi/2)

__device__ __forceinline__ float sigf(float x) { return 1.f / (1.f + expf(-x)); }
__device__ __forceinline__ float dot4(float4 a, float4 b) {
  return a.x * b.x + a.y * b.y + a.z * b.z + a.w * b.w;
}

__device__ __forceinline__ int lmap(int k, int l) {
  int lr = (k & 2) ? (LL - 1 - l) : l;
  return (k & 1) ? (((lr & 63) << 6) | (lr >> 6)) : lr;
}

// Generic 32x32 LDS tile transpose: src[R][C] -> dst[C][R], both coalesced.
__global__ void k_transp(const float* __restrict__ src, float* __restrict__ dst,
                         int R, int C) {
  __shared__ float tile[32][33];
  int r0 = blockIdx.x * 32, c0 = blockIdx.y * 32;
  int t = threadIdx.x;            // 256
  int tc = t & 31, tr = t >> 5;   // tr 0..7
#pragma unroll
  for (int i = 0; i < 4; ++i) {
    int r = r0 + tr + i * 8;
    if (r < R && c0 + tc < C) tile[tr + i * 8][tc] = src[(size_t)r * C + c0 + tc];
  }
  __syncthreads();
#pragma unroll
  for (int i = 0; i < 4; ++i) {
    int c = c0 + tr + i * 8;
    int r = r0 + tc;
    if (c < C && r < R) dst[(size_t)c * R + r] = tile[tc][tr + i * 8];
  }
}

// K0a: wt[k][c] = in_proj_w[c][k]  (96 x 384)
__global__ void k_wt(const float* __restrict__ w, float* __restrict__ wt) {
  int idx = blockIdx.x * 256 + threadIdx.x;  // 36864
  if (idx < 96 * 384) {
    int k = idx / 384, c = idx % 384;
    wt[idx] = w[c * 96 + k];
  }
}

// K0b: xt[k][row] = x[row][k]  (96 x 16384), 64x32 LDS tile transpose
__global__ void k_xt(const float* __restrict__ x, float* __restrict__ xt) {
  __shared__ float tile[32][65];
  int r0 = blockIdx.x * 64, k0 = blockIdx.y * 32;
  int t = threadIdx.x;  // 256
#pragma unroll
  for (int ii = 0; ii < 8; ++ii) {
    int i = (t >> 5) + ii * 8, j = t & 31;
    tile[j][i] = x[(size_t)(r0 + i) * 96 + k0 + j];
  }
  __syncthreads();
#pragma unroll
  for (int jj = 0; jj < 8; ++jj) {
    int j = (t >> 6) + jj * 4, i = t & 63;
    xt[(size_t)(k0 + j) * NR + r0 + i] = tile[j][i];
  }
}

// K1: xz = x @ in_proj_w.T via xt/wt. Lane = 4 rows (f4, coalesced), wave-uniform
// scalar weight loads.
__global__ void k_inproj(const float* __restrict__ xt, const float* __restrict__ wt,
                         float* __restrict__ xi, float* __restrict__ z) {
  int t = threadIdx.x;
  int wv = t >> 6, lane = t & 63;
  int rq = blockIdx.x * 256 + wv * 64 + lane;   // float4-row index (row = rq*4)
  int c0 = blockIdx.y * 8;
  const float4* xt4 = (const float4*)xt;
  float4 acc[8];
#pragma unroll
  for (int c = 0; c < 8; ++c) acc[c] = make_float4(0.f, 0.f, 0.f, 0.f);
  for (int k = 0; k < 96; ++k) {
    float4 xv = xt4[(size_t)k * (NR / 4) + rq];
    const float* wr = wt + k * 384 + c0;  // wave-uniform -> s_load
#pragma unroll
    for (int c = 0; c < 8; ++c) {
      float w = wr[c];
      acc[c].x += w * xv.x; acc[c].y += w * xv.y;
      acc[c].z += w * xv.z; acc[c].w += w * xv.w;
    }
  }
  float* dst; int cc;
  if (c0 < DIv) { dst = xi; cc = c0; } else { dst = z; cc = c0 - DIv; }
#pragma unroll
  for (int li = 0; li < 4; ++li) {
    size_t row = (size_t)rq * 4 + li;
    float4 v0, v1;
    v0.x = (&acc[0].x)[li]; v0.y = (&acc[1].x)[li];
    v0.z = (&acc[2].x)[li]; v0.w = (&acc[3].x)[li];
    v1.x = (&acc[4].x)[li]; v1.y = (&acc[5].x)[li];
    v1.z = (&acc[6].x)[li]; v1.w = (&acc[7].x)[li];
    float4* o4 = (float4*)(dst + row * DIv + cc);
    o4[0] = v0; o4[1] = v1;
  }
}

// K2: xc = silu(dwconv3x3(xi) + conv_b), channel-last
__global__ void k_dwconv(const float* __restrict__ xi, const float* __restrict__ cw,
                         const float* __restrict__ cb, float* __restrict__ xc) {
  size_t idx = (size_t)blockIdx.x * 256 + threadIdx.x;  // B*L*DI
  int d = (int)(idx % DIv);
  int l = (int)((idx / DIv) % LL);
  int b = (int)(idx / ((size_t)DIv * LL));
  int i = l >> 6, j = l & 63;
  float s = cb[d];
#pragma unroll
  for (int di = 0; di < 3; ++di) {
    int ii = i + di - 1;
    if ((unsigned)ii >= (unsigned)HH) continue;
#pragma unroll
    for (int dj = 0; dj < 3; ++dj) {
      int jj = j + dj - 1;
      if ((unsigned)jj >= (unsigned)WW) continue;
      s += xi[((size_t)b * LL + ii * WW + jj) * DIv + d] * cw[d * 9 + di * 3 + dj];
    }
  }
  xc[idx] = s * sigf(s);
}

// K3pre-a: spatial transpose per (d,b): xcTs[d][b][j*64+i] = xcT[d][b][i*64+j]
__global__ void k_spt(const float* __restrict__ xcT, float* __restrict__ xcTs) {
  __shared__ float tile[64][65];
  int d = blockIdx.x >> 2, b = blockIdx.x & 3;
  int t = threadIdx.x;  // 256
  const float* src = xcT + (size_t)d * NR + b * LL;
  float* dst = xcTs + (size_t)d * NR + b * LL;
#pragma unroll
  for (int it = 0; it < 16; ++it) {
    int idx = it * 256 + t;
    tile[idx >> 6][idx & 63] = src[idx];
  }
  __syncthreads();
#pragma unroll
  for (int it = 0; it < 16; ++it) {
    int idx = it * 256 + t;
    dst[idx] = tile[idx & 63][idx >> 6];
  }
}

// K3pre-b: wcatT[p][d][76]: cols 0..37 = w_{k=p}[c][d], 38..75 = w_{k=p+2}[c][d]
__global__ void k_wcat(const float* __restrict__ xpw, float* __restrict__ wcatT) {
  int idx = blockIdx.x * 256 + threadIdx.x;  // 2*192*76 = 29184
  if (idx < 2 * 192 * 76) {
    int p = idx / (192 * 76);
    int rem = idx % (192 * 76);
    int d = rem / 76, j = rem % 76;
    int k = (j >= 38 ? 2 : 0) + p;
    int c = (j >= 38) ? j - 38 : j;
    wcatT[idx] = xpw[((size_t)(k * 38 + c)) * DIv + d];
  }
}

// K3a: x_dbl via transposed operands. Pair p=0: k0 (fwd) + k2 (reversed) from xcT;
// p=1: k1 (fwd) + k3 (reversed) from xcTs. Lanes = f4 row-quads, 4 cols/thread.
__global__ void k_xdbl2(const float* __restrict__ xcT, const float* __restrict__ xcTs,
                        const float* __restrict__ wcatT, float* __restrict__ xdbl) {
  int t = threadIdx.x;                  // 256
  int rq = blockIdx.x * 256 + t;        // 0..1023 f4-row within b
  int jg = blockIdx.y;                  // 0..18 -> cols jg*4..jg*4+3
  int pb = blockIdx.z;                  // p*4 + b
  int p = pb >> 2, b = pb & 3;
  const float4* A = (const float4*)(p ? xcTs : xcT);
  const float* wbase = wcatT + (size_t)p * 192 * 76 + jg * 4;
  float4 acc[4];
#pragma unroll
  for (int j = 0; j < 4; ++j) acc[j] = make_float4(0.f, 0.f, 0.f, 0.f);
  for (int d = 0; d < 192; ++d) {
    float4 xv = A[(size_t)d * (NR / 4) + b * 1024 + rq];
    const float* wr = wbase + d * 76;   // wave-uniform -> s_load
#pragma unroll
    for (int j = 0; j < 4; ++j) {
      float w = wr[j];
      acc[j].x += w * xv.x; acc[j].y += w * xv.y;
      acc[j].z += w * xv.z; acc[j].w += w * xv.w;
    }
  }
#pragma unroll
  for (int li = 0; li < 4; ++li) {
    int r = rq * 4 + li;
#pragma unroll
    for (int j = 0; j < 4; ++j) {
      int col = jg * 4 + j;
      int kk = (col >= 38) ? (2 + p) : p;
      int c = (col >= 38) ? col - 38 : col;
      int l = (col >= 38) ? (LL - 1 - r) : r;
      xdbl[(((size_t)(b * KKv + kk)) * LL + l) * 38 + c] = (&acc[j].x)[li];
    }
  }
}

// K3b: delta[b,k,l,d] = softplus(dts @ dt_projs_w + dt_projs_b)
__global__ void k_delta(const float* __restrict__ xdbl, const float* __restrict__ dtw,
                        const float* __restrict__ dtb, float* __restrict__ delta) {
  size_t idx = (size_t)blockIdx.x * 256 + threadIdx.x;  // B*K*L*DI
  int d = (int)(idx % DIv);
  size_t bkl = idx / DIv;              // (b*K+k)*L + l
  int k = (int)((bkl / LL) % KKv);
  const float* xr = xdbl + bkl * 38;
  const float* wr = dtw + ((size_t)k * DIv + d) * DTRv;
  float s = dtb[k * DIv + d];
#pragma unroll
  for (int r = 0; r < DTRv; ++r) s += xr[r] * wr[r];
  delta[idx] = (s > 20.f) ? s : log1pf(expf(s));
}

// K4a: chunked scan pass 1 — per-chunk local final state S and decay product P.
__global__ void k_scan1(const float* __restrict__ delta, const float* __restrict__ xdbl,
                        const float* __restrict__ xc, const float* __restrict__ alogs,
                        float* __restrict__ S, float* __restrict__ P) {
  int bx = blockIdx.x;
  int c = bx / NDB, dblk = bx % NDB;
  int k = blockIdx.y, b = blockIdx.z;
  int t = threadIdx.x, dl = t >> 4, n = t & 15;
  int d = dblk * 16 + dl;
  float A = -expf(alogs[(size_t)(k * DIv + d) * DSn + n]);
  size_t bkL = (size_t)(b * KKv + k) * LL;
  const float* dp = delta + bkL * DIv + d;
  const float* xq = xdbl + bkL * 38;
  const float* xcb = xc + (size_t)b * LL * DIv + d;
  float h = 0.f, sA = 0.f;
  int l0 = c * CHK;
  for (int i = 0; i < CHK; ++i) {
    int l = l0 + i;
    float de = dp[(size_t)l * DIv];
    float Bv = xq[(size_t)l * 38 + 6 + n];
    float xv = xcb[(size_t)lmap(k, l) * DIv];
    float u = de * A;
    sA += u;
    h = h * expf(u) + de * xv * Bv;
  }
  size_t o = (((size_t)(b * KKv + k) * NC + c) * NDB + dblk) * 256 + t;
  S[o] = h;
  P[o] = expf(sA);
}

// K4b: sequential chunk combine. Rewrites S[c] <- Hin[c] (state entering chunk c).
__global__ void k_scan2(float* __restrict__ S, const float* __restrict__ P) {
  int dblk = blockIdx.x, k = blockIdx.y, b = blockIdx.z;
  int t = threadIdx.x;  // 256
  size_t base = ((size_t)(b * KKv + k) * NC) * (NDB * 256) + (size_t)dblk * 256 + t;
  float h = 0.f;
  for (int c = 0; c < NC; ++c) {
    size_t o = base + (size_t)c * (NDB * 256);
    float s = S[o], p = P[o];
    S[o] = h;  // Hin for chunk c
    h = s + p * h;
  }
}

// K4c: chunked scan pass 3 — exact recurrence from Hin, emit y.
__global__ void k_scan3(const float* __restrict__ delta, const float* __restrict__ xdbl,
                        const float* __restrict__ xc, const float* __restrict__ alogs,
                        const float* __restrict__ Hin, float* __restrict__ ys) {
  int bx = blockIdx.x;
  int c = bx / NDB, dblk = bx % NDB;
  int k = blockIdx.y, b = blockIdx.z;
  int t = threadIdx.x, dl = t >> 4, n = t & 15;
  int d = dblk * 16 + dl;
  float A = -expf(alogs[(size_t)(k * DIv + d) * DSn + n]);
  size_t bkL = (size_t)(b * KKv + k) * LL;
  const float* dp = delta + bkL * DIv + d;
  const float* xq = xdbl + bkL * 38;
  const float* xcb = xc + (size_t)b * LL * DIv + d;
  float* yp = ys + bkL * DIv + d;
  size_t o = (((size_t)(b * KKv + k) * NC + c) * NDB + dblk) * 256 + t;
  float h = Hin[o];
  int l0 = c * CHK;
  for (int i = 0; i < CHK; ++i) {
    int l = l0 + i;
    float de = dp[(size_t)l * DIv];
    float Bv = xq[(size_t)l * 38 + 6 + n];
    float Cv = xq[(size_t)l * 38 + 22 + n];
    float xv = xcb[(size_t)lmap(k, l) * DIv];
    h = h * expf(de * A) + de * xv * Bv;
    float p = h * Cv;
    p += __shfl_down(p, 8, 16);
    p += __shfl_down(p, 4, 16);
    p += __shfl_down(p, 2, 16);
    p += __shfl_down(p, 1, 16);
    if (n == 0) yp[(size_t)l * DIv] = p;
  }
}

// K5: merge 4 directions + D*x skip, output yg[b,l,d]
__global__ void k_combine(const float* __restrict__ ys, const float* __restrict__ xc,
                          const float* __restrict__ Ds, float* __restrict__ yg) {
  size_t idx = (size_t)blockIdx.x * 256 + threadIdx.x;  // B*L*DI
  int d = (int)(idx % DIv);
  int l = (int)((idx / DIv) % LL);
  int b = (int)(idx / ((size_t)DIv * LL));
  int lT = ((l & 63) << 6) | (l >> 6);
  size_t base = (size_t)b * KKv * LL * DIv;
  float v = ys[base + ((size_t)0 * LL + l) * DIv + d]
          + ys[base + ((size_t)2 * LL + (LL - 1 - l)) * DIv + d]
          + ys[base + ((size_t)1 * LL + lT) * DIv + d]
          + ys[base + ((size_t)3 * LL + (LL - 1 - lT)) * DIv + d];
  float sd = Ds[d] + Ds[DIv + d] + Ds[2 * DIv + d] + Ds[3 * DIv + d];
  v += sd * xc[((size_t)b * LL + l) * DIv + d];
  yg[idx] = v;
}

// K6: LayerNorm(DI) * silu(z)
__global__ void k_lngate(const float* __restrict__ yg, const float* __restrict__ z,
                         const float* __restrict__ g, const float* __restrict__ be,
                         float* __restrict__ out) {
  int bl = blockIdx.x;
  int t = threadIdx.x;  // 64
  const float* yr = yg + (size_t)bl * DIv;
  float v[3];
  float s = 0.f, q = 0.f;
#pragma unroll
  for (int cc = 0; cc < 3; ++cc) { v[cc] = yr[t + cc * 64]; s += v[cc]; q += v[cc] * v[cc]; }
#pragma unroll
  for (int o = 32; o > 0; o >>= 1) { s += __shfl_xor(s, o, 64); q += __shfl_xor(q, o, 64); }
  float m = s / DIv;
  float var = q / DIv - m * m;
  float rs = rsqrtf(var + 1e-5f);
  const float* zr = z + (size_t)bl * DIv;
  float* orow = out + (size_t)bl * DIv;
#pragma unroll
  for (int cc = 0; cc < 3; ++cc) {
    int d = t + cc * 64;
    float zz = zr[d];
    float val = (v[cc] - m) * rs * g[d] + be[d];
    orow[d] = val * zz * sigf(zz);
  }
}

// K7: out0 = ygated @ out_proj_w.T via ygtT/opwT. 4 cols/block, lanes = rows.
__global__ void k_outproj2(const float* __restrict__ ygtT, const float* __restrict__ opwT,
                           float* __restrict__ out0) {
  int t = threadIdx.x;                    // 256
  int rq = blockIdx.x * 256 + t;          // f4-row index
  int c0 = blockIdx.y * 4;
  const float4* x4 = (const float4*)ygtT;
  float4 acc[4];
#pragma unroll
  for (int c = 0; c < 4; ++c) acc[c] = make_float4(0.f, 0.f, 0.f, 0.f);
  for (int k = 0; k < DIv; ++k) {
    float4 xv = x4[(size_t)k * (NR / 4) + rq];
    const float* wr = opwT + k * DMv + c0;  // wave-uniform
#pragma unroll
    for (int c = 0; c < 4; ++c) {
      float w = wr[c];
      acc[c].x += w * xv.x; acc[c].y += w * xv.y;
      acc[c].z += w * xv.z; acc[c].w += w * xv.w;
    }
  }
#pragma unroll
  for (int li = 0; li < 4; ++li) {
    float4 v;
    v.x = (&acc[0].x)[li]; v.y = (&acc[1].x)[li];
    v.z = (&acc[2].x)[li]; v.w = (&acc[3].x)[li];
    *(float4*)(out0 + ((size_t)rq * 4 + li) * DMv + c0) = v;
  }
}

// K8: hcl = silu(ygated @ ffn_in_w.T + b) via ygtT/fiwT. 16 cols/block.
__global__ void k_ffnin2(const float* __restrict__ ygtT, const float* __restrict__ fiwT,
                         const float* __restrict__ bias, float* __restrict__ hcl) {
  int t = threadIdx.x;                    // 256
  int rq = blockIdx.x * 256 + t;
  int c0 = blockIdx.y * 16;
  const float4* x4 = (const float4*)ygtT;
  float4 acc[16];
#pragma unroll
  for (int c = 0; c < 16; ++c) acc[c] = make_float4(0.f, 0.f, 0.f, 0.f);
  for (int k = 0; k < DIv; ++k) {
    float4 xv = x4[(size_t)k * (NR / 4) + rq];
    const float* wr = fiwT + k * HIDv + c0;  // wave-uniform
#pragma unroll
    for (int c = 0; c < 16; ++c) {
      float w = wr[c];
      acc[c].x += w * xv.x; acc[c].y += w * xv.y;
      acc[c].z += w * xv.z; acc[c].w += w * xv.w;
    }
  }
#pragma unroll
  for (int li = 0; li < 4; ++li) {
    size_t row = (size_t)rq * 4 + li;
#pragma unroll
    for (int cc = 0; cc < 4; ++cc) {
      float4 v;
#pragma unroll
      for (int j = 0; j < 4; ++j) {
        float s = (&acc[cc * 4 + j].x)[li] + bias[c0 + cc * 4 + j];
        (&v.x)[j] = s * sigf(s);
      }
      *(float4*)(hcl + row * HIDv + c0 + cc * 4) = v;
    }
  }
}

// K9 (tiled): hc2 = (1 + w1)*hc(center) + dwconv3(hc) + dwconv5(hc), fused 5x5 stencil.
constexpr int TS = 16, CG = 32, TW = TS + 4;  // TW=20
__global__ void k_ffnconv(const float* __restrict__ hcl, const float* __restrict__ w1,
                          const float* __restrict__ w3, const float* __restrict__ w5,
                          float* __restrict__ hc2) {
  int tile = blockIdx.x;            // 0..15 (4x4 spatial tiles)
  int cg = blockIdx.y, b = blockIdx.z;
  int t = threadIdx.x;              // 256
  int ti0 = (tile >> 2) * TS, tj0 = (tile & 3) * TS;
  __shared__ float sm[TW * TW * CG];

  for (int e = t; e < TW * TW * CG; e += 256) {
    int ec = e & 31;
    int sp = e >> 5;                // 0..399
    int hi = sp / TW, hj = sp % TW;
    int gi = ti0 + hi - 2, gj = tj0 + hj - 2;
    float v = 0.f;
    if ((unsigned)gi < (unsigned)HH && (unsigned)gj < (unsigned)WW)
      v = hcl[((size_t)b * LL + gi * WW + gj) * HIDv + cg * CG + ec];
    sm[e] = v;
  }

  int c = t & 31;
  int cglob = cg * CG + c;
  float wc[25];
#pragma unroll
  for (int di = 0; di < 5; ++di)
#pragma unroll
    for (int dj = 0; dj < 5; ++dj) {
      float w = w5[cglob * 25 + di * 5 + dj];
      if (di >= 1 && di <= 3 && dj >= 1 && dj <= 3)
        w += w3[cglob * 9 + (di - 1) * 3 + (dj - 1)];
      if (di == 2 && dj == 2) w += 1.f + w1[cglob];
      wc[di * 5 + dj] = w;
    }
  __syncthreads();

  int s0 = t >> 5;  // 0..7
  for (int i = 0; i < 32; ++i) {
    int p = s0 + (i << 3);          // 0..255
    int r = p >> 4, q = p & 15;
    float s = 0.f;
#pragma unroll
    for (int di = 0; di < 5; ++di)
#pragma unroll
      for (int dj = 0; dj < 5; ++dj)
        s += sm[((r + di) * TW + (q + dj)) * CG + c] * wc[di * 5 + dj];
    hc2[((size_t)b * LL + (ti0 + r) * WW + (tj0 + q)) * HIDv + cglob] = s;
  }
}

// K10: LayerNorm over HID
__global__ void k_ln2(const float* __restrict__ hc2, const float* __restrict__ g,
                      const float* __restrict__ be, float* __restrict__ hn) {
  int bl = blockIdx.x;
  int t = threadIdx.x;  // 256
  const float* xr = hc2 + (size_t)bl * HIDv;
  float v[3];
  float s = 0.f, q = 0.f;
#pragma unroll
  for (int cc = 0; cc < 3; ++cc) { v[cc] = xr[t + cc * 256]; s += v[cc]; q += v[cc] * v[cc]; }
#pragma unroll
  for (int o = 32; o > 0; o >>= 1) { s += __shfl_xor(s, o, 64); q += __shfl_xor(q, o, 64); }
  __shared__ float rs_[4], rq_[4];
  int wid = t >> 6;
  if ((t & 63) == 0) { rs_[wid] = s; rq_[wid] = q; }
  __syncthreads();
  s = rs_[0] + rs_[1] + rs_[2] + rs_[3];
  q = rq_[0] + rq_[1] + rq_[2] + rq_[3];
  float m = s / HIDv;
  float var = q / HIDv - m * m;
  float r = rsqrtf(var + 1e-5f);
#pragma unroll
  for (int cc = 0; cc < 3; ++cc) {
    int c = t + cc * 256;
    hn[(size_t)bl * HIDv + c] = (v[cc] - m) * r * g[c] + be[c];
  }
}

// K11: d_out = out0 + skip * (hn @ ffn_out_w.T + b) via hnT/fowT. 8 cols/block, block 128.
__global__ void k_final2(const float* __restrict__ hnT, const float* __restrict__ fowT,
                         const float* __restrict__ bias, const float* __restrict__ out0,
                         const float* __restrict__ skip, float* __restrict__ dout) {
  int t = threadIdx.x;                    // 128
  int rq = blockIdx.x * 128 + t;          // f4-row
  int c0 = blockIdx.y * 8;
  const float4* x4 = (const float4*)hnT;
  float4 acc[8];
#pragma unroll
  for (int c = 0; c < 8; ++c) acc[c] = make_float4(0.f, 0.f, 0.f, 0.f);
  for (int k = 0; k < HIDv; ++k) {
    float4 xv = x4[(size_t)k * (NR / 4) + rq];
    const float* wr = fowT + k * DMv + c0;  // wave-uniform
#pragma unroll
    for (int c = 0; c < 8; ++c) {
      float w = wr[c];
      acc[c].x += w * xv.x; acc[c].y += w * xv.y;
      acc[c].z += w * xv.z; acc[c].w += w * xv.w;
    }
  }
  float sk = skip[0];
#pragma unroll
  for (int li = 0; li < 4; ++li) {
    size_t row = (size_t)rq * 4 + li;
#pragma unroll
    for (int cc = 0; cc < 2; ++cc) {
      float4 v;
#pragma unroll
      for (int j = 0; j < 4; ++j) {
        int c = c0 + cc * 4 + j;
        (&v.x)[j] = out0[row * DMv + c] + sk * ((&acc[cc * 4 + j].x)[li] + bias[c]);
      }
      *(float4*)(dout + row * DMv + c0 + cc * 4) = v;
    }
  }
}

extern "C" void kernel_launch(void* const* d_in, const int* in_sizes, int n_in,
                              void* d_out, int out_size, void* d_ws, size_t ws_size,
                              hipStream_t stream) {
  const float* x        = (const float*)d_in[0];
  const float* in_w     = (const float*)d_in[1];
  const float* conv_w   = (const float*)d_in[2];
  const float* conv_b   = (const float*)d_in[3];
  const float* xpw      = (const float*)d_in[4];
  const float* dtw      = (const float*)d_in[5];
  const float* dtb      = (const float*)d_in[6];
  const float* alogs    = (const float*)d_in[7];
  const float* Ds       = (const float*)d_in[8];
  const float* ong      = (const float*)d_in[9];
  const float* onb      = (const float*)d_in[10];
  const float* opw      = (const float*)d_in[11];
  const float* fiw      = (const float*)d_in[12];
  const float* fib      = (const float*)d_in[13];
  const float* dw1      = (const float*)d_in[14];
  const float* dw3      = (const float*)d_in[15];
  const float* dw5      = (const float*)d_in[16];
  const float* flg      = (const float*)d_in[17];
  const float* flb      = (const float*)d_in[18];
  const float* fow      = (const float*)d_in[19];
  const float* fob      = (const float*)d_in[20];
  const float* skip     = (const float*)d_in[21];

  // Workspace layout (aliased; ~149.5 MB; round-1 proved ws >= 180 MB)
  float* ws    = (float*)d_ws;
  float* xi    = ws;                 // -> S/P during scan -> yg -> ygtT
  float* z     = xi + S_xi;
  float* xc    = z + S_xi;           // -> ygt
  float* xdbl  = xc + S_xi;          // -> out0
  float* delta = xdbl + S_xdbl;      // xt/wt scratch -> delta -> hcl -> hn
  float* ys    = delta + S_big;      // xcT/xcTs scratch -> ys -> hc2 -> hnT
  float* wtiny = ys + S_big;         // persistent small weight transposes
  float* fiwT  = wtiny;              // 192*768 = 147456
  float* opwT  = fiwT + 147456;      // 192*96  = 18432
  float* fowT  = opwT + 18432;       // 768*96  = 73728
  float* wcatT = fowT + 73728;       // 2*192*76 = 29184

  // Small weight transposes (persist whole launch)
  k_transp<<<dim3(24, 6), 256, 0, stream>>>(fiw, fiwT, HIDv, DIv);   // 768x192 -> 192x768
  k_transp<<<dim3(3, 6), 256, 0, stream>>>(opw, opwT, DMv, DIv);     // 96x192  -> 192x96
  k_transp<<<dim3(3, 24), 256, 0, stream>>>(fow, fowT, DMv, HIDv);   // 96x768  -> 768x96
  k_wcat<<<114, 256, 0, stream>>>(xpw, wcatT);

  // In-proj via transposed operands (xt, wt live in the not-yet-used delta region)
  float* xt = delta;                       // 96*16384 floats
  float* wt = delta + 1600000;             // 36,864 floats (within S_big)
  k_wt<<<(96 * 384 + 255) / 256, 256, 0, stream>>>(in_w, wt);
  dim3 gxt(NR / 64, 3);
  k_xt<<<gxt, 256, 0, stream>>>(x, xt);
  dim3 gip(NR / 1024, 48);
  k_inproj<<<gip, 256, 0, stream>>>(xt, wt, xi, z);

  k_dwconv<<<(BB * LL * DIv) / 256, 256, 0, stream>>>(xi, conv_w, conv_b, xc);

  // x_dbl GEMM via transposed operands (xcT/xcTs in ys region, free until k_scan3)
  float* xcT  = ys;                  // 192*16384 = 3,145,728
  float* xcTs = ys + S_xi;           // 3,145,728 (6.3M < S_big)
  k_transp<<<dim3(512, 6), 256, 0, stream>>>(xc, xcT, NR, DIv);
  k_spt<<<DIv * BB, 256, 0, stream>>>(xcT, xcTs);
  dim3 gxd(4, 19, 8);                // rq-blocks x col-groups x (p*4+b)
  k_xdbl2<<<gxd, 256, 0, stream>>>(xcT, xcTs, wcatT, xdbl);

  k_delta<<<(BB * KKv * LL * DIv) / 256, 256, 0, stream>>>(xdbl, dtw, dtb, delta);

  // Chunked scan: S/P buffers alias xi (dead until k_combine writes yg there)
  float* Sbuf = xi;                  // S_sp floats
  float* Pbuf = xi + S_sp;           // S_sp floats (S_sp*2 == S_xi exactly)
  dim3 gs13(NC * NDB, KKv, BB);      // 6144 blocks
  dim3 gs2(NDB, KKv, BB);            // 192 blocks (tiny)
  k_scan1<<<gs13, 256, 0, stream>>>(delta, xdbl, xc, alogs, Sbuf, Pbuf);
  k_scan2<<<gs2, 256, 0, stream>>>(Sbuf, Pbuf);  // S <- Hin
  k_scan3<<<gs13, 256, 0, stream>>>(delta, xdbl, xc, alogs, Sbuf, ys);

  float* yg = xi;  // overwrites S/P (dead after k_scan3)
  k_combine<<<(BB * LL * DIv) / 256, 256, 0, stream>>>(ys, xc, Ds, yg);
  float* ygt = xc;
  k_lngate<<<BB * LL, 64, 0, stream>>>(yg, z, ong, onb, ygt);

  // Transpose ygt (16384x192 -> 192x16384) into xi (yg dead)
  float* ygtT = xi;
  k_transp<<<dim3(512, 6), 256, 0, stream>>>(ygt, ygtT, NR, DIv);

  float* out0 = xdbl;
  dim3 gop(NR / 1024, DMv / 4);      // (16, 24)
  k_outproj2<<<gop, 256, 0, stream>>>(ygtT, opwT, out0);
  float* hcl = delta;
  dim3 gfi(NR / 1024, HIDv / 16);    // (16, 48)
  k_ffnin2<<<gfi, 256, 0, stream>>>(ygtT, fiwT, fib, hcl);
  float* hc2 = ys;
  dim3 gc(16, HIDv / CG, BB);        // 16 spatial tiles x 24 ch-groups x 4
  k_ffnconv<<<gc, 256, 0, stream>>>(hcl, dw1, dw3, dw5, hc2);
  float* hn = delta;  // hcl dead after k_ffnconv
  k_ln2<<<BB * LL, 256, 0, stream>>>(hc2, flg, flb, hn);

  // Transpose hn (16384x768 -> 768x16384) into ys (hc2 dead)
  float* hnT = ys;
  k_transp<<<dim3(512, 24), 256, 0, stream>>>(hn, hnT, NR, HIDv);

  dim3 gfn(NR / 512, DMv / 8);       // (32, 12), block 128
  k_final2<<<gfn, 128, 0, stream>>>(hnT, fowT, fob, out0, skip, (float*)d_out);
}

// Round 9
// 677.551 us; speedup vs baseline: 2.6853x; 1.3574x over previous
//
#include <hip/hip_runtime.h>
#include <hip/hip_bf16.h>

constexpr int BB = 4, HH = 64, WW = 64, DMv = 96;
constexpr int DSn = 16, DIv = 192, DTRv = 6, KKv = 4, HIDv = 768;
constexpr int LL = 4096;
constexpr int NC = 32, CHK = LL / NC;       // 32 chunks of 128
constexpr int NR = BB * LL;                 // 16384 rows
constexpr int XDS = 40;                     // padded xdbl row stride (dt 0-5, B 8-23, C 24-39)

constexpr size_t S_xi   = (size_t)BB * LL * DIv;          // 3,145,728
constexpr size_t S_xdbl = (size_t)BB * KKv * LL * XDS;    // 2,621,440
constexpr size_t S_big  = (size_t)BB * KKv * LL * DIv;    // 12,582,912
constexpr size_t S_sp   = (size_t)BB * KKv * NC * DIv * DSn;  // 1,572,864 (= S_xi/2)

__device__ __forceinline__ float sigf(float x) { return 1.f / (1.f + expf(-x)); }
__device__ __forceinline__ float dot4(float4 a, float4 b) {
  return a.x * b.x + a.y * b.y + a.z * b.z + a.w * b.w;
}

__device__ __forceinline__ int lmap(int k, int l) {
  int lr = (k & 2) ? (LL - 1 - l) : l;
  return (k & 1) ? (((lr & 63) << 6) | (lr >> 6)) : lr;
}

// Generic 32x32 LDS tile transpose: src[R][C] -> dst[C][R], both coalesced.
__global__ void k_transp(const float* __restrict__ src, float* __restrict__ dst,
                         int R, int C) {
  __shared__ float tile[32][33];
  int r0 = blockIdx.x * 32, c0 = blockIdx.y * 32;
  int t = threadIdx.x;            // 256
  int tc = t & 31, tr = t >> 5;   // tr 0..7
#pragma unroll
  for (int i = 0; i < 4; ++i) {
    int r = r0 + tr + i * 8;
    if (r < R && c0 + tc < C) tile[tr + i * 8][tc] = src[(size_t)r * C + c0 + tc];
  }
  __syncthreads();
#pragma unroll
  for (int i = 0; i < 4; ++i) {
    int c = c0 + tr + i * 8;
    int r = r0 + tc;
    if (c < C && r < R) dst[(size_t)c * R + r] = tile[tc][tr + i * 8];
  }
}

// K0a: wt[k][c] = in_proj_w[c][k]  (96 x 384)
__global__ void k_wt(const float* __restrict__ w, float* __restrict__ wt) {
  int idx = blockIdx.x * 256 + threadIdx.x;  // 36864
  if (idx < 96 * 384) {
    int k = idx / 384, c = idx % 384;
    wt[idx] = w[c * 96 + k];
  }
}

// K0b: xt[k][row] = x[row][k]  (96 x 16384), 64x32 LDS tile transpose
__global__ void k_xt(const float* __restrict__ x, float* __restrict__ xt) {
  __shared__ float tile[32][65];
  int r0 = blockIdx.x * 64, k0 = blockIdx.y * 32;
  int t = threadIdx.x;  // 256
#pragma unroll
  for (int ii = 0; ii < 8; ++ii) {
    int i = (t >> 5) + ii * 8, j = t & 31;
    tile[j][i] = x[(size_t)(r0 + i) * 96 + k0 + j];
  }
  __syncthreads();
#pragma unroll
  for (int jj = 0; jj < 8; ++jj) {
    int j = (t >> 6) + jj * 4, i = t & 63;
    xt[(size_t)(k0 + j) * NR + r0 + i] = tile[j][i];
  }
}

// K1: xz = x @ in_proj_w.T via xt/wt. Lane = 4 rows (f4, coalesced), wave-uniform
// scalar weight loads.
__global__ void k_inproj(const float* __restrict__ xt, const float* __restrict__ wt,
                         float* __restrict__ xi, float* __restrict__ z) {
  int t = threadIdx.x;
  int wv = t >> 6, lane = t & 63;
  int rq = blockIdx.x * 256 + wv * 64 + lane;   // float4-row index (row = rq*4)
  int c0 = blockIdx.y * 8;
  const float4* xt4 = (const float4*)xt;
  float4 acc[8];
#pragma unroll
  for (int c = 0; c < 8; ++c) acc[c] = make_float4(0.f, 0.f, 0.f, 0.f);
  for (int k = 0; k < 96; ++k) {
    float4 xv = xt4[(size_t)k * (NR / 4) + rq];
    const float* wr = wt + k * 384 + c0;  // wave-uniform -> s_load
#pragma unroll
    for (int c = 0; c < 8; ++c) {
      float w = wr[c];
      acc[c].x += w * xv.x; acc[c].y += w * xv.y;
      acc[c].z += w * xv.z; acc[c].w += w * xv.w;
    }
  }
  float* dst; int cc;
  if (c0 < DIv) { dst = xi; cc = c0; } else { dst = z; cc = c0 - DIv; }
#pragma unroll
  for (int li = 0; li < 4; ++li) {
    size_t row = (size_t)rq * 4 + li;
    float4 v0, v1;
    v0.x = (&acc[0].x)[li]; v0.y = (&acc[1].x)[li];
    v0.z = (&acc[2].x)[li]; v0.w = (&acc[3].x)[li];
    v1.x = (&acc[4].x)[li]; v1.y = (&acc[5].x)[li];
    v1.z = (&acc[6].x)[li]; v1.w = (&acc[7].x)[li];
    float4* o4 = (float4*)(dst + row * DIv + cc);
    o4[0] = v0; o4[1] = v1;
  }
}

// K2: xc = silu(dwconv3x3(xi) + conv_b), channel-last
__global__ void k_dwconv(const float* __restrict__ xi, const float* __restrict__ cw,
                         const float* __restrict__ cb, float* __restrict__ xc) {
  size_t idx = (size_t)blockIdx.x * 256 + threadIdx.x;  // B*L*DI
  int d = (int)(idx % DIv);
  int l = (int)((idx / DIv) % LL);
  int b = (int)(idx / ((size_t)DIv * LL));
  int i = l >> 6, j = l & 63;
  float s = cb[d];
#pragma unroll
  for (int di = 0; di < 3; ++di) {
    int ii = i + di - 1;
    if ((unsigned)ii >= (unsigned)HH) continue;
#pragma unroll
    for (int dj = 0; dj < 3; ++dj) {
      int jj = j + dj - 1;
      if ((unsigned)jj >= (unsigned)WW) continue;
      s += xi[((size_t)b * LL + ii * WW + jj) * DIv + d] * cw[d * 9 + di * 3 + dj];
    }
  }
  xc[idx] = s * sigf(s);
}

// K3pre-a: spatial transpose per (d,b): xcTs[d][b][j*64+i] = xcT[d][b][i*64+j]
__global__ void k_spt(const float* __restrict__ xcT, float* __restrict__ xcTs) {
  __shared__ float tile[64][65];
  int d = blockIdx.x >> 2, b = blockIdx.x & 3;
  int t = threadIdx.x;  // 256
  const float* src = xcT + (size_t)d * NR + b * LL;
  float* dst = xcTs + (size_t)d * NR + b * LL;
#pragma unroll
  for (int it = 0; it < 16; ++it) {
    int idx = it * 256 + t;
    tile[idx >> 6][idx & 63] = src[idx];
  }
  __syncthreads();
#pragma unroll
  for (int it = 0; it < 16; ++it) {
    int idx = it * 256 + t;
    dst[idx] = tile[idx & 63][idx >> 6];
  }
}

// K3pre-b: wcatT[p][d][76]: cols 0..37 = w_{k=p}[c][d], 38..75 = w_{k=p+2}[c][d]
__global__ void k_wcat(const float* __restrict__ xpw, float* __restrict__ wcatT) {
  int idx = blockIdx.x * 256 + threadIdx.x;  // 2*192*76 = 29184
  if (idx < 2 * 192 * 76) {
    int p = idx / (192 * 76);
    int rem = idx % (192 * 76);
    int d = rem / 76, j = rem % 76;
    int k = (j >= 38 ? 2 : 0) + p;
    int c = (j >= 38) ? j - 38 : j;
    wcatT[idx] = xpw[((size_t)(k * 38 + c)) * DIv + d];
  }
}

// K3a: x_dbl via transposed operands; writes padded stride-40 layout:
// phys col = c + (c>=6 ? 2 : 0)  (dt 0-5, B 8-23, C 24-39).
__global__ void k_xdbl2(const float* __restrict__ xcT, const float* __restrict__ xcTs,
                        const float* __restrict__ wcatT, float* __restrict__ xdbl) {
  int t = threadIdx.x;                  // 256
  int rq = blockIdx.x * 256 + t;        // 0..1023 f4-row within b
  int jg = blockIdx.y;                  // 0..18 -> cols jg*4..jg*4+3
  int pb = blockIdx.z;                  // p*4 + b
  int p = pb >> 2, b = pb & 3;
  const float4* A = (const float4*)(p ? xcTs : xcT);
  const float* wbase = wcatT + (size_t)p * 192 * 76 + jg * 4;
  float4 acc[4];
#pragma unroll
  for (int j = 0; j < 4; ++j) acc[j] = make_float4(0.f, 0.f, 0.f, 0.f);
  for (int d = 0; d < 192; ++d) {
    float4 xv = A[(size_t)d * (NR / 4) + b * 1024 + rq];
    const float* wr = wbase + d * 76;   // wave-uniform -> s_load
#pragma unroll
    for (int j = 0; j < 4; ++j) {
      float w = wr[j];
      acc[j].x += w * xv.x; acc[j].y += w * xv.y;
      acc[j].z += w * xv.z; acc[j].w += w * xv.w;
    }
  }
#pragma unroll
  for (int li = 0; li < 4; ++li) {
    int r = rq * 4 + li;
#pragma unroll
    for (int j = 0; j < 4; ++j) {
      int col = jg * 4 + j;
      int kk = (col >= 38) ? (2 + p) : p;
      int c = (col >= 38) ? col - 38 : col;
      int l = (col >= 38) ? (LL - 1 - r) : r;
      int phys = c + (c >= 6 ? 2 : 0);
      xdbl[(((size_t)(b * KKv + kk)) * LL + l) * XDS + phys] = (&acc[j].x)[li];
    }
  }
}

// K3b: delta[b,k,l,d] = softplus(dts @ dt_projs_w + dt_projs_b)
__global__ void k_delta(const float* __restrict__ xdbl, const float* __restrict__ dtw,
                        const float* __restrict__ dtb, float* __restrict__ delta) {
  size_t idx = (size_t)blockIdx.x * 256 + threadIdx.x;  // B*K*L*DI
  int d = (int)(idx % DIv);
  size_t bkl = idx / DIv;              // (b*K+k)*L + l
  int k = (int)((bkl / LL) % KKv);
  const float* xr = xdbl + bkl * XDS;
  const float* wr = dtw + ((size_t)k * DIv + d) * DTRv;
  float s = dtb[k * DIv + d];
#pragma unroll
  for (int r = 0; r < DTRv; ++r) s += xr[r] * wr[r];
  delta[idx] = (s > 20.f) ? s : log1pf(expf(s));
}

// K4a: chunked scan pass 1. Thread owns (d, n-quad): 4 h-chains in regs.
// Block = 256 thr = 64 d x 4 nq; grid (NC*3, K, B).
__global__ void k_scan1(const float* __restrict__ delta, const float* __restrict__ xdbl,
                        const float* __restrict__ xc, const float* __restrict__ alogs,
                        float* __restrict__ S, float* __restrict__ P) {
  int bx = blockIdx.x;
  int c = bx / 3, dblk = bx % 3;
  int k = blockIdx.y, b = blockIdx.z;
  int t = threadIdx.x, dl = t >> 2, nq = t & 3;
  int d = dblk * 64 + dl;
  float A[4];
#pragma unroll
  for (int j = 0; j < 4; ++j)
    A[j] = -__expf(alogs[(size_t)(k * DIv + d) * DSn + nq * 4 + j]);
  size_t bkL = (size_t)(b * KKv + k) * LL;
  const float* dp = delta + bkL * DIv + d;
  const float* xq = xdbl + bkL * XDS;
  const float* xcb = xc + (size_t)b * LL * DIv + d;
  float h[4] = {0.f, 0.f, 0.f, 0.f}, sA[4] = {0.f, 0.f, 0.f, 0.f};
  int l0 = c * CHK;
  for (int i = 0; i < CHK; ++i) {
    int l = l0 + i;
    float de = dp[(size_t)l * DIv];
    float4 Bv = *(const float4*)(xq + (size_t)l * XDS + 8 + nq * 4);
    float xv = xcb[(size_t)lmap(k, l) * DIv];
    float db = de * xv;
#pragma unroll
    for (int j = 0; j < 4; ++j) {
      float u = de * A[j];
      sA[j] += u;
      h[j] = h[j] * __expf(u) + db * (&Bv.x)[j];
    }
  }
  size_t o = ((((size_t)(b * KKv + k) * NC + c) * 3 + dblk) * 1024) + (size_t)t * 4;
  float4 hs, ps;
#pragma unroll
  for (int j = 0; j < 4; ++j) { (&hs.x)[j] = h[j]; (&ps.x)[j] = __expf(sA[j]); }
  *(float4*)(S + o) = hs;
  *(float4*)(P + o) = ps;
}

// K4b: sequential chunk combine (float4 per thread). Rewrites S[c] <- Hin[c].
__global__ void k_scan2(float* __restrict__ S, const float* __restrict__ P) {
  int dblk = blockIdx.x, k = blockIdx.y, b = blockIdx.z;
  int t = threadIdx.x;  // 256
  size_t base = (((size_t)(b * KKv + k) * NC) * 3 + dblk) * 1024 + (size_t)t * 4;
  float4 h = make_float4(0.f, 0.f, 0.f, 0.f);
  for (int c = 0; c < NC; ++c) {
    size_t o = base + (size_t)c * 3 * 1024;
    float4 s = *(float4*)(S + o), p = *(float4*)(P + o);
    *(float4*)(S + o) = h;  // Hin for chunk c
    h.x = s.x + p.x * h.x; h.y = s.y + p.y * h.y;
    h.z = s.z + p.z * h.z; h.w = s.w + p.w * h.w;
  }
}

// K4c: chunked scan pass 3 — thread owns (d, n-quad); width-4 shuffle for y.
__global__ void k_scan3(const float* __restrict__ delta, const float* __restrict__ xdbl,
                        const float* __restrict__ xc, const float* __restrict__ alogs,
                        const float* __restrict__ Hin, float* __restrict__ ys) {
  int bx = blockIdx.x;
  int c = bx / 3, dblk = bx % 3;
  int k = blockIdx.y, b = blockIdx.z;
  int t = threadIdx.x, dl = t >> 2, nq = t & 3;
  int d = dblk * 64 + dl;
  float A[4];
#pragma unroll
  for (int j = 0; j < 4; ++j)
    A[j] = -__expf(alogs[(size_t)(k * DIv + d) * DSn + nq * 4 + j]);
  size_t bkL = (size_t)(b * KKv + k) * LL;
  const float* dp = delta + bkL * DIv + d;
  const float* xq = xdbl + bkL * XDS;
  const float* xcb = xc + (size_t)b * LL * DIv + d;
  float* yp = ys + bkL * DIv + d;
  size_t o = ((((size_t)(b * KKv + k) * NC + c) * 3 + dblk) * 1024) + (size_t)t * 4;
  float4 h4 = *(const float4*)(Hin + o);
  float h[4] = {h4.x, h4.y, h4.z, h4.w};
  int l0 = c * CHK;
  for (int i = 0; i < CHK; ++i) {
    int l = l0 + i;
    float de = dp[(size_t)l * DIv];
    float4 Bv = *(const float4*)(xq + (size_t)l * XDS + 8 + nq * 4);
    float4 Cv = *(const float4*)(xq + (size_t)l * XDS + 24 + nq * 4);
    float xv = xcb[(size_t)lmap(k, l) * DIv];
    float db = de * xv;
    float p = 0.f;
#pragma unroll
    for (int j = 0; j < 4; ++j) {
      h[j] = h[j] * __expf(de * A[j]) + db * (&Bv.x)[j];
      p += h[j] * (&Cv.x)[j];
    }
    p += __shfl_down(p, 2, 4);
    p += __shfl_down(p, 1, 4);
    if (nq == 0) yp[(size_t)l * DIv] = p;
  }
}

// K5: merge 4 directions + D*x skip, output yg[b,l,d]
__global__ void k_combine(const float* __restrict__ ys, const float* __restrict__ xc,
                          const float* __restrict__ Ds, float* __restrict__ yg) {
  size_t idx = (size_t)blockIdx.x * 256 + threadIdx.x;  // B*L*DI
  int d = (int)(idx % DIv);
  int l = (int)((idx / DIv) % LL);
  int b = (int)(idx / ((size_t)DIv * LL));
  int lT = ((l & 63) << 6) | (l >> 6);
  size_t base = (size_t)b * KKv * LL * DIv;
  float v = ys[base + ((size_t)0 * LL + l) * DIv + d]
          + ys[base + ((size_t)2 * LL + (LL - 1 - l)) * DIv + d]
          + ys[base + ((size_t)1 * LL + lT) * DIv + d]
          + ys[base + ((size_t)3 * LL + (LL - 1 - lT)) * DIv + d];
  float sd = Ds[d] + Ds[DIv + d] + Ds[2 * DIv + d] + Ds[3 * DIv + d];
  v += sd * xc[((size_t)b * LL + l) * DIv + d];
  yg[idx] = v;
}

// K6: LayerNorm(DI) * silu(z)
__global__ void k_lngate(const float* __restrict__ yg, const float* __restrict__ z,
                         const float* __restrict__ g, const float* __restrict__ be,
                         float* __restrict__ out) {
  int bl = blockIdx.x;
  int t = threadIdx.x;  // 64
  const float* yr = yg + (size_t)bl * DIv;
  float v[3];
  float s = 0.f, q = 0.f;
#pragma unroll
  for (int cc = 0; cc < 3; ++cc) { v[cc] = yr[t + cc * 64]; s += v[cc]; q += v[cc] * v[cc]; }
#pragma unroll
  for (int o = 32; o > 0; o >>= 1) { s += __shfl_xor(s, o, 64); q += __shfl_xor(q, o, 64); }
  float m = s / DIv;
  float var = q / DIv - m * m;
  float rs = rsqrtf(var + 1e-5f);
  const float* zr = z + (size_t)bl * DIv;
  float* orow = out + (size_t)bl * DIv;
#pragma unroll
  for (int cc = 0; cc < 3; ++cc) {
    int d = t + cc * 64;
    float zz = zr[d];
    float val = (v[cc] - m) * rs * g[d] + be[d];
    orow[d] = val * zz * sigf(zz);
  }
}

// K7: out0 = ygated @ out_proj_w.T via ygtT/opwT. 4 cols/block, lanes = rows.
__global__ void k_outproj2(const float* __restrict__ ygtT, const float* __restrict__ opwT,
                           float* __restrict__ out0) {
  int t = threadIdx.x;                    // 256
  int rq = blockIdx.x * 256 + t;          // f4-row index
  int c0 = blockIdx.y * 4;
  const float4* x4 = (const float4*)ygtT;
  float4 acc[4];
#pragma unroll
  for (int c = 0; c < 4; ++c) acc[c] = make_float4(0.f, 0.f, 0.f, 0.f);
  for (int k = 0; k < DIv; ++k) {
    float4 xv = x4[(size_t)k * (NR / 4) + rq];
    const float* wr = opwT + k * DMv + c0;  // wave-uniform
#pragma unroll
    for (int c = 0; c < 4; ++c) {
      float w = wr[c];
      acc[c].x += w * xv.x; acc[c].y += w * xv.y;
      acc[c].z += w * xv.z; acc[c].w += w * xv.w;
    }
  }
#pragma unroll
  for (int li = 0; li < 4; ++li) {
    float4 v;
    v.x = (&acc[0].x)[li]; v.y = (&acc[1].x)[li];
    v.z = (&acc[2].x)[li]; v.w = (&acc[3].x)[li];
    *(float4*)(out0 + ((size_t)rq * 4 + li) * DMv + c0) = v;
  }
}

// K8: hcl = silu(ygated @ ffn_in_w.T + b) via ygtT/fiwT. 16 cols/block.
__global__ void k_ffnin2(const float* __restrict__ ygtT, const float* __restrict__ fiwT,
                         const float* __restrict__ bias, float* __restrict__ hcl) {
  int t = threadIdx.x;                    // 256
  int rq = blockIdx.x * 256 + t;
  int c0 = blockIdx.y * 16;
  const float4* x4 = (const float4*)ygtT;
  float4 acc[16];
#pragma unroll
  for (int c = 0; c < 16; ++c) acc[c] = make_float4(0.f, 0.f, 0.f, 0.f);
  for (int k = 0; k < DIv; ++k) {
    float4 xv = x4[(size_t)k * (NR / 4) + rq];
    const float* wr = fiwT + k * HIDv + c0;  // wave-uniform
#pragma unroll
    for (int c = 0; c < 16; ++c) {
      float w = wr[c];
      acc[c].x += w * xv.x; acc[c].y += w * xv.y;
      acc[c].z += w * xv.z; acc[c].w += w * xv.w;
    }
  }
#pragma unroll
  for (int li = 0; li < 4; ++li) {
    size_t row = (size_t)rq * 4 + li;
#pragma unroll
    for (int cc = 0; cc < 4; ++cc) {
      float4 v;
#pragma unroll
      for (int j = 0; j < 4; ++j) {
        float s = (&acc[cc * 4 + j].x)[li] + bias[c0 + cc * 4 + j];
        (&v.x)[j] = s * sigf(s);
      }
      *(float4*)(hcl + row * HIDv + c0 + cc * 4) = v;
    }
  }
}

// K9 (tiled): hc2 = (1 + w1)*hc(center) + dwconv3(hc) + dwconv5(hc), fused 5x5 stencil.
constexpr int TS = 16, CG = 32, TW = TS + 4;  // TW=20
__global__ void k_ffnconv(const float* __restrict__ hcl, const float* __restrict__ w1,
                          const float* __restrict__ w3, const float* __restrict__ w5,
                          float* __restrict__ hc2) {
  int tile = blockIdx.x;            // 0..15 (4x4 spatial tiles)
  int cg = blockIdx.y, b = blockIdx.z;
  int t = threadIdx.x;              // 256
  int ti0 = (tile >> 2) * TS, tj0 = (tile & 3) * TS;
  __shared__ float sm[TW * TW * CG];

  for (int e = t; e < TW * TW * CG; e += 256) {
    int ec = e & 31;
    int sp = e >> 5;                // 0..399
    int hi = sp / TW, hj = sp % TW;
    int gi = ti0 + hi - 2, gj = tj0 + hj - 2;
    float v = 0.f;
    if ((unsigned)gi < (unsigned)HH && (unsigned)gj < (unsigned)WW)
      v = hcl[((size_t)b * LL + gi * WW + gj) * HIDv + cg * CG + ec];
    sm[e] = v;
  }

  int c = t & 31;
  int cglob = cg * CG + c;
  float wc[25];
#pragma unroll
  for (int di = 0; di < 5; ++di)
#pragma unroll
    for (int dj = 0; dj < 5; ++dj) {
      float w = w5[cglob * 25 + di * 5 + dj];
      if (di >= 1 && di <= 3 && dj >= 1 && dj <= 3)
        w += w3[cglob * 9 + (di - 1) * 3 + (dj - 1)];
      if (di == 2 && dj == 2) w += 1.f + w1[cglob];
      wc[di * 5 + dj] = w;
    }
  __syncthreads();

  int s0 = t >> 5;  // 0..7
  for (int i = 0; i < 32; ++i) {
    int p = s0 + (i << 3);          // 0..255
    int r = p >> 4, q = p & 15;
    float s = 0.f;
#pragma unroll
    for (int di = 0; di < 5; ++di)
#pragma unroll
      for (int dj = 0; dj < 5; ++dj)
        s += sm[((r + di) * TW + (q + dj)) * CG + c] * wc[di * 5 + dj];
    hc2[((size_t)b * LL + (ti0 + r) * WW + (tj0 + q)) * HIDv + cglob] = s;
  }
}

// K10: LayerNorm over HID
__global__ void k_ln2(const float* __restrict__ hc2, const float* __restrict__ g,
                      const float* __restrict__ be, float* __restrict__ hn) {
  int bl = blockIdx.x;
  int t = threadIdx.x;  // 256
  const float* xr = hc2 + (size_t)bl * HIDv;
  float v[3];
  float s = 0.f, q = 0.f;
#pragma unroll
  for (int cc = 0; cc < 3; ++cc) { v[cc] = xr[t + cc * 256]; s += v[cc]; q += v[cc] * v[cc]; }
#pragma unroll
  for (int o = 32; o > 0; o >>= 1) { s += __shfl_xor(s, o, 64); q += __shfl_xor(q, o, 64); }
  __shared__ float rs_[4], rq_[4];
  int wid = t >> 6;
  if ((t & 63) == 0) { rs_[wid] = s; rq_[wid] = q; }
  __syncthreads();
  s = rs_[0] + rs_[1] + rs_[2] + rs_[3];
  q = rq_[0] + rq_[1] + rq_[2] + rq_[3];
  float m = s / HIDv;
  float var = q / HIDv - m * m;
  float r = rsqrtf(var + 1e-5f);
#pragma unroll
  for (int cc = 0; cc < 3; ++cc) {
    int c = t + cc * 256;
    hn[(size_t)bl * HIDv + c] = (v[cc] - m) * r * g[c] + be[c];
  }
}

// K11: d_out = out0 + skip * (hn @ ffn_out_w.T + b) via hnT/fowT. 8 cols/block, block 128.
__global__ void k_final2(const float* __restrict__ hnT, const float* __restrict__ fowT,
                         const float* __restrict__ bias, const float* __restrict__ out0,
                         const float* __restrict__ skip, float* __restrict__ dout) {
  int t = threadIdx.x;                    // 128
  int rq = blockIdx.x * 128 + t;          // f4-row
  int c0 = blockIdx.y * 8;
  const float4* x4 = (const float4*)hnT;
  float4 acc[8];
#pragma unroll
  for (int c = 0; c < 8; ++c) acc[c] = make_float4(0.f, 0.f, 0.f, 0.f);
  for (int k = 0; k < HIDv; ++k) {
    float4 xv = x4[(size_t)k * (NR / 4) + rq];
    const float* wr = fowT + k * DMv + c0;  // wave-uniform
#pragma unroll
    for (int c = 0; c < 8; ++c) {
      float w = wr[c];
      acc[c].x += w * xv.x; acc[c].y += w * xv.y;
      acc[c].z += w * xv.z; acc[c].w += w * xv.w;
    }
  }
  float sk = skip[0];
#pragma unroll
  for (int li = 0; li < 4; ++li) {
    size_t row = (size_t)rq * 4 + li;
#pragma unroll
    for (int cc = 0; cc < 2; ++cc) {
      float4 v;
#pragma unroll
      for (int j = 0; j < 4; ++j) {
        int c = c0 + cc * 4 + j;
        (&v.x)[j] = out0[row * DMv + c] + sk * ((&acc[cc * 4 + j].x)[li] + bias[c]);
      }
      *(float4*)(dout + row * DMv + c0 + cc * 4) = v;
    }
  }
}

extern "C" void kernel_launch(void* const* d_in, const int* in_sizes, int n_in,
                              void* d_out, int out_size, void* d_ws, size_t ws_size,
                              hipStream_t stream) {
  const float* x        = (const float*)d_in[0];
  const float* in_w     = (const float*)d_in[1];
  const float* conv_w   = (const float*)d_in[2];
  const float* conv_b   = (const float*)d_in[3];
  const float* xpw      = (const float*)d_in[4];
  const float* dtw      = (const float*)d_in[5];
  const float* dtb      = (const float*)d_in[6];
  const float* alogs    = (const float*)d_in[7];
  const float* Ds       = (const float*)d_in[8];
  const float* ong      = (const float*)d_in[9];
  const float* onb      = (const float*)d_in[10];
  const float* opw      = (const float*)d_in[11];
  const float* fiw      = (const float*)d_in[12];
  const float* fib      = (const float*)d_in[13];
  const float* dw1      = (const float*)d_in[14];
  const float* dw3      = (const float*)d_in[15];
  const float* dw5      = (const float*)d_in[16];
  const float* flg      = (const float*)d_in[17];
  const float* flb      = (const float*)d_in[18];
  const float* fow      = (const float*)d_in[19];
  const float* fob      = (const float*)d_in[20];
  const float* skip     = (const float*)d_in[21];

  // Workspace layout (aliased; ~150 MB)
  float* ws    = (float*)d_ws;
  float* xi    = ws;                 // -> S/P during scan -> yg -> ygtT
  float* z     = xi + S_xi;
  float* xc    = z + S_xi;           // -> ygt
  float* xdbl  = xc + S_xi;          // -> out0
  float* delta = xdbl + S_xdbl;      // xt/wt scratch -> delta -> hcl -> hn
  float* ys    = delta + S_big;      // xcT/xcTs scratch -> ys -> hc2 -> hnT
  float* wtiny = ys + S_big;         // persistent small weight transposes
  float* fiwT  = wtiny;              // 192*768 = 147456
  float* opwT  = fiwT + 147456;      // 192*96  = 18432
  float* fowT  = opwT + 18432;       // 768*96  = 73728
  float* wcatT = fowT + 73728;       // 2*192*76 = 29184

  // Small weight transposes (persist whole launch)
  k_transp<<<dim3(24, 6), 256, 0, stream>>>(fiw, fiwT, HIDv, DIv);   // 768x192 -> 192x768
  k_transp<<<dim3(3, 6), 256, 0, stream>>>(opw, opwT, DMv, DIv);     // 96x192  -> 192x96
  k_transp<<<dim3(3, 24), 256, 0, stream>>>(fow, fowT, DMv, HIDv);   // 96x768  -> 768x96
  k_wcat<<<114, 256, 0, stream>>>(xpw, wcatT);

  // In-proj via transposed operands (xt, wt live in the not-yet-used delta region)
  float* xt = delta;                       // 96*16384 floats
  float* wt = delta + 1600000;             // 36,864 floats (within S_big)
  k_wt<<<(96 * 384 + 255) / 256, 256, 0, stream>>>(in_w, wt);
  dim3 gxt(NR / 64, 3);
  k_xt<<<gxt, 256, 0, stream>>>(x, xt);
  dim3 gip(NR / 1024, 48);
  k_inproj<<<gip, 256, 0, stream>>>(xt, wt, xi, z);

  k_dwconv<<<(BB * LL * DIv) / 256, 256, 0, stream>>>(xi, conv_w, conv_b, xc);

  // x_dbl GEMM via transposed operands (xcT/xcTs in ys region, free until k_scan3)
  float* xcT  = ys;                  // 192*16384 = 3,145,728
  float* xcTs = ys + S_xi;           // 3,145,728 (6.3M < S_big)
  k_transp<<<dim3(512, 6), 256, 0, stream>>>(xc, xcT, NR, DIv);
  k_spt<<<DIv * BB, 256, 0, stream>>>(xcT, xcTs);
  dim3 gxd(4, 19, 8);                // rq-blocks x col-groups x (p*4+b)
  k_xdbl2<<<gxd, 256, 0, stream>>>(xcT, xcTs, wcatT, xdbl);

  k_delta<<<(BB * KKv * LL * DIv) / 256, 256, 0, stream>>>(xdbl, dtw, dtb, delta);

  // Chunked scan: S/P buffers alias xi (dead until k_combine writes yg there)
  float* Sbuf = xi;                  // S_sp floats
  float* Pbuf = xi + S_sp;           // S_sp floats (S_sp*2 == S_xi exactly)
  dim3 gs13(NC * 3, KKv, BB);        // 1536 blocks, 64d x 4nq threads
  dim3 gs2(3, KKv, BB);              // 48 blocks (tiny)
  k_scan1<<<gs13, 256, 0, stream>>>(delta, xdbl, xc, alogs, Sbuf, Pbuf);
  k_scan2<<<gs2, 256, 0, stream>>>(Sbuf, Pbuf);  // S <- Hin
  k_scan3<<<gs13, 256, 0, stream>>>(delta, xdbl, xc, alogs, Sbuf, ys);

  float* yg = xi;  // overwrites S/P (dead after k_scan3)
  k_combine<<<(BB * LL * DIv) / 256, 256, 0, stream>>>(ys, xc, Ds, yg);
  float* ygt = xc;
  k_lngate<<<BB * LL, 64, 0, stream>>>(yg, z, ong, onb, ygt);

  // Transpose ygt (16384x192 -> 192x16384) into xi (yg dead)
  float* ygtT = xi;
  k_transp<<<dim3(512, 6), 256, 0, stream>>>(ygt, ygtT, NR, DIv);

  float* out0 = xdbl;
  dim3 gop(NR / 1024, DMv / 4);      // (16, 24)
  k_outproj2<<<gop, 256, 0, stream>>>(ygtT, opwT, out0);
  float* hcl = delta;
  dim3 gfi(NR / 1024, HIDv / 16);    // (16, 48)
  k_ffnin2<<<gfi, 256, 0, stream>>>(ygtT, fiwT, fib, hcl);
  float* hc2 = ys;
  dim3 gc(16, HIDv / CG, BB);        // 16 spatial tiles x 24 ch-groups x 4
  k_ffnconv<<<gc, 256, 0, stream>>>(hcl, dw1, dw3, dw5, hc2);
  float* hn = delta;  // hcl dead after k_ffnconv
  k_ln2<<<BB * LL, 256, 0, stream>>>(hc2, flg, flb, hn);

  // Transpose hn (16384x768 -> 768x16384) into ys (hc2 dead)
  float* hnT = ys;
  k_transp<<<dim3(512, 24), 256, 0, stream>>>(hn, hnT, NR, HIDv);

  dim3 gfn(NR / 512, DMv / 8);       // (32, 12), block 128
  k_final2<<<gfn, 128, 0, stream>>>(hnT, fowT, fob, out0, skip, (float*)d_out);
}

// Round 10
// 627.853 us; speedup vs baseline: 2.8978x; 1.0792x over previous
//
#include <hip/hip_runtime.h>
#include <hip/hip_bf16.h>

constexpr int BB = 4, HH = 64, WW = 64, DMv = 96;
constexpr int DSn = 16, DIv = 192, DTRv = 6, KKv = 4, HIDv = 768;
constexpr int LL = 4096;
constexpr int NC = 32, CHK = LL / NC;       // 32 chunks of 128
constexpr int NR = BB * LL;                 // 16384 rows
constexpr int XDS = 40;                     // padded xdbl row stride (dt 0-5, B 8-23, C 24-39)

constexpr size_t S_xi   = (size_t)BB * LL * DIv;          // 3,145,728
constexpr size_t S_xdbl = (size_t)BB * KKv * LL * XDS;    // 2,621,440
constexpr size_t S_big  = (size_t)BB * KKv * LL * DIv;    // 12,582,912
constexpr size_t S_sp   = (size_t)BB * KKv * NC * DIv * DSn;  // 1,572,864 (= S_xi/2)

__device__ __forceinline__ float sigf(float x) { return 1.f / (1.f + __expf(-x)); }
__device__ __forceinline__ float dot4(float4 a, float4 b) {
  return a.x * b.x + a.y * b.y + a.z * b.z + a.w * b.w;
}

__device__ __forceinline__ int lmap(int k, int l) {
  int lr = (k & 2) ? (LL - 1 - l) : l;
  return (k & 1) ? (((lr & 63) << 6) | (lr >> 6)) : lr;
}

// Generic 32x32 LDS tile transpose: src[R][C] -> dst[C][R], both coalesced.
__global__ void k_transp(const float* __restrict__ src, float* __restrict__ dst,
                         int R, int C) {
  __shared__ float tile[32][33];
  int r0 = blockIdx.x * 32, c0 = blockIdx.y * 32;
  int t = threadIdx.x;            // 256
  int tc = t & 31, tr = t >> 5;   // tr 0..7
#pragma unroll
  for (int i = 0; i < 4; ++i) {
    int r = r0 + tr + i * 8;
    if (r < R && c0 + tc < C) tile[tr + i * 8][tc] = src[(size_t)r * C + c0 + tc];
  }
  __syncthreads();
#pragma unroll
  for (int i = 0; i < 4; ++i) {
    int c = c0 + tr + i * 8;
    int r = r0 + tc;
    if (c < C && r < R) dst[(size_t)c * R + r] = tile[tc][tr + i * 8];
  }
}

// K0a: wt[k][c] = in_proj_w[c][k]  (96 x 384)
__global__ void k_wt(const float* __restrict__ w, float* __restrict__ wt) {
  int idx = blockIdx.x * 256 + threadIdx.x;  // 36864
  if (idx < 96 * 384) {
    int k = idx / 384, c = idx % 384;
    wt[idx] = w[c * 96 + k];
  }
}

// K0b: xt[k][row] = x[row][k]  (96 x 16384), 64x32 LDS tile transpose
__global__ void k_xt(const float* __restrict__ x, float* __restrict__ xt) {
  __shared__ float tile[32][65];
  int r0 = blockIdx.x * 64, k0 = blockIdx.y * 32;
  int t = threadIdx.x;  // 256
#pragma unroll
  for (int ii = 0; ii < 8; ++ii) {
    int i = (t >> 5) + ii * 8, j = t & 31;
    tile[j][i] = x[(size_t)(r0 + i) * 96 + k0 + j];
  }
  __syncthreads();
#pragma unroll
  for (int jj = 0; jj < 8; ++jj) {
    int j = (t >> 6) + jj * 4, i = t & 63;
    xt[(size_t)(k0 + j) * NR + r0 + i] = tile[j][i];
  }
}

// K1: xz = x @ in_proj_w.T via xt/wt. Lane = 4 rows (f4, coalesced), wave-uniform
// scalar weight loads.
__global__ void k_inproj(const float* __restrict__ xt, const float* __restrict__ wt,
                         float* __restrict__ xi, float* __restrict__ z) {
  int t = threadIdx.x;
  int wv = t >> 6, lane = t & 63;
  int rq = blockIdx.x * 256 + wv * 64 + lane;   // float4-row index (row = rq*4)
  int c0 = blockIdx.y * 8;
  const float4* xt4 = (const float4*)xt;
  float4 acc[8];
#pragma unroll
  for (int c = 0; c < 8; ++c) acc[c] = make_float4(0.f, 0.f, 0.f, 0.f);
  for (int k = 0; k < 96; ++k) {
    float4 xv = xt4[(size_t)k * (NR / 4) + rq];
    const float* wr = wt + k * 384 + c0;  // wave-uniform -> s_load
#pragma unroll
    for (int c = 0; c < 8; ++c) {
      float w = wr[c];
      acc[c].x += w * xv.x; acc[c].y += w * xv.y;
      acc[c].z += w * xv.z; acc[c].w += w * xv.w;
    }
  }
  float* dst; int cc;
  if (c0 < DIv) { dst = xi; cc = c0; } else { dst = z; cc = c0 - DIv; }
#pragma unroll
  for (int li = 0; li < 4; ++li) {
    size_t row = (size_t)rq * 4 + li;
    float4 v0, v1;
    v0.x = (&acc[0].x)[li]; v0.y = (&acc[1].x)[li];
    v0.z = (&acc[2].x)[li]; v0.w = (&acc[3].x)[li];
    v1.x = (&acc[4].x)[li]; v1.y = (&acc[5].x)[li];
    v1.z = (&acc[6].x)[li]; v1.w = (&acc[7].x)[li];
    float4* o4 = (float4*)(dst + row * DIv + cc);
    o4[0] = v0; o4[1] = v1;
  }
}

// K2: xc = silu(dwconv3x3(xi) + conv_b), channel-last
__global__ void k_dwconv(const float* __restrict__ xi, const float* __restrict__ cw,
                         const float* __restrict__ cb, float* __restrict__ xc) {
  size_t idx = (size_t)blockIdx.x * 256 + threadIdx.x;  // B*L*DI
  int d = (int)(idx % DIv);
  int l = (int)((idx / DIv) % LL);
  int b = (int)(idx / ((size_t)DIv * LL));
  int i = l >> 6, j = l & 63;
  float s = cb[d];
#pragma unroll
  for (int di = 0; di < 3; ++di) {
    int ii = i + di - 1;
    if ((unsigned)ii >= (unsigned)HH) continue;
#pragma unroll
    for (int dj = 0; dj < 3; ++dj) {
      int jj = j + dj - 1;
      if ((unsigned)jj >= (unsigned)WW) continue;
      s += xi[((size_t)b * LL + ii * WW + jj) * DIv + d] * cw[d * 9 + di * 3 + dj];
    }
  }
  xc[idx] = s * sigf(s);
}

// K3pre-a: spatial transpose per (d,b): xcTs[d][b][j*64+i] = xcT[d][b][i*64+j]
__global__ void k_spt(const float* __restrict__ xcT, float* __restrict__ xcTs) {
  __shared__ float tile[64][65];
  int d = blockIdx.x >> 2, b = blockIdx.x & 3;
  int t = threadIdx.x;  // 256
  const float* src = xcT + (size_t)d * NR + b * LL;
  float* dst = xcTs + (size_t)d * NR + b * LL;
#pragma unroll
  for (int it = 0; it < 16; ++it) {
    int idx = it * 256 + t;
    tile[idx >> 6][idx & 63] = src[idx];
  }
  __syncthreads();
#pragma unroll
  for (int it = 0; it < 16; ++it) {
    int idx = it * 256 + t;
    dst[idx] = tile[idx & 63][idx >> 6];
  }
}

// K3pre-b: wcatT[p][d][76]: cols 0..37 = w_{k=p}[c][d], 38..75 = w_{k=p+2}[c][d]
__global__ void k_wcat(const float* __restrict__ xpw, float* __restrict__ wcatT) {
  int idx = blockIdx.x * 256 + threadIdx.x;  // 2*192*76 = 29184
  if (idx < 2 * 192 * 76) {
    int p = idx / (192 * 76);
    int rem = idx % (192 * 76);
    int d = rem / 76, j = rem % 76;
    int k = (j >= 38 ? 2 : 0) + p;
    int c = (j >= 38) ? j - 38 : j;
    wcatT[idx] = xpw[((size_t)(k * 38 + c)) * DIv + d];
  }
}

// K3a: x_dbl via transposed operands; writes padded stride-40 layout:
// phys col = c + (c>=6 ? 2 : 0)  (dt 0-5, B 8-23, C 24-39). Also zeroes pad cols 6,7.
__global__ void k_xdbl2(const float* __restrict__ xcT, const float* __restrict__ xcTs,
                        const float* __restrict__ wcatT, float* __restrict__ xdbl) {
  int t = threadIdx.x;                  // 256
  int rq = blockIdx.x * 256 + t;        // 0..1023 f4-row within b
  int jg = blockIdx.y;                  // 0..18 -> cols jg*4..jg*4+3
  int pb = blockIdx.z;                  // p*4 + b
  int p = pb >> 2, b = pb & 3;
  const float4* A = (const float4*)(p ? xcTs : xcT);
  const float* wbase = wcatT + (size_t)p * 192 * 76 + jg * 4;
  float4 acc[4];
#pragma unroll
  for (int j = 0; j < 4; ++j) acc[j] = make_float4(0.f, 0.f, 0.f, 0.f);
  for (int d = 0; d < 192; ++d) {
    float4 xv = A[(size_t)d * (NR / 4) + b * 1024 + rq];
    const float* wr = wbase + d * 76;   // wave-uniform -> s_load
#pragma unroll
    for (int j = 0; j < 4; ++j) {
      float w = wr[j];
      acc[j].x += w * xv.x; acc[j].y += w * xv.y;
      acc[j].z += w * xv.z; acc[j].w += w * xv.w;
    }
  }
#pragma unroll
  for (int li = 0; li < 4; ++li) {
    int r = rq * 4 + li;
#pragma unroll
    for (int j = 0; j < 4; ++j) {
      int col = jg * 4 + j;
      int kk = (col >= 38) ? (2 + p) : p;
      int c = (col >= 38) ? col - 38 : col;
      int l = (col >= 38) ? (LL - 1 - r) : r;
      int phys = c + (c >= 6 ? 2 : 0);
      size_t ro = (((size_t)(b * KKv + kk)) * LL + l) * XDS;
      xdbl[ro + phys] = (&acc[j].x)[li];
      if (col == 5) { xdbl[ro + 6] = 0.f; xdbl[ro + 7] = 0.f; }
    }
  }
}

// K3b: delta[b,k,l,d] = softplus(dts @ dt_projs_w + dt_projs_b)
__global__ void k_delta(const float* __restrict__ xdbl, const float* __restrict__ dtw,
                        const float* __restrict__ dtb, float* __restrict__ delta) {
  size_t idx = (size_t)blockIdx.x * 256 + threadIdx.x;  // B*K*L*DI
  int d = (int)(idx % DIv);
  size_t bkl = idx / DIv;              // (b*K+k)*L + l
  int k = (int)((bkl / LL) % KKv);
  const float* xr = xdbl + bkl * XDS;
  const float* wr = dtw + ((size_t)k * DIv + d) * DTRv;
  float s = dtb[k * DIv + d];
#pragma unroll
  for (int r = 0; r < DTRv; ++r) s += xr[r] * wr[r];
  delta[idx] = (s > 20.f) ? s : __logf(1.f + __expf(s));
}

// K4a: chunked scan pass 1 with LDS-staged inputs. Block 256 = 64 d x 4 nq;
// grid (NC*3, K, B). 16-l tiles staged into LDS (de, xv, B/C).
__global__ void k_scan1(const float* __restrict__ delta, const float* __restrict__ xdbl,
                        const float* __restrict__ xc, const float* __restrict__ alogs,
                        float* __restrict__ S, float* __restrict__ P) {
  int bx = blockIdx.x;
  int c = bx / 3, dblk = bx % 3;
  int k = blockIdx.y, b = blockIdx.z;
  int t = threadIdx.x, dl = t >> 2, nq = t & 3;
  int d = dblk * 64 + dl;
  __shared__ float de_s[16][64], xv_s[16][64], bc_s[16][32];
  float A[4];
#pragma unroll
  for (int j = 0; j < 4; ++j)
    A[j] = -__expf(alogs[(size_t)(k * DIv + d) * DSn + nq * 4 + j]);
  size_t bkL = (size_t)(b * KKv + k) * LL;
  const float* dp = delta + bkL * DIv;
  const float* xq = xdbl + bkL * XDS;
  const float* xcb = xc + (size_t)b * LL * DIv;
  float h[4] = {0.f, 0.f, 0.f, 0.f}, sA[4] = {0.f, 0.f, 0.f, 0.f};
  int l0 = c * CHK;
  for (int tile = 0; tile < CHK / 16; ++tile) {
    int lt = l0 + tile * 16;
    __syncthreads();
    {
      int r = t >> 4, q = t & 15;
      int l = lt + r;
      *(float4*)&de_s[r][q * 4] = *(const float4*)(dp + (size_t)l * DIv + dblk * 64 + q * 4);
      int lc = lmap(k, l);
      *(float4*)&xv_s[r][q * 4] = *(const float4*)(xcb + (size_t)lc * DIv + dblk * 64 + q * 4);
      if (t < 128) {
        int r2 = t >> 3, q2 = t & 7;
        *(float4*)&bc_s[r2][q2 * 4] = *(const float4*)(xq + (size_t)(lt + r2) * XDS + 8 + q2 * 4);
      }
    }
    __syncthreads();
#pragma unroll
    for (int i2 = 0; i2 < 16; ++i2) {
      float de = de_s[i2][dl];
      float xv = xv_s[i2][dl];
      float4 Bv = *(float4*)&bc_s[i2][nq * 4];
      float db = de * xv;
#pragma unroll
      for (int j = 0; j < 4; ++j) {
        float u = de * A[j];
        sA[j] += u;
        h[j] = h[j] * __expf(u) + db * (&Bv.x)[j];
      }
    }
  }
  size_t o = ((((size_t)(b * KKv + k) * NC + c) * 3 + dblk) * 1024) + (size_t)t * 4;
  float4 hs, ps;
#pragma unroll
  for (int j = 0; j < 4; ++j) { (&hs.x)[j] = h[j]; (&ps.x)[j] = __expf(sA[j]); }
  *(float4*)(S + o) = hs;
  *(float4*)(P + o) = ps;
}

// K4b: sequential chunk combine (float4 per thread). Rewrites S[c] <- Hin[c].
__global__ void k_scan2(float* __restrict__ S, const float* __restrict__ P) {
  int dblk = blockIdx.x, k = blockIdx.y, b = blockIdx.z;
  int t = threadIdx.x;  // 256
  size_t base = (((size_t)(b * KKv + k) * NC) * 3 + dblk) * 1024 + (size_t)t * 4;
  float4 h = make_float4(0.f, 0.f, 0.f, 0.f);
  for (int c = 0; c < NC; ++c) {
    size_t o = base + (size_t)c * 3 * 1024;
    float4 s = *(float4*)(S + o), p = *(float4*)(P + o);
    *(float4*)(S + o) = h;  // Hin for chunk c
    h.x = s.x + p.x * h.x; h.y = s.y + p.y * h.y;
    h.z = s.z + p.z * h.z; h.w = s.w + p.w * h.w;
  }
}

// K4c: chunked scan pass 3 — LDS-staged; width-4 shuffle for y.
__global__ void k_scan3(const float* __restrict__ delta, const float* __restrict__ xdbl,
                        const float* __restrict__ xc, const float* __restrict__ alogs,
                        const float* __restrict__ Hin, float* __restrict__ ys) {
  int bx = blockIdx.x;
  int c = bx / 3, dblk = bx % 3;
  int k = blockIdx.y, b = blockIdx.z;
  int t = threadIdx.x, dl = t >> 2, nq = t & 3;
  int d = dblk * 64 + dl;
  __shared__ float de_s[16][64], xv_s[16][64], bc_s[16][32];
  float A[4];
#pragma unroll
  for (int j = 0; j < 4; ++j)
    A[j] = -__expf(alogs[(size_t)(k * DIv + d) * DSn + nq * 4 + j]);
  size_t bkL = (size_t)(b * KKv + k) * LL;
  const float* dp = delta + bkL * DIv;
  const float* xq = xdbl + bkL * XDS;
  const float* xcb = xc + (size_t)b * LL * DIv;
  float* yp = ys + bkL * DIv + d;
  size_t o = ((((size_t)(b * KKv + k) * NC + c) * 3 + dblk) * 1024) + (size_t)t * 4;
  float4 h4 = *(const float4*)(Hin + o);
  float h[4] = {h4.x, h4.y, h4.z, h4.w};
  int l0 = c * CHK;
  for (int tile = 0; tile < CHK / 16; ++tile) {
    int lt = l0 + tile * 16;
    __syncthreads();
    {
      int r = t >> 4, q = t & 15;
      int l = lt + r;
      *(float4*)&de_s[r][q * 4] = *(const float4*)(dp + (size_t)l * DIv + dblk * 64 + q * 4);
      int lc = lmap(k, l);
      *(float4*)&xv_s[r][q * 4] = *(const float4*)(xcb + (size_t)lc * DIv + dblk * 64 + q * 4);
      if (t < 128) {
        int r2 = t >> 3, q2 = t & 7;
        *(float4*)&bc_s[r2][q2 * 4] = *(const float4*)(xq + (size_t)(lt + r2) * XDS + 8 + q2 * 4);
      }
    }
    __syncthreads();
#pragma unroll
    for (int i2 = 0; i2 < 16; ++i2) {
      float de = de_s[i2][dl];
      float xv = xv_s[i2][dl];
      float4 Bv = *(float4*)&bc_s[i2][nq * 4];
      float4 Cv = *(float4*)&bc_s[i2][16 + nq * 4];
      float db = de * xv;
      float p = 0.f;
#pragma unroll
      for (int j = 0; j < 4; ++j) {
        h[j] = h[j] * __expf(de * A[j]) + db * (&Bv.x)[j];
        p += h[j] * (&Cv.x)[j];
      }
      p += __shfl_down(p, 2, 4);
      p += __shfl_down(p, 1, 4);
      if (nq == 0) yp[(size_t)(lt + i2) * DIv] = p;
    }
  }
}

// K5+K6 fused: merge 4 directions + D*x skip, LayerNorm(DI), * silu(z) -> ygt
__global__ void k_comln(const float* __restrict__ ys, const float* __restrict__ xc,
                        const float* __restrict__ Ds, const float* __restrict__ z,
                        const float* __restrict__ g, const float* __restrict__ be,
                        float* __restrict__ out) {
  int bl = blockIdx.x;            // b*L + l
  int b = bl >> 12, l = bl & 4095;
  int t = threadIdx.x;            // 64
  int lT = ((l & 63) << 6) | (l >> 6);
  size_t base = (size_t)b * KKv * LL * DIv;
  const float* r0 = ys + base + (size_t)l * DIv;
  const float* r2 = ys + base + ((size_t)2 * LL + (LL - 1 - l)) * DIv;
  const float* r1 = ys + base + ((size_t)1 * LL + lT) * DIv;
  const float* r3 = ys + base + ((size_t)3 * LL + (LL - 1 - lT)) * DIv;
  const float* xr = xc + ((size_t)b * LL + l) * DIv;
  float v[3];
  float s = 0.f, q = 0.f;
#pragma unroll
  for (int cc = 0; cc < 3; ++cc) {
    int d = t + cc * 64;
    float sd = Ds[d] + Ds[DIv + d] + Ds[2 * DIv + d] + Ds[3 * DIv + d];
    float vv = r0[d] + r2[d] + r1[d] + r3[d] + sd * xr[d];
    v[cc] = vv; s += vv; q += vv * vv;
  }
#pragma unroll
  for (int o = 32; o > 0; o >>= 1) { s += __shfl_xor(s, o, 64); q += __shfl_xor(q, o, 64); }
  float m = s / DIv;
  float var = q / DIv - m * m;
  float rs = rsqrtf(var + 1e-5f);
  const float* zr = z + (size_t)bl * DIv;
  float* orow = out + (size_t)bl * DIv;
#pragma unroll
  for (int cc = 0; cc < 3; ++cc) {
    int d = t + cc * 64;
    float zz = zr[d];
    float val = (v[cc] - m) * rs * g[d] + be[d];
    orow[d] = val * zz * sigf(zz);
  }
}

// K7: out0 = ygated @ out_proj_w.T via ygtT/opwT. 4 cols/block, lanes = rows.
__global__ void k_outproj2(const float* __restrict__ ygtT, const float* __restrict__ opwT,
                           float* __restrict__ out0) {
  int t = threadIdx.x;                    // 256
  int rq = blockIdx.x * 256 + t;          // f4-row index
  int c0 = blockIdx.y * 4;
  const float4* x4 = (const float4*)ygtT;
  float4 acc[4];
#pragma unroll
  for (int c = 0; c < 4; ++c) acc[c] = make_float4(0.f, 0.f, 0.f, 0.f);
  for (int k = 0; k < DIv; ++k) {
    float4 xv = x4[(size_t)k * (NR / 4) + rq];
    const float* wr = opwT + k * DMv + c0;  // wave-uniform
#pragma unroll
    for (int c = 0; c < 4; ++c) {
      float w = wr[c];
      acc[c].x += w * xv.x; acc[c].y += w * xv.y;
      acc[c].z += w * xv.z; acc[c].w += w * xv.w;
    }
  }
#pragma unroll
  for (int li = 0; li < 4; ++li) {
    float4 v;
    v.x = (&acc[0].x)[li]; v.y = (&acc[1].x)[li];
    v.z = (&acc[2].x)[li]; v.w = (&acc[3].x)[li];
    *(float4*)(out0 + ((size_t)rq * 4 + li) * DMv + c0) = v;
  }
}

// K8: hcl = silu(ygated @ ffn_in_w.T + b) via ygtT/fiwT. 16 cols/block.
__global__ void k_ffnin2(const float* __restrict__ ygtT, const float* __restrict__ fiwT,
                         const float* __restrict__ bias, float* __restrict__ hcl) {
  int t = threadIdx.x;                    // 256
  int rq = blockIdx.x * 256 + t;
  int c0 = blockIdx.y * 16;
  const float4* x4 = (const float4*)ygtT;
  float4 acc[16];
#pragma unroll
  for (int c = 0; c < 16; ++c) acc[c] = make_float4(0.f, 0.f, 0.f, 0.f);
  for (int k = 0; k < DIv; ++k) {
    float4 xv = x4[(size_t)k * (NR / 4) + rq];
    const float* wr = fiwT + k * HIDv + c0;  // wave-uniform
#pragma unroll
    for (int c = 0; c < 16; ++c) {
      float w = wr[c];
      acc[c].x += w * xv.x; acc[c].y += w * xv.y;
      acc[c].z += w * xv.z; acc[c].w += w * xv.w;
    }
  }
#pragma unroll
  for (int li = 0; li < 4; ++li) {
    size_t row = (size_t)rq * 4 + li;
#pragma unroll
    for (int cc = 0; cc < 4; ++cc) {
      float4 v;
#pragma unroll
      for (int j = 0; j < 4; ++j) {
        float s = (&acc[cc * 4 + j].x)[li] + bias[c0 + cc * 4 + j];
        (&v.x)[j] = s * sigf(s);
      }
      *(float4*)(hcl + row * HIDv + c0 + cc * 4) = v;
    }
  }
}

// K9 (tiled): hc2 = (1 + w1)*hc(center) + dwconv3(hc) + dwconv5(hc), fused 5x5 stencil.
constexpr int TS = 16, CG = 32, TW = TS + 4;  // TW=20
__global__ void k_ffnconv(const float* __restrict__ hcl, const float* __restrict__ w1,
                          const float* __restrict__ w3, const float* __restrict__ w5,
                          float* __restrict__ hc2) {
  int tile = blockIdx.x;            // 0..15 (4x4 spatial tiles)
  int cg = blockIdx.y, b = blockIdx.z;
  int t = threadIdx.x;              // 256
  int ti0 = (tile >> 2) * TS, tj0 = (tile & 3) * TS;
  __shared__ float sm[TW * TW * CG];

  for (int e = t; e < TW * TW * CG; e += 256) {
    int ec = e & 31;
    int sp = e >> 5;                // 0..399
    int hi = sp / TW, hj = sp % TW;
    int gi = ti0 + hi - 2, gj = tj0 + hj - 2;
    float v = 0.f;
    if ((unsigned)gi < (unsigned)HH && (unsigned)gj < (unsigned)WW)
      v = hcl[((size_t)b * LL + gi * WW + gj) * HIDv + cg * CG + ec];
    sm[e] = v;
  }

  int c = t & 31;
  int cglob = cg * CG + c;
  float wc[25];
#pragma unroll
  for (int di = 0; di < 5; ++di)
#pragma unroll
    for (int dj = 0; dj < 5; ++dj) {
      float w = w5[cglob * 25 + di * 5 + dj];
      if (di >= 1 && di <= 3 && dj >= 1 && dj <= 3)
        w += w3[cglob * 9 + (di - 1) * 3 + (dj - 1)];
      if (di == 2 && dj == 2) w += 1.f + w1[cglob];
      wc[di * 5 + dj] = w;
    }
  __syncthreads();

  int s0 = t >> 5;  // 0..7
  for (int i = 0; i < 32; ++i) {
    int p = s0 + (i << 3);          // 0..255
    int r = p >> 4, q = p & 15;
    float s = 0.f;
#pragma unroll
    for (int di = 0; di < 5; ++di)
#pragma unroll
      for (int dj = 0; dj < 5; ++dj)
        s += sm[((r + di) * TW + (q + dj)) * CG + c] * wc[di * 5 + dj];
    hc2[((size_t)b * LL + (ti0 + r) * WW + (tj0 + q)) * HIDv + cglob] = s;
  }
}

// K10: LayerNorm over HID
__global__ void k_ln2(const float* __restrict__ hc2, const float* __restrict__ g,
                      const float* __restrict__ be, float* __restrict__ hn) {
  int bl = blockIdx.x;
  int t = threadIdx.x;  // 256
  const float* xr = hc2 + (size_t)bl * HIDv;
  float v[3];
  float s = 0.f, q = 0.f;
#pragma unroll
  for (int cc = 0; cc < 3; ++cc) { v[cc] = xr[t + cc * 256]; s += v[cc]; q += v[cc] * v[cc]; }
#pragma unroll
  for (int o = 32; o > 0; o >>= 1) { s += __shfl_xor(s, o, 64); q += __shfl_xor(q, o, 64); }
  __shared__ float rs_[4], rq_[4];
  int wid = t >> 6;
  if ((t & 63) == 0) { rs_[wid] = s; rq_[wid] = q; }
  __syncthreads();
  s = rs_[0] + rs_[1] + rs_[2] + rs_[3];
  q = rq_[0] + rq_[1] + rq_[2] + rq_[3];
  float m = s / HIDv;
  float var = q / HIDv - m * m;
  float r = rsqrtf(var + 1e-5f);
#pragma unroll
  for (int cc = 0; cc < 3; ++cc) {
    int c = t + cc * 256;
    hn[(size_t)bl * HIDv + c] = (v[cc] - m) * r * g[c] + be[c];
  }
}

// K11: d_out = out0 + skip * (hn @ ffn_out_w.T + b) via hnT/fowT. 8 cols/block, block 128.
__global__ void k_final2(const float* __restrict__ hnT, const float* __restrict__ fowT,
                         const float* __restrict__ bias, const float* __restrict__ out0,
                         const float* __restrict__ skip, float* __restrict__ dout) {
  int t = threadIdx.x;                    // 128
  int rq = blockIdx.x * 128 + t;          // f4-row
  int c0 = blockIdx.y * 8;
  const float4* x4 = (const float4*)hnT;
  float4 acc[8];
#pragma unroll
  for (int c = 0; c < 8; ++c) acc[c] = make_float4(0.f, 0.f, 0.f, 0.f);
  for (int k = 0; k < HIDv; ++k) {
    float4 xv = x4[(size_t)k * (NR / 4) + rq];
    const float* wr = fowT + k * DMv + c0;  // wave-uniform
#pragma unroll
    for (int c = 0; c < 8; ++c) {
      float w = wr[c];
      acc[c].x += w * xv.x; acc[c].y += w * xv.y;
      acc[c].z += w * xv.z; acc[c].w += w * xv.w;
    }
  }
  float sk = skip[0];
#pragma unroll
  for (int li = 0; li < 4; ++li) {
    size_t row = (size_t)rq * 4 + li;
#pragma unroll
    for (int cc = 0; cc < 2; ++cc) {
      float4 v;
#pragma unroll
      for (int j = 0; j < 4; ++j) {
        int c = c0 + cc * 4 + j;
        (&v.x)[j] = out0[row * DMv + c] + sk * ((&acc[cc * 4 + j].x)[li] + bias[c]);
      }
      *(float4*)(dout + row * DMv + c0 + cc * 4) = v;
    }
  }
}

extern "C" void kernel_launch(void* const* d_in, const int* in_sizes, int n_in,
                              void* d_out, int out_size, void* d_ws, size_t ws_size,
                              hipStream_t stream) {
  const float* x        = (const float*)d_in[0];
  const float* in_w     = (const float*)d_in[1];
  const float* conv_w   = (const float*)d_in[2];
  const float* conv_b   = (const float*)d_in[3];
  const float* xpw      = (const float*)d_in[4];
  const float* dtw      = (const float*)d_in[5];
  const float* dtb      = (const float*)d_in[6];
  const float* alogs    = (const float*)d_in[7];
  const float* Ds       = (const float*)d_in[8];
  const float* ong      = (const float*)d_in[9];
  const float* onb      = (const float*)d_in[10];
  const float* opw      = (const float*)d_in[11];
  const float* fiw      = (const float*)d_in[12];
  const float* fib      = (const float*)d_in[13];
  const float* dw1      = (const float*)d_in[14];
  const float* dw3      = (const float*)d_in[15];
  const float* dw5      = (const float*)d_in[16];
  const float* flg      = (const float*)d_in[17];
  const float* flb      = (const float*)d_in[18];
  const float* fow      = (const float*)d_in[19];
  const float* fob      = (const float*)d_in[20];
  const float* skip     = (const float*)d_in[21];

  // Workspace layout (aliased; ~150 MB)
  float* ws    = (float*)d_ws;
  float* xi    = ws;                 // -> S/P during scan -> ygtT
  float* z     = xi + S_xi;
  float* xc    = z + S_xi;           // -> ygt
  float* xdbl  = xc + S_xi;          // -> out0
  float* delta = xdbl + S_xdbl;      // xt/wt scratch -> delta -> hcl -> hn
  float* ys    = delta + S_big;      // xcT/xcTs scratch -> ys -> hc2 -> hnT
  float* wtiny = ys + S_big;         // persistent small weight transposes
  float* fiwT  = wtiny;              // 192*768 = 147456
  float* opwT  = fiwT + 147456;      // 192*96  = 18432
  float* fowT  = opwT + 18432;       // 768*96  = 73728
  float* wcatT = fowT + 73728;       // 2*192*76 = 29184

  // Small weight transposes (persist whole launch)
  k_transp<<<dim3(24, 6), 256, 0, stream>>>(fiw, fiwT, HIDv, DIv);   // 768x192 -> 192x768
  k_transp<<<dim3(3, 6), 256, 0, stream>>>(opw, opwT, DMv, DIv);     // 96x192  -> 192x96
  k_transp<<<dim3(3, 24), 256, 0, stream>>>(fow, fowT, DMv, HIDv);   // 96x768  -> 768x96
  k_wcat<<<114, 256, 0, stream>>>(xpw, wcatT);

  // In-proj via transposed operands (xt, wt live in the not-yet-used delta region)
  float* xt = delta;                       // 96*16384 floats
  float* wt = delta + 1600000;             // 36,864 floats (within S_big)
  k_wt<<<(96 * 384 + 255) / 256, 256, 0, stream>>>(in_w, wt);
  dim3 gxt(NR / 64, 3);
  k_xt<<<gxt, 256, 0, stream>>>(x, xt);
  dim3 gip(NR / 1024, 48);
  k_inproj<<<gip, 256, 0, stream>>>(xt, wt, xi, z);

  k_dwconv<<<(BB * LL * DIv) / 256, 256, 0, stream>>>(xi, conv_w, conv_b, xc);

  // x_dbl GEMM via transposed operands (xcT/xcTs in ys region, free until k_scan3)
  float* xcT  = ys;                  // 192*16384 = 3,145,728
  float* xcTs = ys + S_xi;           // 3,145,728 (6.3M < S_big)
  k_transp<<<dim3(512, 6), 256, 0, stream>>>(xc, xcT, NR, DIv);
  k_spt<<<DIv * BB, 256, 0, stream>>>(xcT, xcTs);
  dim3 gxd(4, 19, 8);                // rq-blocks x col-groups x (p*4+b)
  k_xdbl2<<<gxd, 256, 0, stream>>>(xcT, xcTs, wcatT, xdbl);

  k_delta<<<(BB * KKv * LL * DIv) / 256, 256, 0, stream>>>(xdbl, dtw, dtb, delta);

  // Chunked scan: S/P buffers alias xi (dead until ygtT lands there)
  float* Sbuf = xi;                  // S_sp floats
  float* Pbuf = xi + S_sp;           // S_sp floats (S_sp*2 == S_xi exactly)
  dim3 gs13(NC * 3, KKv, BB);        // 1536 blocks, 64d x 4nq threads
  dim3 gs2(3, KKv, BB);              // 48 blocks (tiny)
  k_scan1<<<gs13, 256, 0, stream>>>(delta, xdbl, xc, alogs, Sbuf, Pbuf);
  k_scan2<<<gs2, 256, 0, stream>>>(Sbuf, Pbuf);  // S <- Hin
  k_scan3<<<gs13, 256, 0, stream>>>(delta, xdbl, xc, alogs, Sbuf, ys);

  // Fused combine + LayerNorm + silu-gate -> ygt
  float* ygt = xc;
  k_comln<<<BB * LL, 64, 0, stream>>>(ys, xc, Ds, z, ong, onb, ygt);

  // Transpose ygt (16384x192 -> 192x16384) into xi (S/P dead)
  float* ygtT = xi;
  k_transp<<<dim3(512, 6), 256, 0, stream>>>(ygt, ygtT, NR, DIv);

  float* out0 = xdbl;
  dim3 gop(NR / 1024, DMv / 4);      // (16, 24)
  k_outproj2<<<gop, 256, 0, stream>>>(ygtT, opwT, out0);
  float* hcl = delta;
  dim3 gfi(NR / 1024, HIDv / 16);    // (16, 48)
  k_ffnin2<<<gfi, 256, 0, stream>>>(ygtT, fiwT, fib, hcl);
  float* hc2 = ys;
  dim3 gc(16, HIDv / CG, BB);        // 16 spatial tiles x 24 ch-groups x 4
  k_ffnconv<<<gc, 256, 0, stream>>>(hcl, dw1, dw3, dw5, hc2);
  float* hn = delta;  // hcl dead after k_ffnconv
  k_ln2<<<BB * LL, 256, 0, stream>>>(hc2, flg, flb, hn);

  // Transpose hn (16384x768 -> 768x16384) into ys (hc2 dead)
  float* hnT = ys;
  k_transp<<<dim3(512, 24), 256, 0, stream>>>(hn, hnT, NR, HIDv);

  dim3 gfn(NR / 512, DMv / 8);       // (32, 12), block 128
  k_final2<<<gfn, 128, 0, stream>>>(hnT, fowT, fob, out0, skip, (float*)d_out);
}

// Round 11
// 608.025 us; speedup vs baseline: 2.9923x; 1.0326x over previous
//
#include <hip/hip_runtime.h>
#include <hip/hip_bf16.h>

constexpr int BB = 4, HH = 64, WW = 64, DMv = 96;
constexpr int DSn = 16, DIv = 192, DTRv = 6, KKv = 4, HIDv = 768;
constexpr int LL = 4096;
constexpr int NC = 32, CHK = LL / NC;       // 32 chunks of 128
constexpr int NR = BB * LL;                 // 16384 rows
constexpr int XDS = 40;                     // padded xdbl row stride (dt 0-5, B 8-23, C 24-39)

constexpr size_t S_xi   = (size_t)BB * LL * DIv;          // 3,145,728
constexpr size_t S_xdbl = (size_t)BB * KKv * LL * XDS;    // 2,621,440
constexpr size_t S_big  = (size_t)BB * KKv * LL * DIv;    // 12,582,912
constexpr size_t S_sp   = (size_t)BB * KKv * NC * DIv * DSn;  // 1,572,864 (= S_xi/2)

__device__ __forceinline__ float sigf(float x) { return 1.f / (1.f + __expf(-x)); }

__device__ __forceinline__ int lmap(int k, int l) {
  int lr = (k & 2) ? (LL - 1 - l) : l;
  return (k & 1) ? (((lr & 63) << 6) | (lr >> 6)) : lr;
}

// Generic 32x32 LDS tile transpose: src[R][C] -> dst[C][R], both coalesced.
__global__ void k_transp(const float* __restrict__ src, float* __restrict__ dst,
                         int R, int C) {
  __shared__ float tile[32][33];
  int r0 = blockIdx.x * 32, c0 = blockIdx.y * 32;
  int t = threadIdx.x;            // 256
  int tc = t & 31, tr = t >> 5;   // tr 0..7
#pragma unroll
  for (int i = 0; i < 4; ++i) {
    int r = r0 + tr + i * 8;
    if (r < R && c0 + tc < C) tile[tr + i * 8][tc] = src[(size_t)r * C + c0 + tc];
  }
  __syncthreads();
#pragma unroll
  for (int i = 0; i < 4; ++i) {
    int c = c0 + tr + i * 8;
    int r = r0 + tc;
    if (c < C && r < R) dst[(size_t)c * R + r] = tile[tc][tr + i * 8];
  }
}

// K0a: wt[k][c] = in_proj_w[c][k]  (96 x 384)
__global__ void k_wt(const float* __restrict__ w, float* __restrict__ wt) {
  int idx = blockIdx.x * 256 + threadIdx.x;  // 36864
  if (idx < 96 * 384) {
    int k = idx / 384, c = idx % 384;
    wt[idx] = w[c * 96 + k];
  }
}

// K0b: xt[k][row] = x[row][k]  (96 x 16384), 64x32 LDS tile transpose
__global__ void k_xt(const float* __restrict__ x, float* __restrict__ xt) {
  __shared__ float tile[32][65];
  int r0 = blockIdx.x * 64, k0 = blockIdx.y * 32;
  int t = threadIdx.x;  // 256
#pragma unroll
  for (int ii = 0; ii < 8; ++ii) {
    int i = (t >> 5) + ii * 8, j = t & 31;
    tile[j][i] = x[(size_t)(r0 + i) * 96 + k0 + j];
  }
  __syncthreads();
#pragma unroll
  for (int jj = 0; jj < 8; ++jj) {
    int j = (t >> 6) + jj * 4, i = t & 63;
    xt[(size_t)(k0 + j) * NR + r0 + i] = tile[j][i];
  }
}

// K1: xz = x @ in_proj_w.T via xt/wt. Lane = 4 rows (f4, coalesced), wave-uniform
// scalar weight loads.
__global__ void k_inproj(const float* __restrict__ xt, const float* __restrict__ wt,
                         float* __restrict__ xi, float* __restrict__ z) {
  int t = threadIdx.x;
  int wv = t >> 6, lane = t & 63;
  int rq = blockIdx.x * 256 + wv * 64 + lane;   // float4-row index (row = rq*4)
  int c0 = blockIdx.y * 8;
  const float4* xt4 = (const float4*)xt;
  float4 acc[8];
#pragma unroll
  for (int c = 0; c < 8; ++c) acc[c] = make_float4(0.f, 0.f, 0.f, 0.f);
  for (int k = 0; k < 96; ++k) {
    float4 xv = xt4[(size_t)k * (NR / 4) + rq];
    const float* wr = wt + k * 384 + c0;  // wave-uniform -> s_load
#pragma unroll
    for (int c = 0; c < 8; ++c) {
      float w = wr[c];
      acc[c].x += w * xv.x; acc[c].y += w * xv.y;
      acc[c].z += w * xv.z; acc[c].w += w * xv.w;
    }
  }
  float* dst; int cc;
  if (c0 < DIv) { dst = xi; cc = c0; } else { dst = z; cc = c0 - DIv; }
#pragma unroll
  for (int li = 0; li < 4; ++li) {
    size_t row = (size_t)rq * 4 + li;
    float4 v0, v1;
    v0.x = (&acc[0].x)[li]; v0.y = (&acc[1].x)[li];
    v0.z = (&acc[2].x)[li]; v0.w = (&acc[3].x)[li];
    v1.x = (&acc[4].x)[li]; v1.y = (&acc[5].x)[li];
    v1.z = (&acc[6].x)[li]; v1.w = (&acc[7].x)[li];
    float4* o4 = (float4*)(dst + row * DIv + cc);
    o4[0] = v0; o4[1] = v1;
  }
}

// K2: xc = silu(dwconv3x3(xi) + conv_b), channel-last
__global__ void k_dwconv(const float* __restrict__ xi, const float* __restrict__ cw,
                         const float* __restrict__ cb, float* __restrict__ xc) {
  size_t idx = (size_t)blockIdx.x * 256 + threadIdx.x;  // B*L*DI
  int d = (int)(idx % DIv);
  int l = (int)((idx / DIv) % LL);
  int b = (int)(idx / ((size_t)DIv * LL));
  int i = l >> 6, j = l & 63;
  float s = cb[d];
#pragma unroll
  for (int di = 0; di < 3; ++di) {
    int ii = i + di - 1;
    if ((unsigned)ii >= (unsigned)HH) continue;
#pragma unroll
    for (int dj = 0; dj < 3; ++dj) {
      int jj = j + dj - 1;
      if ((unsigned)jj >= (unsigned)WW) continue;
      s += xi[((size_t)b * LL + ii * WW + jj) * DIv + d] * cw[d * 9 + di * 3 + dj];
    }
  }
  xc[idx] = s * sigf(s);
}

// K3pre-a: spatial transpose per (d,b): xcTs[d][b][j*64+i] = xcT[d][b][i*64+j]
__global__ void k_spt(const float* __restrict__ xcT, float* __restrict__ xcTs) {
  __shared__ float tile[64][65];
  int d = blockIdx.x >> 2, b = blockIdx.x & 3;
  int t = threadIdx.x;  // 256
  const float* src = xcT + (size_t)d * NR + b * LL;
  float* dst = xcTs + (size_t)d * NR + b * LL;
#pragma unroll
  for (int it = 0; it < 16; ++it) {
    int idx = it * 256 + t;
    tile[idx >> 6][idx & 63] = src[idx];
  }
  __syncthreads();
#pragma unroll
  for (int it = 0; it < 16; ++it) {
    int idx = it * 256 + t;
    dst[idx] = tile[idx & 63][idx >> 6];
  }
}

// K3pre-b: wcatT[p][d][76]: cols 0..37 = w_{k=p}[c][d], 38..75 = w_{k=p+2}[c][d]
__global__ void k_wcat(const float* __restrict__ xpw, float* __restrict__ wcatT) {
  int idx = blockIdx.x * 256 + threadIdx.x;  // 2*192*76 = 29184
  if (idx < 2 * 192 * 76) {
    int p = idx / (192 * 76);
    int rem = idx % (192 * 76);
    int d = rem / 76, j = rem % 76;
    int k = (j >= 38 ? 2 : 0) + p;
    int c = (j >= 38) ? j - 38 : j;
    wcatT[idx] = xpw[((size_t)(k * 38 + c)) * DIv + d];
  }
}

// K3a: x_dbl via transposed operands; stride-40 layout, zeroes pad cols 6,7.
__global__ void k_xdbl2(const float* __restrict__ xcT, const float* __restrict__ xcTs,
                        const float* __restrict__ wcatT, float* __restrict__ xdbl) {
  int t = threadIdx.x;                  // 256
  int rq = blockIdx.x * 256 + t;        // 0..1023 f4-row within b
  int jg = blockIdx.y;                  // 0..18 -> cols jg*4..jg*4+3
  int pb = blockIdx.z;                  // p*4 + b
  int p = pb >> 2, b = pb & 3;
  const float4* A = (const float4*)(p ? xcTs : xcT);
  const float* wbase = wcatT + (size_t)p * 192 * 76 + jg * 4;
  float4 acc[4];
#pragma unroll
  for (int j = 0; j < 4; ++j) acc[j] = make_float4(0.f, 0.f, 0.f, 0.f);
  for (int d = 0; d < 192; ++d) {
    float4 xv = A[(size_t)d * (NR / 4) + b * 1024 + rq];
    const float* wr = wbase + d * 76;   // wave-uniform -> s_load
#pragma unroll
    for (int j = 0; j < 4; ++j) {
      float w = wr[j];
      acc[j].x += w * xv.x; acc[j].y += w * xv.y;
      acc[j].z += w * xv.z; acc[j].w += w * xv.w;
    }
  }
#pragma unroll
  for (int li = 0; li < 4; ++li) {
    int r = rq * 4 + li;
#pragma unroll
    for (int j = 0; j < 4; ++j) {
      int col = jg * 4 + j;
      int kk = (col >= 38) ? (2 + p) : p;
      int c = (col >= 38) ? col - 38 : col;
      int l = (col >= 38) ? (LL - 1 - r) : r;
      int phys = c + (c >= 6 ? 2 : 0);
      size_t ro = (((size_t)(b * KKv + kk)) * LL + l) * XDS;
      xdbl[ro + phys] = (&acc[j].x)[li];
      if (col == 5) { xdbl[ro + 6] = 0.f; xdbl[ro + 7] = 0.f; }
    }
  }
}

// K3b: delta[b,k,l,d] = softplus(dts @ dt_projs_w + dt_projs_b)
__global__ void k_delta(const float* __restrict__ xdbl, const float* __restrict__ dtw,
                        const float* __restrict__ dtb, float* __restrict__ delta) {
  size_t idx = (size_t)blockIdx.x * 256 + threadIdx.x;  // B*K*L*DI
  int d = (int)(idx % DIv);
  size_t bkl = idx / DIv;              // (b*K+k)*L + l
  int k = (int)((bkl / LL) % KKv);
  const float* xr = xdbl + bkl * XDS;
  const float* wr = dtw + ((size_t)k * DIv + d) * DTRv;
  float s = dtb[k * DIv + d];
#pragma unroll
  for (int r = 0; r < DTRv; ++r) s += xr[r] * wr[r];
  delta[idx] = (s > 20.f) ? s : __logf(1.f + __expf(s));
}

// K4a: chunked scan pass 1 with LDS-staged inputs. Block 256 = 64 d x 4 nq.
__global__ void k_scan1(const float* __restrict__ delta, const float* __restrict__ xdbl,
                        const float* __restrict__ xc, const float* __restrict__ alogs,
                        float* __restrict__ S, float* __restrict__ P) {
  int bx = blockIdx.x;
  int c = bx / 3, dblk = bx % 3;
  int k = blockIdx.y, b = blockIdx.z;
  int t = threadIdx.x, dl = t >> 2, nq = t & 3;
  int d = dblk * 64 + dl;
  __shared__ float de_s[16][64], xv_s[16][64], bc_s[16][32];
  float A[4];
#pragma unroll
  for (int j = 0; j < 4; ++j)
    A[j] = -__expf(alogs[(size_t)(k * DIv + d) * DSn + nq * 4 + j]);
  size_t bkL = (size_t)(b * KKv + k) * LL;
  const float* dp = delta + bkL * DIv;
  const float* xq = xdbl + bkL * XDS;
  const float* xcb = xc + (size_t)b * LL * DIv;
  float h[4] = {0.f, 0.f, 0.f, 0.f}, sA[4] = {0.f, 0.f, 0.f, 0.f};
  int l0 = c * CHK;
  for (int tile = 0; tile < CHK / 16; ++tile) {
    int lt = l0 + tile * 16;
    __syncthreads();
    {
      int r = t >> 4, q = t & 15;
      int l = lt + r;
      *(float4*)&de_s[r][q * 4] = *(const float4*)(dp + (size_t)l * DIv + dblk * 64 + q * 4);
      int lc = lmap(k, l);
      *(float4*)&xv_s[r][q * 4] = *(const float4*)(xcb + (size_t)lc * DIv + dblk * 64 + q * 4);
      if (t < 128) {
        int r2 = t >> 3, q2 = t & 7;
        *(float4*)&bc_s[r2][q2 * 4] = *(const float4*)(xq + (size_t)(lt + r2) * XDS + 8 + q2 * 4);
      }
    }
    __syncthreads();
#pragma unroll
    for (int i2 = 0; i2 < 16; ++i2) {
      float de = de_s[i2][dl];
      float xv = xv_s[i2][dl];
      float4 Bv = *(float4*)&bc_s[i2][nq * 4];
      float db = de * xv;
#pragma unroll
      for (int j = 0; j < 4; ++j) {
        float u = de * A[j];
        sA[j] += u;
        h[j] = h[j] * __expf(u) + db * (&Bv.x)[j];
      }
    }
  }
  size_t o = ((((size_t)(b * KKv + k) * NC + c) * 3 + dblk) * 1024) + (size_t)t * 4;
  float4 hs, ps;
#pragma unroll
  for (int j = 0; j < 4; ++j) { (&hs.x)[j] = h[j]; (&ps.x)[j] = __expf(sA[j]); }
  *(float4*)(S + o) = hs;
  *(float4*)(P + o) = ps;
}

// K4b: sequential chunk combine (float4 per thread). Rewrites S[c] <- Hin[c].
__global__ void k_scan2(float* __restrict__ S, const float* __restrict__ P) {
  int dblk = blockIdx.x, k = blockIdx.y, b = blockIdx.z;
  int t = threadIdx.x;  // 256
  size_t base = (((size_t)(b * KKv + k) * NC) * 3 + dblk) * 1024 + (size_t)t * 4;
  float4 h = make_float4(0.f, 0.f, 0.f, 0.f);
  for (int c = 0; c < NC; ++c) {
    size_t o = base + (size_t)c * 3 * 1024;
    float4 s = *(float4*)(S + o), p = *(float4*)(P + o);
    *(float4*)(S + o) = h;  // Hin for chunk c
    h.x = s.x + p.x * h.x; h.y = s.y + p.y * h.y;
    h.z = s.z + p.z * h.z; h.w = s.w + p.w * h.w;
  }
}

// K4c: chunked scan pass 3 — LDS-staged; width-4 shuffle for y.
__global__ void k_scan3(const float* __restrict__ delta, const float* __restrict__ xdbl,
                        const float* __restrict__ xc, const float* __restrict__ alogs,
                        const float* __restrict__ Hin, float* __restrict__ ys) {
  int bx = blockIdx.x;
  int c = bx / 3, dblk = bx % 3;
  int k = blockIdx.y, b = blockIdx.z;
  int t = threadIdx.x, dl = t >> 2, nq = t & 3;
  int d = dblk * 64 + dl;
  __shared__ float de_s[16][64], xv_s[16][64], bc_s[16][32];
  float A[4];
#pragma unroll
  for (int j = 0; j < 4; ++j)
    A[j] = -__expf(alogs[(size_t)(k * DIv + d) * DSn + nq * 4 + j]);
  size_t bkL = (size_t)(b * KKv + k) * LL;
  const float* dp = delta + bkL * DIv;
  const float* xq = xdbl + bkL * XDS;
  const float* xcb = xc + (size_t)b * LL * DIv;
  float* yp = ys + bkL * DIv + d;
  size_t o = ((((size_t)(b * KKv + k) * NC + c) * 3 + dblk) * 1024) + (size_t)t * 4;
  float4 h4 = *(const float4*)(Hin + o);
  float h[4] = {h4.x, h4.y, h4.z, h4.w};
  int l0 = c * CHK;
  for (int tile = 0; tile < CHK / 16; ++tile) {
    int lt = l0 + tile * 16;
    __syncthreads();
    {
      int r = t >> 4, q = t & 15;
      int l = lt + r;
      *(float4*)&de_s[r][q * 4] = *(const float4*)(dp + (size_t)l * DIv + dblk * 64 + q * 4);
      int lc = lmap(k, l);
      *(float4*)&xv_s[r][q * 4] = *(const float4*)(xcb + (size_t)lc * DIv + dblk * 64 + q * 4);
      if (t < 128) {
        int r2 = t >> 3, q2 = t & 7;
        *(float4*)&bc_s[r2][q2 * 4] = *(const float4*)(xq + (size_t)(lt + r2) * XDS + 8 + q2 * 4);
      }
    }
    __syncthreads();
#pragma unroll
    for (int i2 = 0; i2 < 16; ++i2) {
      float de = de_s[i2][dl];
      float xv = xv_s[i2][dl];
      float4 Bv = *(float4*)&bc_s[i2][nq * 4];
      float4 Cv = *(float4*)&bc_s[i2][16 + nq * 4];
      float db = de * xv;
      float p = 0.f;
#pragma unroll
      for (int j = 0; j < 4; ++j) {
        h[j] = h[j] * __expf(de * A[j]) + db * (&Bv.x)[j];
        p += h[j] * (&Cv.x)[j];
      }
      p += __shfl_down(p, 2, 4);
      p += __shfl_down(p, 1, 4);
      if (nq == 0) yp[(size_t)(lt + i2) * DIv] = p;
    }
  }
}

// K5+K6 fused: merge 4 directions + D*x skip, LayerNorm(DI), * silu(z) -> ygt
__global__ void k_comln(const float* __restrict__ ys, const float* __restrict__ xc,
                        const float* __restrict__ Ds, const float* __restrict__ z,
                        const float* __restrict__ g, const float* __restrict__ be,
                        float* __restrict__ out) {
  int bl = blockIdx.x;            // b*L + l
  int b = bl >> 12, l = bl & 4095;
  int t = threadIdx.x;            // 64
  int lT = ((l & 63) << 6) | (l >> 6);
  size_t base = (size_t)b * KKv * LL * DIv;
  const float* r0 = ys + base + (size_t)l * DIv;
  const float* r2 = ys + base + ((size_t)2 * LL + (LL - 1 - l)) * DIv;
  const float* r1 = ys + base + ((size_t)1 * LL + lT) * DIv;
  const float* r3 = ys + base + ((size_t)3 * LL + (LL - 1 - lT)) * DIv;
  const float* xr = xc + ((size_t)b * LL + l) * DIv;
  float v[3];
  float s = 0.f, q = 0.f;
#pragma unroll
  for (int cc = 0; cc < 3; ++cc) {
    int d = t + cc * 64;
    float sd = Ds[d] + Ds[DIv + d] + Ds[2 * DIv + d] + Ds[3 * DIv + d];
    float vv = r0[d] + r2[d] + r1[d] + r3[d] + sd * xr[d];
    v[cc] = vv; s += vv; q += vv * vv;
  }
#pragma unroll
  for (int o = 32; o > 0; o >>= 1) { s += __shfl_xor(s, o, 64); q += __shfl_xor(q, o, 64); }
  float m = s / DIv;
  float var = q / DIv - m * m;
  float rs = rsqrtf(var + 1e-5f);
  const float* zr = z + (size_t)bl * DIv;
  float* orow = out + (size_t)bl * DIv;
#pragma unroll
  for (int cc = 0; cc < 3; ++cc) {
    int d = t + cc * 64;
    float zz = zr[d];
    float val = (v[cc] - m) * rs * g[d] + be[d];
    orow[d] = val * zz * sigf(zz);
  }
}

// K7: out0 = ygated @ out_proj_w.T via ygtT/opwT. 4 cols/block, lanes = rows.
__global__ void k_outproj2(const float* __restrict__ ygtT, const float* __restrict__ opwT,
                           float* __restrict__ out0) {
  int t = threadIdx.x;                    // 256
  int rq = blockIdx.x * 256 + t;          // f4-row index
  int c0 = blockIdx.y * 4;
  const float4* x4 = (const float4*)ygtT;
  float4 acc[4];
#pragma unroll
  for (int c = 0; c < 4; ++c) acc[c] = make_float4(0.f, 0.f, 0.f, 0.f);
  for (int k = 0; k < DIv; ++k) {
    float4 xv = x4[(size_t)k * (NR / 4) + rq];
    const float* wr = opwT + k * DMv + c0;  // wave-uniform
#pragma unroll
    for (int c = 0; c < 4; ++c) {
      float w = wr[c];
      acc[c].x += w * xv.x; acc[c].y += w * xv.y;
      acc[c].z += w * xv.z; acc[c].w += w * xv.w;
    }
  }
#pragma unroll
  for (int li = 0; li < 4; ++li) {
    float4 v;
    v.x = (&acc[0].x)[li]; v.y = (&acc[1].x)[li];
    v.z = (&acc[2].x)[li]; v.w = (&acc[3].x)[li];
    *(float4*)(out0 + ((size_t)rq * 4 + li) * DMv + c0) = v;
  }
}

// K8: hcl = silu(ygated @ ffn_in_w.T + b) via ygtT/fiwT. 16 cols/block.
__global__ void k_ffnin2(const float* __restrict__ ygtT, const float* __restrict__ fiwT,
                         const float* __restrict__ bias, float* __restrict__ hcl) {
  int t = threadIdx.x;                    // 256
  int rq = blockIdx.x * 256 + t;
  int c0 = blockIdx.y * 16;
  const float4* x4 = (const float4*)ygtT;
  float4 acc[16];
#pragma unroll
  for (int c = 0; c < 16; ++c) acc[c] = make_float4(0.f, 0.f, 0.f, 0.f);
  for (int k = 0; k < DIv; ++k) {
    float4 xv = x4[(size_t)k * (NR / 4) + rq];
    const float* wr = fiwT + k * HIDv + c0;  // wave-uniform
#pragma unroll
    for (int c = 0; c < 16; ++c) {
      float w = wr[c];
      acc[c].x += w * xv.x; acc[c].y += w * xv.y;
      acc[c].z += w * xv.z; acc[c].w += w * xv.w;
    }
  }
#pragma unroll
  for (int li = 0; li < 4; ++li) {
    size_t row = (size_t)rq * 4 + li;
#pragma unroll
    for (int cc = 0; cc < 4; ++cc) {
      float4 v;
#pragma unroll
      for (int j = 0; j < 4; ++j) {
        float s = (&acc[cc * 4 + j].x)[li] + bias[c0 + cc * 4 + j];
        (&v.x)[j] = s * sigf(s);
      }
      *(float4*)(hcl + row * HIDv + c0 + cc * 4) = v;
    }
  }
}

// K9 (tiled): hc2 = (1 + w1)*hc(center) + dwconv3(hc) + dwconv5(hc), fused 5x5 stencil.
constexpr int TS = 16, CG = 32, TW = TS + 4;  // TW=20
__global__ void k_ffnconv(const float* __restrict__ hcl, const float* __restrict__ w1,
                          const float* __restrict__ w3, const float* __restrict__ w5,
                          float* __restrict__ hc2) {
  int tile = blockIdx.x;            // 0..15 (4x4 spatial tiles)
  int cg = blockIdx.y, b = blockIdx.z;
  int t = threadIdx.x;              // 256
  int ti0 = (tile >> 2) * TS, tj0 = (tile & 3) * TS;
  __shared__ float sm[TW * TW * CG];

  for (int e = t; e < TW * TW * CG; e += 256) {
    int ec = e & 31;
    int sp = e >> 5;                // 0..399
    int hi = sp / TW, hj = sp % TW;
    int gi = ti0 + hi - 2, gj = tj0 + hj - 2;
    float v = 0.f;
    if ((unsigned)gi < (unsigned)HH && (unsigned)gj < (unsigned)WW)
      v = hcl[((size_t)b * LL + gi * WW + gj) * HIDv + cg * CG + ec];
    sm[e] = v;
  }

  int c = t & 31;
  int cglob = cg * CG + c;
  float wc[25];
#pragma unroll
  for (int di = 0; di < 5; ++di)
#pragma unroll
    for (int dj = 0; dj < 5; ++dj) {
      float w = w5[cglob * 25 + di * 5 + dj];
      if (di >= 1 && di <= 3 && dj >= 1 && dj <= 3)
        w += w3[cglob * 9 + (di - 1) * 3 + (dj - 1)];
      if (di == 2 && dj == 2) w += 1.f + w1[cglob];
      wc[di * 5 + dj] = w;
    }
  __syncthreads();

  int s0 = t >> 5;  // 0..7
  for (int i = 0; i < 32; ++i) {
    int p = s0 + (i << 3);          // 0..255
    int r = p >> 4, q = p & 15;
    float s = 0.f;
#pragma unroll
    for (int di = 0; di < 5; ++di)
#pragma unroll
      for (int dj = 0; dj < 5; ++dj)
        s += sm[((r + di) * TW + (q + dj)) * CG + c] * wc[di * 5 + dj];
    hc2[((size_t)b * LL + (ti0 + r) * WW + (tj0 + q)) * HIDv + cglob] = s;
  }
}

// K10: fused LayerNorm(HID) + transpose: hc2[NR][768] -> hnT[768][NR].
// Block = 32-row stripe; phase1 row stats (8 lanes/row), phase2 32x32 tiles.
__global__ void k_ln2t(const float* __restrict__ hc2, const float* __restrict__ g,
                       const float* __restrict__ be, float* __restrict__ hnT) {
  int r0 = blockIdx.x * 32;
  int t = threadIdx.x;  // 256
  __shared__ float m_[32], rs_[32];
  __shared__ float tile[32][33];
  {
    int r = t >> 3, q = t & 7;
    const float4* row4 = (const float4*)(hc2 + (size_t)(r0 + r) * HIDv);
    float s = 0.f, qq = 0.f;
#pragma unroll
    for (int j = 0; j < 24; ++j) {
      float4 v = row4[q + j * 8];
      s += v.x + v.y + v.z + v.w;
      qq += v.x * v.x + v.y * v.y + v.z * v.z + v.w * v.w;
    }
    s += __shfl_down(s, 4, 8); qq += __shfl_down(qq, 4, 8);
    s += __shfl_down(s, 2, 8); qq += __shfl_down(qq, 2, 8);
    s += __shfl_down(s, 1, 8); qq += __shfl_down(qq, 1, 8);
    if (q == 0) {
      float m = s / HIDv;
      m_[r] = m;
      rs_[r] = rsqrtf(qq / HIDv - m * m + 1e-5f);
    }
  }
  __syncthreads();
  int tc = t & 31, tr = t >> 5;  // tr 0..7
  for (int ch = 0; ch < 24; ++ch) {
    int c0 = ch * 32;
    float gg = g[c0 + tc], bb = be[c0 + tc];
    __syncthreads();
#pragma unroll
    for (int i = 0; i < 4; ++i) {
      int r = tr + i * 8;
      float v = hc2[(size_t)(r0 + r) * HIDv + c0 + tc];
      tile[tc][r] = (v - m_[r]) * rs_[r] * gg + bb;
    }
    __syncthreads();
#pragma unroll
    for (int i = 0; i < 4; ++i) {
      int cr = tr + i * 8;
      hnT[(size_t)(c0 + cr) * NR + r0 + tc] = tile[cr][tc];
    }
  }
}

// K11a: split-K partial GEMM: part[ks][row][c] = sum_{k in seg} hnT*fowT.
__global__ void k_final3(const float* __restrict__ hnT, const float* __restrict__ fowT,
                         float* __restrict__ part) {
  int t = threadIdx.x;                    // 128
  int rq = blockIdx.x * 128 + t;          // f4-row
  int c0 = blockIdx.y * 8;
  int ks = blockIdx.z;                    // 4 segments of 192
  const float4* x4 = (const float4*)hnT;
  float4 acc[8];
#pragma unroll
  for (int c = 0; c < 8; ++c) acc[c] = make_float4(0.f, 0.f, 0.f, 0.f);
  int k0 = ks * 192;
  for (int k = k0; k < k0 + 192; ++k) {
    float4 xv = x4[(size_t)k * (NR / 4) + rq];
    const float* wr = fowT + k * DMv + c0;  // wave-uniform
#pragma unroll
    for (int c = 0; c < 8; ++c) {
      float w = wr[c];
      acc[c].x += w * xv.x; acc[c].y += w * xv.y;
      acc[c].z += w * xv.z; acc[c].w += w * xv.w;
    }
  }
  float* pb = part + (size_t)ks * NR * DMv;
#pragma unroll
  for (int li = 0; li < 4; ++li) {
    size_t row = (size_t)rq * 4 + li;
#pragma unroll
    for (int cc = 0; cc < 2; ++cc) {
      float4 v;
#pragma unroll
      for (int j = 0; j < 4; ++j) (&v.x)[j] = (&acc[cc * 4 + j].x)[li];
      *(float4*)(pb + row * DMv + c0 + cc * 4) = v;
    }
  }
}

// K11b: dout = out0 + skip*(sum_k part[k] + bias), float4 elementwise.
__global__ void k_finred(const float* __restrict__ part, const float* __restrict__ out0,
                         const float* __restrict__ bias, const float* __restrict__ skip,
                         float* __restrict__ dout) {
  size_t i = (size_t)blockIdx.x * 256 + threadIdx.x;   // f4 index over NR*DMv/4
  int cq = (int)(i % (DMv / 4));
  const float4* p4 = (const float4*)part;
  size_t npart = (size_t)NR * DMv / 4;
  float4 a = p4[i], b2 = p4[i + npart], c2 = p4[i + 2 * npart], d2 = p4[i + 3 * npart];
  float4 o = ((const float4*)out0)[i];
  float4 bi = ((const float4*)bias)[cq];
  float sk = skip[0];
  float4 r;
  r.x = o.x + sk * (a.x + b2.x + c2.x + d2.x + bi.x);
  r.y = o.y + sk * (a.y + b2.y + c2.y + d2.y + bi.y);
  r.z = o.z + sk * (a.z + b2.z + c2.z + d2.z + bi.z);
  r.w = o.w + sk * (a.w + b2.w + c2.w + d2.w + bi.w);
  ((float4*)dout)[i] = r;
}

extern "C" void kernel_launch(void* const* d_in, const int* in_sizes, int n_in,
                              void* d_out, int out_size, void* d_ws, size_t ws_size,
                              hipStream_t stream) {
  const float* x        = (const float*)d_in[0];
  const float* in_w     = (const float*)d_in[1];
  const float* conv_w   = (const float*)d_in[2];
  const float* conv_b   = (const float*)d_in[3];
  const float* xpw      = (const float*)d_in[4];
  const float* dtw      = (const float*)d_in[5];
  const float* dtb      = (const float*)d_in[6];
  const float* alogs    = (const float*)d_in[7];
  const float* Ds       = (const float*)d_in[8];
  const float* ong      = (const float*)d_in[9];
  const float* onb      = (const float*)d_in[10];
  const float* opw      = (const float*)d_in[11];
  const float* fiw      = (const float*)d_in[12];
  const float* fib      = (const float*)d_in[13];
  const float* dw1      = (const float*)d_in[14];
  const float* dw3      = (const float*)d_in[15];
  const float* dw5      = (const float*)d_in[16];
  const float* flg      = (const float*)d_in[17];
  const float* flb      = (const float*)d_in[18];
  const float* fow      = (const float*)d_in[19];
  const float* fob      = (const float*)d_in[20];
  const float* skip     = (const float*)d_in[21];

  // Workspace layout (aliased; ~150 MB)
  float* ws    = (float*)d_ws;
  float* xi    = ws;                 // -> S/P -> ygtT -> part (with z)
  float* z     = xi + S_xi;
  float* xc    = z + S_xi;           // -> ygt
  float* xdbl  = xc + S_xi;          // -> out0
  float* delta = xdbl + S_xdbl;      // xt/wt scratch -> delta -> hcl -> hnT
  float* ys    = delta + S_big;      // xcT/xcTs scratch -> ys -> hc2
  float* wtiny = ys + S_big;         // persistent small weight transposes
  float* fiwT  = wtiny;              // 192*768 = 147456
  float* opwT  = fiwT + 147456;      // 192*96  = 18432
  float* fowT  = opwT + 18432;       // 768*96  = 73728
  float* wcatT = fowT + 73728;       // 2*192*76 = 29184

  // Small weight transposes (persist whole launch)
  k_transp<<<dim3(24, 6), 256, 0, stream>>>(fiw, fiwT, HIDv, DIv);   // 768x192 -> 192x768
  k_transp<<<dim3(3, 6), 256, 0, stream>>>(opw, opwT, DMv, DIv);     // 96x192  -> 192x96
  k_transp<<<dim3(3, 24), 256, 0, stream>>>(fow, fowT, DMv, HIDv);   // 96x768  -> 768x96
  k_wcat<<<114, 256, 0, stream>>>(xpw, wcatT);

  // In-proj via transposed operands (xt, wt live in the not-yet-used delta region)
  float* xt = delta;                       // 96*16384 floats
  float* wt = delta + 1600000;             // 36,864 floats (within S_big)
  k_wt<<<(96 * 384 + 255) / 256, 256, 0, stream>>>(in_w, wt);
  dim3 gxt(NR / 64, 3);
  k_xt<<<gxt, 256, 0, stream>>>(x, xt);
  dim3 gip(NR / 1024, 48);
  k_inproj<<<gip, 256, 0, stream>>>(xt, wt, xi, z);

  k_dwconv<<<(BB * LL * DIv) / 256, 256, 0, stream>>>(xi, conv_w, conv_b, xc);

  // x_dbl GEMM via transposed operands (xcT/xcTs in ys region, free until k_scan3)
  float* xcT  = ys;                  // 192*16384 = 3,145,728
  float* xcTs = ys + S_xi;           // 3,145,728 (6.3M < S_big)
  k_transp<<<dim3(512, 6), 256, 0, stream>>>(xc, xcT, NR, DIv);
  k_spt<<<DIv * BB, 256, 0, stream>>>(xcT, xcTs);
  dim3 gxd(4, 19, 8);                // rq-blocks x col-groups x (p*4+b)
  k_xdbl2<<<gxd, 256, 0, stream>>>(xcT, xcTs, wcatT, xdbl);

  k_delta<<<(BB * KKv * LL * DIv) / 256, 256, 0, stream>>>(xdbl, dtw, dtb, delta);

  // Chunked scan: S/P buffers alias xi (dead until ygtT lands there)
  float* Sbuf = xi;                  // S_sp floats
  float* Pbuf = xi + S_sp;           // S_sp floats (S_sp*2 == S_xi exactly)
  dim3 gs13(NC * 3, KKv, BB);        // 1536 blocks, 64d x 4nq threads
  dim3 gs2(3, KKv, BB);              // 48 blocks (tiny)
  k_scan1<<<gs13, 256, 0, stream>>>(delta, xdbl, xc, alogs, Sbuf, Pbuf);
  k_scan2<<<gs2, 256, 0, stream>>>(Sbuf, Pbuf);  // S <- Hin
  k_scan3<<<gs13, 256, 0, stream>>>(delta, xdbl, xc, alogs, Sbuf, ys);

  // Fused combine + LayerNorm + silu-gate -> ygt
  float* ygt = xc;
  k_comln<<<BB * LL, 64, 0, stream>>>(ys, xc, Ds, z, ong, onb, ygt);

  // Transpose ygt (16384x192 -> 192x16384) into xi (S/P dead)
  float* ygtT = xi;
  k_transp<<<dim3(512, 6), 256, 0, stream>>>(ygt, ygtT, NR, DIv);

  float* out0 = xdbl;
  dim3 gop(NR / 1024, DMv / 4);      // (16, 24)
  k_outproj2<<<gop, 256, 0, stream>>>(ygtT, opwT, out0);
  float* hcl = delta;
  dim3 gfi(NR / 1024, HIDv / 16);    // (16, 48)
  k_ffnin2<<<gfi, 256, 0, stream>>>(ygtT, fiwT, fib, hcl);
  float* hc2 = ys;
  dim3 gc(16, HIDv / CG, BB);        // 16 spatial tiles x 24 ch-groups x 4
  k_ffnconv<<<gc, 256, 0, stream>>>(hcl, dw1, dw3, dw5, hc2);

  // Fused LayerNorm + transpose: hc2 (ys) -> hnT (delta; hcl dead)
  float* hnT = delta;
  k_ln2t<<<NR / 32, 256, 0, stream>>>(hc2, flg, flb, hnT);

  // Split-K final GEMM: partials in xi+z region (ygtT dead after ffnin2)
  float* part = xi;                  // 4 * NR * 96 = 6,291,456 floats (= 2*S_xi)
  dim3 gfn(NR / 512, DMv / 8, 4);    // (32, 12, 4), block 128
  k_final3<<<gfn, 128, 0, stream>>>(hnT, fowT, part);
  k_finred<<<(NR * DMv / 4) / 256, 256, 0, stream>>>(part, out0, fob, skip, (float*)d_out);
}

// Round 12
// 597.630 us; speedup vs baseline: 3.0444x; 1.0174x over previous
//
#include <hip/hip_runtime.h>
#include <hip/hip_bf16.h>

constexpr int BB = 4, HH = 64, WW = 64, DMv = 96;
constexpr int DSn = 16, DIv = 192, DTRv = 6, KKv = 4, HIDv = 768;
constexpr int LL = 4096;
constexpr int NC = 32, CHK = LL / NC;       // 32 chunks of 128
constexpr int NR = BB * LL;                 // 16384 rows
constexpr int XDS = 40;                     // padded xdbl row stride (dt 0-5, B 8-23, C 24-39)

constexpr size_t S_xi   = (size_t)BB * LL * DIv;          // 3,145,728
constexpr size_t S_xdbl = (size_t)BB * KKv * LL * XDS;    // 2,621,440
constexpr size_t S_big  = (size_t)BB * KKv * LL * DIv;    // 12,582,912
constexpr size_t S_sp   = (size_t)BB * KKv * NC * DIv * DSn;  // 1,572,864 (= S_xi/2)

__device__ __forceinline__ float sigf(float x) { return 1.f / (1.f + __expf(-x)); }

__device__ __forceinline__ int lmap(int k, int l) {
  int lr = (k & 2) ? (LL - 1 - l) : l;
  return (k & 1) ? (((lr & 63) << 6) | (lr >> 6)) : lr;
}

// Generic 32x32 LDS tile transpose: src[R][C] -> dst[C][R], both coalesced.
__global__ void k_transp(const float* __restrict__ src, float* __restrict__ dst,
                         int R, int C) {
  __shared__ float tile[32][33];
  int r0 = blockIdx.x * 32, c0 = blockIdx.y * 32;
  int t = threadIdx.x;            // 256
  int tc = t & 31, tr = t >> 5;   // tr 0..7
#pragma unroll
  for (int i = 0; i < 4; ++i) {
    int r = r0 + tr + i * 8;
    if (r < R && c0 + tc < C) tile[tr + i * 8][tc] = src[(size_t)r * C + c0 + tc];
  }
  __syncthreads();
#pragma unroll
  for (int i = 0; i < 4; ++i) {
    int c = c0 + tr + i * 8;
    int r = r0 + tc;
    if (c < C && r < R) dst[(size_t)c * R + r] = tile[tc][tr + i * 8];
  }
}

// K0a: wt[k][c] = in_proj_w[c][k]  (96 x 384)
__global__ void k_wt(const float* __restrict__ w, float* __restrict__ wt) {
  int idx = blockIdx.x * 256 + threadIdx.x;  // 36864
  if (idx < 96 * 384) {
    int k = idx / 384, c = idx % 384;
    wt[idx] = w[c * 96 + k];
  }
}

// K0b: xt[k][row] = x[row][k]  (96 x 16384), 64x32 LDS tile transpose
__global__ void k_xt(const float* __restrict__ x, float* __restrict__ xt) {
  __shared__ float tile[32][65];
  int r0 = blockIdx.x * 64, k0 = blockIdx.y * 32;
  int t = threadIdx.x;  // 256
#pragma unroll
  for (int ii = 0; ii < 8; ++ii) {
    int i = (t >> 5) + ii * 8, j = t & 31;
    tile[j][i] = x[(size_t)(r0 + i) * 96 + k0 + j];
  }
  __syncthreads();
#pragma unroll
  for (int jj = 0; jj < 8; ++jj) {
    int j = (t >> 6) + jj * 4, i = t & 63;
    xt[(size_t)(k0 + j) * NR + r0 + i] = tile[j][i];
  }
}

// K1: xz = x @ in_proj_w.T via xt/wt. Lane = 4 rows (f4, coalesced), wave-uniform
// scalar weight loads.
__global__ void k_inproj(const float* __restrict__ xt, const float* __restrict__ wt,
                         float* __restrict__ xi, float* __restrict__ z) {
  int t = threadIdx.x;
  int wv = t >> 6, lane = t & 63;
  int rq = blockIdx.x * 256 + wv * 64 + lane;   // float4-row index (row = rq*4)
  int c0 = blockIdx.y * 8;
  const float4* xt4 = (const float4*)xt;
  float4 acc[8];
#pragma unroll
  for (int c = 0; c < 8; ++c) acc[c] = make_float4(0.f, 0.f, 0.f, 0.f);
  for (int k = 0; k < 96; ++k) {
    float4 xv = xt4[(size_t)k * (NR / 4) + rq];
    const float* wr = wt + k * 384 + c0;  // wave-uniform -> s_load
#pragma unroll
    for (int c = 0; c < 8; ++c) {
      float w = wr[c];
      acc[c].x += w * xv.x; acc[c].y += w * xv.y;
      acc[c].z += w * xv.z; acc[c].w += w * xv.w;
    }
  }
  float* dst; int cc;
  if (c0 < DIv) { dst = xi; cc = c0; } else { dst = z; cc = c0 - DIv; }
#pragma unroll
  for (int li = 0; li < 4; ++li) {
    size_t row = (size_t)rq * 4 + li;
    float4 v0, v1;
    v0.x = (&acc[0].x)[li]; v0.y = (&acc[1].x)[li];
    v0.z = (&acc[2].x)[li]; v0.w = (&acc[3].x)[li];
    v1.x = (&acc[4].x)[li]; v1.y = (&acc[5].x)[li];
    v1.z = (&acc[6].x)[li]; v1.w = (&acc[7].x)[li];
    float4* o4 = (float4*)(dst + row * DIv + cc);
    o4[0] = v0; o4[1] = v1;
  }
}

// K2: xc = silu(dwconv3x3(xi) + conv_b), channel-last
__global__ void k_dwconv(const float* __restrict__ xi, const float* __restrict__ cw,
                         const float* __restrict__ cb, float* __restrict__ xc) {
  size_t idx = (size_t)blockIdx.x * 256 + threadIdx.x;  // B*L*DI
  int d = (int)(idx % DIv);
  int l = (int)((idx / DIv) % LL);
  int b = (int)(idx / ((size_t)DIv * LL));
  int i = l >> 6, j = l & 63;
  float s = cb[d];
#pragma unroll
  for (int di = 0; di < 3; ++di) {
    int ii = i + di - 1;
    if ((unsigned)ii >= (unsigned)HH) continue;
#pragma unroll
    for (int dj = 0; dj < 3; ++dj) {
      int jj = j + dj - 1;
      if ((unsigned)jj >= (unsigned)WW) continue;
      s += xi[((size_t)b * LL + ii * WW + jj) * DIv + d] * cw[d * 9 + di * 3 + dj];
    }
  }
  xc[idx] = s * sigf(s);
}

// K3pre-a: spatial transpose per (d,b): xcTs[d][b][j*64+i] = xcT[d][b][i*64+j]
__global__ void k_spt(const float* __restrict__ xcT, float* __restrict__ xcTs) {
  __shared__ float tile[64][65];
  int d = blockIdx.x >> 2, b = blockIdx.x & 3;
  int t = threadIdx.x;  // 256
  const float* src = xcT + (size_t)d * NR + b * LL;
  float* dst = xcTs + (size_t)d * NR + b * LL;
#pragma unroll
  for (int it = 0; it < 16; ++it) {
    int idx = it * 256 + t;
    tile[idx >> 6][idx & 63] = src[idx];
  }
  __syncthreads();
#pragma unroll
  for (int it = 0; it < 16; ++it) {
    int idx = it * 256 + t;
    dst[idx] = tile[idx & 63][idx >> 6];
  }
}

// K3pre-b: wcatT[p][d][76]: cols 0..37 = w_{k=p}[c][d], 38..75 = w_{k=p+2}[c][d]
__global__ void k_wcat(const float* __restrict__ xpw, float* __restrict__ wcatT) {
  int idx = blockIdx.x * 256 + threadIdx.x;  // 2*192*76 = 29184
  if (idx < 2 * 192 * 76) {
    int p = idx / (192 * 76);
    int rem = idx % (192 * 76);
    int d = rem / 76, j = rem % 76;
    int k = (j >= 38 ? 2 : 0) + p;
    int c = (j >= 38) ? j - 38 : j;
    wcatT[idx] = xpw[((size_t)(k * 38 + c)) * DIv + d];
  }
}

// K3a: x_dbl via transposed operands; stride-40 layout, zeroes pad cols 6,7.
__global__ void k_xdbl2(const float* __restrict__ xcT, const float* __restrict__ xcTs,
                        const float* __restrict__ wcatT, float* __restrict__ xdbl) {
  int t = threadIdx.x;                  // 256
  int rq = blockIdx.x * 256 + t;        // 0..1023 f4-row within b
  int jg = blockIdx.y;                  // 0..18 -> cols jg*4..jg*4+3
  int pb = blockIdx.z;                  // p*4 + b
  int p = pb >> 2, b = pb & 3;
  const float4* A = (const float4*)(p ? xcTs : xcT);
  const float* wbase = wcatT + (size_t)p * 192 * 76 + jg * 4;
  float4 acc[4];
#pragma unroll
  for (int j = 0; j < 4; ++j) acc[j] = make_float4(0.f, 0.f, 0.f, 0.f);
  for (int d = 0; d < 192; ++d) {
    float4 xv = A[(size_t)d * (NR / 4) + b * 1024 + rq];
    const float* wr = wbase + d * 76;   // wave-uniform -> s_load
#pragma unroll
    for (int j = 0; j < 4; ++j) {
      float w = wr[j];
      acc[j].x += w * xv.x; acc[j].y += w * xv.y;
      acc[j].z += w * xv.z; acc[j].w += w * xv.w;
    }
  }
#pragma unroll
  for (int li = 0; li < 4; ++li) {
    int r = rq * 4 + li;
#pragma unroll
    for (int j = 0; j < 4; ++j) {
      int col = jg * 4 + j;
      int kk = (col >= 38) ? (2 + p) : p;
      int c = (col >= 38) ? col - 38 : col;
      int l = (col >= 38) ? (LL - 1 - r) : r;
      int phys = c + (c >= 6 ? 2 : 0);
      size_t ro = (((size_t)(b * KKv + kk)) * LL + l) * XDS;
      xdbl[ro + phys] = (&acc[j].x)[li];
      if (col == 5) { xdbl[ro + 6] = 0.f; xdbl[ro + 7] = 0.f; }
    }
  }
}

// K3b: delta[b,k,l,d] = softplus(dts @ dt_projs_w + dt_projs_b)
__global__ void k_delta(const float* __restrict__ xdbl, const float* __restrict__ dtw,
                        const float* __restrict__ dtb, float* __restrict__ delta) {
  size_t idx = (size_t)blockIdx.x * 256 + threadIdx.x;  // B*K*L*DI
  int d = (int)(idx % DIv);
  size_t bkl = idx / DIv;              // (b*K+k)*L + l
  int k = (int)((bkl / LL) % KKv);
  const float* xr = xdbl + bkl * XDS;
  const float* wr = dtw + ((size_t)k * DIv + d) * DTRv;
  float s = dtb[k * DIv + d];
#pragma unroll
  for (int r = 0; r < DTRv; ++r) s += xr[r] * wr[r];
  delta[idx] = (s > 20.f) ? s : __logf(1.f + __expf(s));
}

// K4a: chunked scan pass 1 with LDS-staged inputs. Block 256 = 64 d x 4 nq.
__global__ void k_scan1(const float* __restrict__ delta, const float* __restrict__ xdbl,
                        const float* __restrict__ xc, const float* __restrict__ alogs,
                        float* __restrict__ S, float* __restrict__ P) {
  int bx = blockIdx.x;
  int c = bx / 3, dblk = bx % 3;
  int k = blockIdx.y, b = blockIdx.z;
  int t = threadIdx.x, dl = t >> 2, nq = t & 3;
  int d = dblk * 64 + dl;
  __shared__ float de_s[16][64], xv_s[16][64], bc_s[16][32];
  float A[4];
#pragma unroll
  for (int j = 0; j < 4; ++j)
    A[j] = -__expf(alogs[(size_t)(k * DIv + d) * DSn + nq * 4 + j]);
  size_t bkL = (size_t)(b * KKv + k) * LL;
  const float* dp = delta + bkL * DIv;
  const float* xq = xdbl + bkL * XDS;
  const float* xcb = xc + (size_t)b * LL * DIv;
  float h[4] = {0.f, 0.f, 0.f, 0.f}, sA[4] = {0.f, 0.f, 0.f, 0.f};
  int l0 = c * CHK;
  for (int tile = 0; tile < CHK / 16; ++tile) {
    int lt = l0 + tile * 16;
    __syncthreads();
    {
      int r = t >> 4, q = t & 15;
      int l = lt + r;
      *(float4*)&de_s[r][q * 4] = *(const float4*)(dp + (size_t)l * DIv + dblk * 64 + q * 4);
      int lc = lmap(k, l);
      *(float4*)&xv_s[r][q * 4] = *(const float4*)(xcb + (size_t)lc * DIv + dblk * 64 + q * 4);
      if (t < 128) {
        int r2 = t >> 3, q2 = t & 7;
        *(float4*)&bc_s[r2][q2 * 4] = *(const float4*)(xq + (size_t)(lt + r2) * XDS + 8 + q2 * 4);
      }
    }
    __syncthreads();
#pragma unroll
    for (int i2 = 0; i2 < 16; ++i2) {
      float de = de_s[i2][dl];
      float xv = xv_s[i2][dl];
      float4 Bv = *(float4*)&bc_s[i2][nq * 4];
      float db = de * xv;
#pragma unroll
      for (int j = 0; j < 4; ++j) {
        float u = de * A[j];
        sA[j] += u;
        h[j] = h[j] * __expf(u) + db * (&Bv.x)[j];
      }
    }
  }
  size_t o = ((((size_t)(b * KKv + k) * NC + c) * 3 + dblk) * 1024) + (size_t)t * 4;
  float4 hs, ps;
#pragma unroll
  for (int j = 0; j < 4; ++j) { (&hs.x)[j] = h[j]; (&ps.x)[j] = __expf(sA[j]); }
  *(float4*)(S + o) = hs;
  *(float4*)(P + o) = ps;
}

// K4b: sequential chunk combine (float4 per thread). Rewrites S[c] <- Hin[c].
__global__ void k_scan2(float* __restrict__ S, const float* __restrict__ P) {
  int dblk = blockIdx.x, k = blockIdx.y, b = blockIdx.z;
  int t = threadIdx.x;  // 256
  size_t base = (((size_t)(b * KKv + k) * NC) * 3 + dblk) * 1024 + (size_t)t * 4;
  float4 h = make_float4(0.f, 0.f, 0.f, 0.f);
  for (int c = 0; c < NC; ++c) {
    size_t o = base + (size_t)c * 3 * 1024;
    float4 s = *(float4*)(S + o), p = *(float4*)(P + o);
    *(float4*)(S + o) = h;  // Hin for chunk c
    h.x = s.x + p.x * h.x; h.y = s.y + p.y * h.y;
    h.z = s.z + p.z * h.z; h.w = s.w + p.w * h.w;
  }
}

// K4c: chunked scan pass 3 — LDS-staged; width-4 shuffle for y.
__global__ void k_scan3(const float* __restrict__ delta, const float* __restrict__ xdbl,
                        const float* __restrict__ xc, const float* __restrict__ alogs,
                        const float* __restrict__ Hin, float* __restrict__ ys) {
  int bx = blockIdx.x;
  int c = bx / 3, dblk = bx % 3;
  int k = blockIdx.y, b = blockIdx.z;
  int t = threadIdx.x, dl = t >> 2, nq = t & 3;
  int d = dblk * 64 + dl;
  __shared__ float de_s[16][64], xv_s[16][64], bc_s[16][32];
  float A[4];
#pragma unroll
  for (int j = 0; j < 4; ++j)
    A[j] = -__expf(alogs[(size_t)(k * DIv + d) * DSn + nq * 4 + j]);
  size_t bkL = (size_t)(b * KKv + k) * LL;
  const float* dp = delta + bkL * DIv;
  const float* xq = xdbl + bkL * XDS;
  const float* xcb = xc + (size_t)b * LL * DIv;
  float* yp = ys + bkL * DIv + d;
  size_t o = ((((size_t)(b * KKv + k) * NC + c) * 3 + dblk) * 1024) + (size_t)t * 4;
  float4 h4 = *(const float4*)(Hin + o);
  float h[4] = {h4.x, h4.y, h4.z, h4.w};
  int l0 = c * CHK;
  for (int tile = 0; tile < CHK / 16; ++tile) {
    int lt = l0 + tile * 16;
    __syncthreads();
    {
      int r = t >> 4, q = t & 15;
      int l = lt + r;
      *(float4*)&de_s[r][q * 4] = *(const float4*)(dp + (size_t)l * DIv + dblk * 64 + q * 4);
      int lc = lmap(k, l);
      *(float4*)&xv_s[r][q * 4] = *(const float4*)(xcb + (size_t)lc * DIv + dblk * 64 + q * 4);
      if (t < 128) {
        int r2 = t >> 3, q2 = t & 7;
        *(float4*)&bc_s[r2][q2 * 4] = *(const float4*)(xq + (size_t)(lt + r2) * XDS + 8 + q2 * 4);
      }
    }
    __syncthreads();
#pragma unroll
    for (int i2 = 0; i2 < 16; ++i2) {
      float de = de_s[i2][dl];
      float xv = xv_s[i2][dl];
      float4 Bv = *(float4*)&bc_s[i2][nq * 4];
      float4 Cv = *(float4*)&bc_s[i2][16 + nq * 4];
      float db = de * xv;
      float p = 0.f;
#pragma unroll
      for (int j = 0; j < 4; ++j) {
        h[j] = h[j] * __expf(de * A[j]) + db * (&Bv.x)[j];
        p += h[j] * (&Cv.x)[j];
      }
      p += __shfl_down(p, 2, 4);
      p += __shfl_down(p, 1, 4);
      if (nq == 0) yp[(size_t)(lt + i2) * DIv] = p;
    }
  }
}

// K5+K6 fused: merge 4 directions + D*x skip, LayerNorm(DI), * silu(z) -> ygt
__global__ void k_comln(const float* __restrict__ ys, const float* __restrict__ xc,
                        const float* __restrict__ Ds, const float* __restrict__ z,
                        const float* __restrict__ g, const float* __restrict__ be,
                        float* __restrict__ out) {
  int bl = blockIdx.x;            // b*L + l
  int b = bl >> 12, l = bl & 4095;
  int t = threadIdx.x;            // 64
  int lT = ((l & 63) << 6) | (l >> 6);
  size_t base = (size_t)b * KKv * LL * DIv;
  const float* r0 = ys + base + (size_t)l * DIv;
  const float* r2 = ys + base + ((size_t)2 * LL + (LL - 1 - l)) * DIv;
  const float* r1 = ys + base + ((size_t)1 * LL + lT) * DIv;
  const float* r3 = ys + base + ((size_t)3 * LL + (LL - 1 - lT)) * DIv;
  const float* xr = xc + ((size_t)b * LL + l) * DIv;
  float v[3];
  float s = 0.f, q = 0.f;
#pragma unroll
  for (int cc = 0; cc < 3; ++cc) {
    int d = t + cc * 64;
    float sd = Ds[d] + Ds[DIv + d] + Ds[2 * DIv + d] + Ds[3 * DIv + d];
    float vv = r0[d] + r2[d] + r1[d] + r3[d] + sd * xr[d];
    v[cc] = vv; s += vv; q += vv * vv;
  }
#pragma unroll
  for (int o = 32; o > 0; o >>= 1) { s += __shfl_xor(s, o, 64); q += __shfl_xor(q, o, 64); }
  float m = s / DIv;
  float var = q / DIv - m * m;
  float rs = rsqrtf(var + 1e-5f);
  const float* zr = z + (size_t)bl * DIv;
  float* orow = out + (size_t)bl * DIv;
#pragma unroll
  for (int cc = 0; cc < 3; ++cc) {
    int d = t + cc * 64;
    float zz = zr[d];
    float val = (v[cc] - m) * rs * g[d] + be[d];
    orow[d] = val * zz * sigf(zz);
  }
}

// K7: out0 = ygated @ out_proj_w.T via ygtT/opwT. float2 rows, 4 cols/block.
// Grid (32, 24) = 768 blocks.
__global__ void k_outproj3(const float* __restrict__ ygtT, const float* __restrict__ opwT,
                           float* __restrict__ out0) {
  int t = threadIdx.x;                    // 256
  int r2 = blockIdx.x * 256 + t;          // float2-row index
  int c0 = blockIdx.y * 4;
  const float2* x2 = (const float2*)ygtT;
  float2 acc[4];
#pragma unroll
  for (int c = 0; c < 4; ++c) acc[c] = make_float2(0.f, 0.f);
  for (int k = 0; k < DIv; ++k) {
    float2 xv = x2[(size_t)k * (NR / 2) + r2];
    const float* wr = opwT + k * DMv + c0;  // wave-uniform
#pragma unroll
    for (int c = 0; c < 4; ++c) {
      float w = wr[c];
      acc[c].x += w * xv.x; acc[c].y += w * xv.y;
    }
  }
#pragma unroll
  for (int li = 0; li < 2; ++li) {
    float4 v;
    v.x = (&acc[0].x)[li]; v.y = (&acc[1].x)[li];
    v.z = (&acc[2].x)[li]; v.w = (&acc[3].x)[li];
    *(float4*)(out0 + ((size_t)r2 * 2 + li) * DMv + c0) = v;
  }
}

// K8: hcl = silu(ygated @ ffn_in_w.T + b). float2 rows, 16 cols/block.
// Grid (32, 48) = 1536 blocks (2x occupancy vs float4 variant, same L2 reuse).
__global__ void k_ffnin3(const float* __restrict__ ygtT, const float* __restrict__ fiwT,
                         const float* __restrict__ bias, float* __restrict__ hcl) {
  int t = threadIdx.x;                    // 256
  int r2 = blockIdx.x * 256 + t;          // float2-row index
  int c0 = blockIdx.y * 16;
  const float2* x2 = (const float2*)ygtT;
  float2 acc[16];
#pragma unroll
  for (int c = 0; c < 16; ++c) acc[c] = make_float2(0.f, 0.f);
  for (int k = 0; k < DIv; ++k) {
    float2 xv = x2[(size_t)k * (NR / 2) + r2];
    const float* wr = fiwT + k * HIDv + c0;  // wave-uniform
#pragma unroll
    for (int c = 0; c < 16; ++c) {
      float w = wr[c];
      acc[c].x += w * xv.x; acc[c].y += w * xv.y;
    }
  }
#pragma unroll
  for (int li = 0; li < 2; ++li) {
    size_t row = (size_t)r2 * 2 + li;
#pragma unroll
    for (int cc = 0; cc < 4; ++cc) {
      float4 v;
#pragma unroll
      for (int j = 0; j < 4; ++j) {
        float s = (&acc[cc * 4 + j].x)[li] + bias[c0 + cc * 4 + j];
        (&v.x)[j] = s * sigf(s);
      }
      *(float4*)(hcl + row * HIDv + c0 + cc * 4) = v;
    }
  }
}

// K9 (tiled): hc2 = (1 + w1)*hc(center) + dwconv3(hc) + dwconv5(hc), fused 5x5 stencil.
constexpr int TS = 16, CG = 32, TW = TS + 4;  // TW=20
__global__ void k_ffnconv(const float* __restrict__ hcl, const float* __restrict__ w1,
                          const float* __restrict__ w3, const float* __restrict__ w5,
                          float* __restrict__ hc2) {
  int tile = blockIdx.x;            // 0..15 (4x4 spatial tiles)
  int cg = blockIdx.y, b = blockIdx.z;
  int t = threadIdx.x;              // 256
  int ti0 = (tile >> 2) * TS, tj0 = (tile & 3) * TS;
  __shared__ float sm[TW * TW * CG];

  for (int e = t; e < TW * TW * CG; e += 256) {
    int ec = e & 31;
    int sp = e >> 5;                // 0..399
    int hi = sp / TW, hj = sp % TW;
    int gi = ti0 + hi - 2, gj = tj0 + hj - 2;
    float v = 0.f;
    if ((unsigned)gi < (unsigned)HH && (unsigned)gj < (unsigned)WW)
      v = hcl[((size_t)b * LL + gi * WW + gj) * HIDv + cg * CG + ec];
    sm[e] = v;
  }

  int c = t & 31;
  int cglob = cg * CG + c;
  float wc[25];
#pragma unroll
  for (int di = 0; di < 5; ++di)
#pragma unroll
    for (int dj = 0; dj < 5; ++dj) {
      float w = w5[cglob * 25 + di * 5 + dj];
      if (di >= 1 && di <= 3 && dj >= 1 && dj <= 3)
        w += w3[cglob * 9 + (di - 1) * 3 + (dj - 1)];
      if (di == 2 && dj == 2) w += 1.f + w1[cglob];
      wc[di * 5 + dj] = w;
    }
  __syncthreads();

  int s0 = t >> 5;  // 0..7
  for (int i = 0; i < 32; ++i) {
    int p = s0 + (i << 3);          // 0..255
    int r = p >> 4, q = p & 15;
    float s = 0.f;
#pragma unroll
    for (int di = 0; di < 5; ++di)
#pragma unroll
      for (int dj = 0; dj < 5; ++dj)
        s += sm[((r + di) * TW + (q + dj)) * CG + c] * wc[di * 5 + dj];
    hc2[((size_t)b * LL + (ti0 + r) * WW + (tj0 + q)) * HIDv + cglob] = s;
  }
}

// K10: fused LayerNorm(HID) + transpose: hc2[NR][768] -> hnT[768][NR].
__global__ void k_ln2t(const float* __restrict__ hc2, const float* __restrict__ g,
                       const float* __restrict__ be, float* __restrict__ hnT) {
  int r0 = blockIdx.x * 32;
  int t = threadIdx.x;  // 256
  __shared__ float m_[32], rs_[32];
  __shared__ float tile[32][33];
  {
    int r = t >> 3, q = t & 7;
    const float4* row4 = (const float4*)(hc2 + (size_t)(r0 + r) * HIDv);
    float s = 0.f, qq = 0.f;
#pragma unroll
    for (int j = 0; j < 24; ++j) {
      float4 v = row4[q + j * 8];
      s += v.x + v.y + v.z + v.w;
      qq += v.x * v.x + v.y * v.y + v.z * v.z + v.w * v.w;
    }
    s += __shfl_down(s, 4, 8); qq += __shfl_down(qq, 4, 8);
    s += __shfl_down(s, 2, 8); qq += __shfl_down(qq, 2, 8);
    s += __shfl_down(s, 1, 8); qq += __shfl_down(qq, 1, 8);
    if (q == 0) {
      float m = s / HIDv;
      m_[r] = m;
      rs_[r] = rsqrtf(qq / HIDv - m * m + 1e-5f);
    }
  }
  __syncthreads();
  int tc = t & 31, tr = t >> 5;  // tr 0..7
  for (int ch = 0; ch < 24; ++ch) {
    int c0 = ch * 32;
    float gg = g[c0 + tc], bb = be[c0 + tc];
    __syncthreads();
#pragma unroll
    for (int i = 0; i < 4; ++i) {
      int r = tr + i * 8;
      float v = hc2[(size_t)(r0 + r) * HIDv + c0 + tc];
      tile[tc][r] = (v - m_[r]) * rs_[r] * gg + bb;
    }
    __syncthreads();
#pragma unroll
    for (int i = 0; i < 4; ++i) {
      int cr = tr + i * 8;
      hnT[(size_t)(c0 + cr) * NR + r0 + tc] = tile[cr][tc];
    }
  }
}

// K11a: split-K partial GEMM: part[ks][row][c] = sum_{k in seg} hnT*fowT.
__global__ void k_final3(const float* __restrict__ hnT, const float* __restrict__ fowT,
                         float* __restrict__ part) {
  int t = threadIdx.x;                    // 128
  int rq = blockIdx.x * 128 + t;          // f4-row
  int c0 = blockIdx.y * 8;
  int ks = blockIdx.z;                    // 4 segments of 192
  const float4* x4 = (const float4*)hnT;
  float4 acc[8];
#pragma unroll
  for (int c = 0; c < 8; ++c) acc[c] = make_float4(0.f, 0.f, 0.f, 0.f);
  int k0 = ks * 192;
  for (int k = k0; k < k0 + 192; ++k) {
    float4 xv = x4[(size_t)k * (NR / 4) + rq];
    const float* wr = fowT + k * DMv + c0;  // wave-uniform
#pragma unroll
    for (int c = 0; c < 8; ++c) {
      float w = wr[c];
      acc[c].x += w * xv.x; acc[c].y += w * xv.y;
      acc[c].z += w * xv.z; acc[c].w += w * xv.w;
    }
  }
  float* pb = part + (size_t)ks * NR * DMv;
#pragma unroll
  for (int li = 0; li < 4; ++li) {
    size_t row = (size_t)rq * 4 + li;
#pragma unroll
    for (int cc = 0; cc < 2; ++cc) {
      float4 v;
#pragma unroll
      for (int j = 0; j < 4; ++j) (&v.x)[j] = (&acc[cc * 4 + j].x)[li];
      *(float4*)(pb + row * DMv + c0 + cc * 4) = v;
    }
  }
}

// K11b: dout = out0 + skip*(sum_k part[k] + bias), float4 elementwise.
__global__ void k_finred(const float* __restrict__ part, const float* __restrict__ out0,
                         const float* __restrict__ bias, const float* __restrict__ skip,
                         float* __restrict__ dout) {
  size_t i = (size_t)blockIdx.x * 256 + threadIdx.x;   // f4 index over NR*DMv/4
  int cq = (int)(i % (DMv / 4));
  const float4* p4 = (const float4*)part;
  size_t npart = (size_t)NR * DMv / 4;
  float4 a = p4[i], b2 = p4[i + npart], c2 = p4[i + 2 * npart], d2 = p4[i + 3 * npart];
  float4 o = ((const float4*)out0)[i];
  float4 bi = ((const float4*)bias)[cq];
  float sk = skip[0];
  float4 r;
  r.x = o.x + sk * (a.x + b2.x + c2.x + d2.x + bi.x);
  r.y = o.y + sk * (a.y + b2.y + c2.y + d2.y + bi.y);
  r.z = o.z + sk * (a.z + b2.z + c2.z + d2.z + bi.z);
  r.w = o.w + sk * (a.w + b2.w + c2.w + d2.w + bi.w);
  ((float4*)dout)[i] = r;
}

extern "C" void kernel_launch(void* const* d_in, const int* in_sizes, int n_in,
                              void* d_out, int out_size, void* d_ws, size_t ws_size,
                              hipStream_t stream) {
  const float* x        = (const float*)d_in[0];
  const float* in_w     = (const float*)d_in[1];
  const float* conv_w   = (const float*)d_in[2];
  const float* conv_b   = (const float*)d_in[3];
  const float* xpw      = (const float*)d_in[4];
  const float* dtw      = (const float*)d_in[5];
  const float* dtb      = (const float*)d_in[6];
  const float* alogs    = (const float*)d_in[7];
  const float* Ds       = (const float*)d_in[8];
  const float* ong      = (const float*)d_in[9];
  const float* onb      = (const float*)d_in[10];
  const float* opw      = (const float*)d_in[11];
  const float* fiw      = (const float*)d_in[12];
  const float* fib      = (const float*)d_in[13];
  const float* dw1      = (const float*)d_in[14];
  const float* dw3      = (const float*)d_in[15];
  const float* dw5      = (const float*)d_in[16];
  const float* flg      = (const float*)d_in[17];
  const float* flb      = (const float*)d_in[18];
  const float* fow      = (const float*)d_in[19];
  const float* fob      = (const float*)d_in[20];
  const float* skip     = (const float*)d_in[21];

  // Workspace layout (aliased; ~150 MB)
  float* ws    = (float*)d_ws;
  float* xi    = ws;                 // -> S/P -> ygtT -> part (with z)
  float* z     = xi + S_xi;
  float* xc    = z + S_xi;           // -> ygt
  float* xdbl  = xc + S_xi;          // -> out0
  float* delta = xdbl + S_xdbl;      // xt/wt scratch -> delta -> hcl -> hnT
  float* ys    = delta + S_big;      // xcT/xcTs scratch -> ys -> hc2
  float* wtiny = ys + S_big;         // persistent small weight transposes
  float* fiwT  = wtiny;              // 192*768 = 147456
  float* opwT  = fiwT + 147456;      // 192*96  = 18432
  float* fowT  = opwT + 18432;       // 768*96  = 73728
  float* wcatT = fowT + 73728;       // 2*192*76 = 29184

  // Small weight transposes (persist whole launch)
  k_transp<<<dim3(24, 6), 256, 0, stream>>>(fiw, fiwT, HIDv, DIv);   // 768x192 -> 192x768
  k_transp<<<dim3(3, 6), 256, 0, stream>>>(opw, opwT, DMv, DIv);     // 96x192  -> 192x96
  k_transp<<<dim3(3, 24), 256, 0, stream>>>(fow, fowT, DMv, HIDv);   // 96x768  -> 768x96
  k_wcat<<<114, 256, 0, stream>>>(xpw, wcatT);

  // In-proj via transposed operands (xt, wt live in the not-yet-used delta region)
  float* xt = delta;                       // 96*16384 floats
  float* wt = delta + 1600000;             // 36,864 floats (within S_big)
  k_wt<<<(96 * 384 + 255) / 256, 256, 0, stream>>>(in_w, wt);
  dim3 gxt(NR / 64, 3);
  k_xt<<<gxt, 256, 0, stream>>>(x, xt);
  dim3 gip(NR / 1024, 48);
  k_inproj<<<gip, 256, 0, stream>>>(xt, wt, xi, z);

  k_dwconv<<<(BB * LL * DIv) / 256, 256, 0, stream>>>(xi, conv_w, conv_b, xc);

  // x_dbl GEMM via transposed operands (xcT/xcTs in ys region, free until k_scan3)
  float* xcT  = ys;                  // 192*16384 = 3,145,728
  float* xcTs = ys + S_xi;           // 3,145,728 (6.3M < S_big)
  k_transp<<<dim3(512, 6), 256, 0, stream>>>(xc, xcT, NR, DIv);
  k_spt<<<DIv * BB, 256, 0, stream>>>(xcT, xcTs);
  dim3 gxd(4, 19, 8);                // rq-blocks x col-groups x (p*4+b)
  k_xdbl2<<<gxd, 256, 0, stream>>>(xcT, xcTs, wcatT, xdbl);

  k_delta<<<(BB * KKv * LL * DIv) / 256, 256, 0, stream>>>(xdbl, dtw, dtb, delta);

  // Chunked scan: S/P buffers alias xi (dead until ygtT lands there)
  float* Sbuf = xi;                  // S_sp floats
  float* Pbuf = xi + S_sp;           // S_sp floats (S_sp*2 == S_xi exactly)
  dim3 gs13(NC * 3, KKv, BB);        // 1536 blocks, 64d x 4nq threads
  dim3 gs2(3, KKv, BB);              // 48 blocks (tiny)
  k_scan1<<<gs13, 256, 0, stream>>>(delta, xdbl, xc, alogs, Sbuf, Pbuf);
  k_scan2<<<gs2, 256, 0, stream>>>(Sbuf, Pbuf);  // S <- Hin
  k_scan3<<<gs13, 256, 0, stream>>>(delta, xdbl, xc, alogs, Sbuf, ys);

  // Fused combine + LayerNorm + silu-gate -> ygt
  float* ygt = xc;
  k_comln<<<BB * LL, 64, 0, stream>>>(ys, xc, Ds, z, ong, onb, ygt);

  // Transpose ygt (16384x192 -> 192x16384) into xi (S/P dead)
  float* ygtT = xi;
  k_transp<<<dim3(512, 6), 256, 0, stream>>>(ygt, ygtT, NR, DIv);

  float* out0 = xdbl;
  dim3 gop(NR / 512, DMv / 4);       // (32, 24) = 768 blocks
  k_outproj3<<<gop, 256, 0, stream>>>(ygtT, opwT, out0);
  float* hcl = delta;
  dim3 gfi(NR / 512, HIDv / 16);     // (32, 48) = 1536 blocks
  k_ffnin3<<<gfi, 256, 0, stream>>>(ygtT, fiwT, fib, hcl);
  float* hc2 = ys;
  dim3 gc(16, HIDv / CG, BB);        // 16 spatial tiles x 24 ch-groups x 4
  k_ffnconv<<<gc, 256, 0, stream>>>(hcl, dw1, dw3, dw5, hc2);

  // Fused LayerNorm + transpose: hc2 (ys) -> hnT (delta; hcl dead)
  float* hnT = delta;
  k_ln2t<<<NR / 32, 256, 0, stream>>>(hc2, flg, flb, hnT);

  // Split-K final GEMM: partials in xi+z region (ygtT dead after ffnin3)
  float* part = xi;                  // 4 * NR * 96 = 6,291,456 floats (= 2*S_xi)
  dim3 gfn(NR / 512, DMv / 8, 4);    // (32, 12, 4), block 128
  k_final3<<<gfn, 128, 0, stream>>>(hnT, fowT, part);
  k_finred<<<(NR * DMv / 4) / 256, 256, 0, stream>>>(part, out0, fob, skip, (float*)d_out);
}

// Round 13
// 554.789 us; speedup vs baseline: 3.2795x; 1.0772x over previous
//
#include <hip/hip_runtime.h>
#include <hip/hip_bf16.h>

constexpr int BB = 4, HH = 64, WW = 64, DMv = 96;
constexpr int DSn = 16, DIv = 192, DTRv = 6, KKv = 4, HIDv = 768;
constexpr int LL = 4096;
constexpr int NC = 32, CHK = LL / NC;       // 32 chunks of 128
constexpr int NR = BB * LL;                 // 16384 rows
constexpr int XDS = 40;                     // padded xdbl row stride (dt 0-5, B 8-23, C 24-39)

constexpr size_t S_xi   = (size_t)BB * LL * DIv;          // 3,145,728
constexpr size_t S_xdbl = (size_t)BB * KKv * LL * XDS;    // 2,621,440
constexpr size_t S_big  = (size_t)BB * KKv * LL * DIv;    // 12,582,912
constexpr size_t S_sp   = (size_t)BB * KKv * NC * DIv * DSn;  // 1,572,864 (= S_xi/2)

__device__ __forceinline__ float sigf(float x) { return 1.f / (1.f + __expf(-x)); }
__device__ __forceinline__ float softp(float x) {
  return (x > 20.f) ? x : __logf(1.f + __expf(x));
}

__device__ __forceinline__ int lmap(int k, int l) {
  int lr = (k & 2) ? (LL - 1 - l) : l;
  return (k & 1) ? (((lr & 63) << 6) | (lr >> 6)) : lr;
}

// Generic 32x32 LDS tile transpose: src[R][C] -> dst[C][R], both coalesced.
__global__ void k_transp(const float* __restrict__ src, float* __restrict__ dst,
                         int R, int C) {
  __shared__ float tile[32][33];
  int r0 = blockIdx.x * 32, c0 = blockIdx.y * 32;
  int t = threadIdx.x;            // 256
  int tc = t & 31, tr = t >> 5;   // tr 0..7
#pragma unroll
  for (int i = 0; i < 4; ++i) {
    int r = r0 + tr + i * 8;
    if (r < R && c0 + tc < C) tile[tr + i * 8][tc] = src[(size_t)r * C + c0 + tc];
  }
  __syncthreads();
#pragma unroll
  for (int i = 0; i < 4; ++i) {
    int c = c0 + tr + i * 8;
    int r = r0 + tc;
    if (c < C && r < R) dst[(size_t)c * R + r] = tile[tc][tr + i * 8];
  }
}

// K0a: wt[k][c] = in_proj_w[c][k]  (96 x 384)
__global__ void k_wt(const float* __restrict__ w, float* __restrict__ wt) {
  int idx = blockIdx.x * 256 + threadIdx.x;  // 36864
  if (idx < 96 * 384) {
    int k = idx / 384, c = idx % 384;
    wt[idx] = w[c * 96 + k];
  }
}

// K0b: xt[k][row] = x[row][k]  (96 x 16384), 64x32 LDS tile transpose
__global__ void k_xt(const float* __restrict__ x, float* __restrict__ xt) {
  __shared__ float tile[32][65];
  int r0 = blockIdx.x * 64, k0 = blockIdx.y * 32;
  int t = threadIdx.x;  // 256
#pragma unroll
  for (int ii = 0; ii < 8; ++ii) {
    int i = (t >> 5) + ii * 8, j = t & 31;
    tile[j][i] = x[(size_t)(r0 + i) * 96 + k0 + j];
  }
  __syncthreads();
#pragma unroll
  for (int jj = 0; jj < 8; ++jj) {
    int j = (t >> 6) + jj * 4, i = t & 63;
    xt[(size_t)(k0 + j) * NR + r0 + i] = tile[j][i];
  }
}

// K1: xz = x @ in_proj_w.T via xt/wt. Lane = 4 rows (f4, coalesced), wave-uniform
// scalar weight loads.
__global__ void k_inproj(const float* __restrict__ xt, const float* __restrict__ wt,
                         float* __restrict__ xi, float* __restrict__ z) {
  int t = threadIdx.x;
  int wv = t >> 6, lane = t & 63;
  int rq = blockIdx.x * 256 + wv * 64 + lane;   // float4-row index (row = rq*4)
  int c0 = blockIdx.y * 8;
  const float4* xt4 = (const float4*)xt;
  float4 acc[8];
#pragma unroll
  for (int c = 0; c < 8; ++c) acc[c] = make_float4(0.f, 0.f, 0.f, 0.f);
  for (int k = 0; k < 96; ++k) {
    float4 xv = xt4[(size_t)k * (NR / 4) + rq];
    const float* wr = wt + k * 384 + c0;  // wave-uniform -> s_load
#pragma unroll
    for (int c = 0; c < 8; ++c) {
      float w = wr[c];
      acc[c].x += w * xv.x; acc[c].y += w * xv.y;
      acc[c].z += w * xv.z; acc[c].w += w * xv.w;
    }
  }
  float* dst; int cc;
  if (c0 < DIv) { dst = xi; cc = c0; } else { dst = z; cc = c0 - DIv; }
#pragma unroll
  for (int li = 0; li < 4; ++li) {
    size_t row = (size_t)rq * 4 + li;
    float4 v0, v1;
    v0.x = (&acc[0].x)[li]; v0.y = (&acc[1].x)[li];
    v0.z = (&acc[2].x)[li]; v0.w = (&acc[3].x)[li];
    v1.x = (&acc[4].x)[li]; v1.y = (&acc[5].x)[li];
    v1.z = (&acc[6].x)[li]; v1.w = (&acc[7].x)[li];
    float4* o4 = (float4*)(dst + row * DIv + cc);
    o4[0] = v0; o4[1] = v1;
  }
}

// K2 (tiled): xc = silu(dwconv3x3(xi) + conv_b). 16x16 tile x 32 ch, halo +-1.
constexpr int TW2 = 18;
__global__ void k_dwconv2(const float* __restrict__ xi, const float* __restrict__ cw,
                          const float* __restrict__ cb, float* __restrict__ xc) {
  int tile = blockIdx.x;            // 0..15 (4x4 spatial tiles)
  int cg = blockIdx.y, b = blockIdx.z;
  int t = threadIdx.x;              // 256
  int ti0 = (tile >> 2) * 16, tj0 = (tile & 3) * 16;
  __shared__ float sm[TW2 * TW2 * 32];

  for (int e = t; e < TW2 * TW2 * 32; e += 256) {
    int ec = e & 31;
    int sp = e >> 5;                // 0..323
    int hi = sp / TW2, hj = sp % TW2;
    int gi = ti0 + hi - 1, gj = tj0 + hj - 1;
    float v = 0.f;
    if ((unsigned)gi < (unsigned)HH && (unsigned)gj < (unsigned)WW)
      v = xi[((size_t)b * LL + gi * WW + gj) * DIv + cg * 32 + ec];
    sm[e] = v;
  }

  int c = t & 31;
  int cglob = cg * 32 + c;
  float wc[9];
#pragma unroll
  for (int j = 0; j < 9; ++j) wc[j] = cw[cglob * 9 + j];
  float bv = cb[cglob];
  __syncthreads();

  int s0 = t >> 5;  // 0..7
  for (int i = 0; i < 32; ++i) {
    int p = s0 + (i << 3);          // 0..255
    int r = p >> 4, q = p & 15;
    float s = bv;
#pragma unroll
    for (int di = 0; di < 3; ++di)
#pragma unroll
      for (int dj = 0; dj < 3; ++dj)
        s += sm[((r + di) * TW2 + (q + dj)) * 32 + c] * wc[di * 3 + dj];
    xc[((size_t)b * LL + (ti0 + r) * WW + (tj0 + q)) * DIv + cglob] = s * sigf(s);
  }
}

// K3pre-a: spatial transpose per (d,b): xcTs[d][b][j*64+i] = xcT[d][b][i*64+j]
__global__ void k_spt(const float* __restrict__ xcT, float* __restrict__ xcTs) {
  __shared__ float tile[64][65];
  int d = blockIdx.x >> 2, b = blockIdx.x & 3;
  int t = threadIdx.x;  // 256
  const float* src = xcT + (size_t)d * NR + b * LL;
  float* dst = xcTs + (size_t)d * NR + b * LL;
#pragma unroll
  for (int it = 0; it < 16; ++it) {
    int idx = it * 256 + t;
    tile[idx >> 6][idx & 63] = src[idx];
  }
  __syncthreads();
#pragma unroll
  for (int it = 0; it < 16; ++it) {
    int idx = it * 256 + t;
    dst[idx] = tile[idx & 63][idx >> 6];
  }
}

// K3pre-b: wcatT[p][d][76]: cols 0..37 = w_{k=p}[c][d], 38..75 = w_{k=p+2}[c][d]
__global__ void k_wcat(const float* __restrict__ xpw, float* __restrict__ wcatT) {
  int idx = blockIdx.x * 256 + threadIdx.x;  // 2*192*76 = 29184
  if (idx < 2 * 192 * 76) {
    int p = idx / (192 * 76);
    int rem = idx % (192 * 76);
    int d = rem / 76, j = rem % 76;
    int k = (j >= 38 ? 2 : 0) + p;
    int c = (j >= 38) ? j - 38 : j;
    wcatT[idx] = xpw[((size_t)(k * 38 + c)) * DIv + d];
  }
}

// K3a: x_dbl via transposed operands; stride-40 layout, zeroes pad cols 6,7.
__global__ void k_xdbl2(const float* __restrict__ xcT, const float* __restrict__ xcTs,
                        const float* __restrict__ wcatT, float* __restrict__ xdbl) {
  int t = threadIdx.x;                  // 256
  int rq = blockIdx.x * 256 + t;        // 0..1023 f4-row within b
  int jg = blockIdx.y;                  // 0..18 -> cols jg*4..jg*4+3
  int pb = blockIdx.z;                  // p*4 + b
  int p = pb >> 2, b = pb & 3;
  const float4* A = (const float4*)(p ? xcTs : xcT);
  const float* wbase = wcatT + (size_t)p * 192 * 76 + jg * 4;
  float4 acc[4];
#pragma unroll
  for (int j = 0; j < 4; ++j) acc[j] = make_float4(0.f, 0.f, 0.f, 0.f);
  for (int d = 0; d < 192; ++d) {
    float4 xv = A[(size_t)d * (NR / 4) + b * 1024 + rq];
    const float* wr = wbase + d * 76;   // wave-uniform -> s_load
#pragma unroll
    for (int j = 0; j < 4; ++j) {
      float w = wr[j];
      acc[j].x += w * xv.x; acc[j].y += w * xv.y;
      acc[j].z += w * xv.z; acc[j].w += w * xv.w;
    }
  }
#pragma unroll
  for (int li = 0; li < 4; ++li) {
    int r = rq * 4 + li;
#pragma unroll
    for (int j = 0; j < 4; ++j) {
      int col = jg * 4 + j;
      int kk = (col >= 38) ? (2 + p) : p;
      int c = (col >= 38) ? col - 38 : col;
      int l = (col >= 38) ? (LL - 1 - r) : r;
      int phys = c + (c >= 6 ? 2 : 0);
      size_t ro = (((size_t)(b * KKv + kk)) * LL + l) * XDS;
      xdbl[ro + phys] = (&acc[j].x)[li];
      if (col == 5) { xdbl[ro + 6] = 0.f; xdbl[ro + 7] = 0.f; }
    }
  }
}

// K4a: chunked scan pass 1. Delta computed in-kernel from staged dt cols.
// Block 256 = 64 d x 4 nq; grid (NC*3, K, B).
__global__ void k_scan1(const float* __restrict__ xdbl, const float* __restrict__ xc,
                        const float* __restrict__ alogs, const float* __restrict__ dtw,
                        const float* __restrict__ dtb,
                        float* __restrict__ S, float* __restrict__ P) {
  int bx = blockIdx.x;
  int c = bx / 3, dblk = bx % 3;
  int k = blockIdx.y, b = blockIdx.z;
  int t = threadIdx.x, dl = t >> 2, nq = t & 3;
  int d = dblk * 64 + dl;
  __shared__ float de_s[16][64], xv_s[16][64], bc_s[16][32], dt_s[16][8];
  float A[4];
#pragma unroll
  for (int j = 0; j < 4; ++j)
    A[j] = -__expf(alogs[(size_t)(k * DIv + d) * DSn + nq * 4 + j]);
  // de-compute role: this thread covers row (t>>4), d-cols (t&15)*4..+3 of dblk
  int derow = t >> 4, dec0 = (t & 15) * 4;
  float DTW[4][6], DTB[4];
#pragma unroll
  for (int jj = 0; jj < 4; ++jj) {
    int dd = k * DIv + dblk * 64 + dec0 + jj;
    DTB[jj] = dtb[dd];
#pragma unroll
    for (int r2 = 0; r2 < 6; ++r2) DTW[jj][r2] = dtw[(size_t)dd * 6 + r2];
  }
  size_t bkL = (size_t)(b * KKv + k) * LL;
  const float* xq = xdbl + bkL * XDS;
  const float* xcb = xc + (size_t)b * LL * DIv;
  float h[4] = {0.f, 0.f, 0.f, 0.f}, sA[4] = {0.f, 0.f, 0.f, 0.f};
  int l0 = c * CHK;
  for (int tile = 0; tile < CHK / 16; ++tile) {
    int lt = l0 + tile * 16;
    __syncthreads();
    {
      int r = t >> 4, q = t & 15;
      int lc = lmap(k, lt + r);
      *(float4*)&xv_s[r][q * 4] = *(const float4*)(xcb + (size_t)lc * DIv + dblk * 64 + q * 4);
      if (t < 128) {
        int r2 = t >> 3, q2 = t & 7;
        *(float4*)&bc_s[r2][q2 * 4] = *(const float4*)(xq + (size_t)(lt + r2) * XDS + 8 + q2 * 4);
      } else if (t < 160) {
        int i3 = t - 128, r3 = i3 >> 1, half = i3 & 1;
        *(float4*)&dt_s[r3][half * 4] = *(const float4*)(xq + (size_t)(lt + r3) * XDS + half * 4);
      }
    }
    __syncthreads();
    {
#pragma unroll
      for (int jj = 0; jj < 4; ++jj) {
        float s = DTB[jj];
#pragma unroll
        for (int r2 = 0; r2 < 6; ++r2) s += dt_s[derow][r2] * DTW[jj][r2];
        de_s[derow][dec0 + jj] = softp(s);
      }
    }
    __syncthreads();
#pragma unroll
    for (int i2 = 0; i2 < 16; ++i2) {
      float de = de_s[i2][dl];
      float xv = xv_s[i2][dl];
      float4 Bv = *(float4*)&bc_s[i2][nq * 4];
      float db = de * xv;
#pragma unroll
      for (int j = 0; j < 4; ++j) {
        float u = de * A[j];
        sA[j] += u;
        h[j] = h[j] * __expf(u) + db * (&Bv.x)[j];
      }
    }
  }
  size_t o = ((((size_t)(b * KKv + k) * NC + c) * 3 + dblk) * 1024) + (size_t)t * 4;
  float4 hs, ps;
#pragma unroll
  for (int j = 0; j < 4; ++j) { (&hs.x)[j] = h[j]; (&ps.x)[j] = __expf(sA[j]); }
  *(float4*)(S + o) = hs;
  *(float4*)(P + o) = ps;
}

// K4b: sequential chunk combine (float4 per thread). Rewrites S[c] <- Hin[c].
__global__ void k_scan2(float* __restrict__ S, const float* __restrict__ P) {
  int dblk = blockIdx.x, k = blockIdx.y, b = blockIdx.z;
  int t = threadIdx.x;  // 256
  size_t base = (((size_t)(b * KKv + k) * NC) * 3 + dblk) * 1024 + (size_t)t * 4;
  float4 h = make_float4(0.f, 0.f, 0.f, 0.f);
  for (int c = 0; c < NC; ++c) {
    size_t o = base + (size_t)c * 3 * 1024;
    float4 s = *(float4*)(S + o), p = *(float4*)(P + o);
    *(float4*)(S + o) = h;  // Hin for chunk c
    h.x = s.x + p.x * h.x; h.y = s.y + p.y * h.y;
    h.z = s.z + p.z * h.z; h.w = s.w + p.w * h.w;
  }
}

// K4c: chunked scan pass 3 — delta in-kernel; width-4 shuffle for y.
__global__ void k_scan3(const float* __restrict__ xdbl, const float* __restrict__ xc,
                        const float* __restrict__ alogs, const float* __restrict__ dtw,
                        const float* __restrict__ dtb,
                        const float* __restrict__ Hin, float* __restrict__ ys) {
  int bx = blockIdx.x;
  int c = bx / 3, dblk = bx % 3;
  int k = blockIdx.y, b = blockIdx.z;
  int t = threadIdx.x, dl = t >> 2, nq = t & 3;
  int d = dblk * 64 + dl;
  __shared__ float de_s[16][64], xv_s[16][64], bc_s[16][32], dt_s[16][8];
  float A[4];
#pragma unroll
  for (int j = 0; j < 4; ++j)
    A[j] = -__expf(alogs[(size_t)(k * DIv + d) * DSn + nq * 4 + j]);
  int derow = t >> 4, dec0 = (t & 15) * 4;
  float DTW[4][6], DTB[4];
#pragma unroll
  for (int jj = 0; jj < 4; ++jj) {
    int dd = k * DIv + dblk * 64 + dec0 + jj;
    DTB[jj] = dtb[dd];
#pragma unroll
    for (int r2 = 0; r2 < 6; ++r2) DTW[jj][r2] = dtw[(size_t)dd * 6 + r2];
  }
  size_t bkL = (size_t)(b * KKv + k) * LL;
  const float* xq = xdbl + bkL * XDS;
  const float* xcb = xc + (size_t)b * LL * DIv;
  float* yp = ys + bkL * DIv + d;
  size_t o = ((((size_t)(b * KKv + k) * NC + c) * 3 + dblk) * 1024) + (size_t)t * 4;
  float4 h4 = *(const float4*)(Hin + o);
  float h[4] = {h4.x, h4.y, h4.z, h4.w};
  int l0 = c * CHK;
  for (int tile = 0; tile < CHK / 16; ++tile) {
    int lt = l0 + tile * 16;
    __syncthreads();
    {
      int r = t >> 4, q = t & 15;
      int lc = lmap(k, lt + r);
      *(float4*)&xv_s[r][q * 4] = *(const float4*)(xcb + (size_t)lc * DIv + dblk * 64 + q * 4);
      if (t < 128) {
        int r2 = t >> 3, q2 = t & 7;
        *(float4*)&bc_s[r2][q2 * 4] = *(const float4*)(xq + (size_t)(lt + r2) * XDS + 8 + q2 * 4);
      } else if (t < 160) {
        int i3 = t - 128, r3 = i3 >> 1, half = i3 & 1;
        *(float4*)&dt_s[r3][half * 4] = *(const float4*)(xq + (size_t)(lt + r3) * XDS + half * 4);
      }
    }
    __syncthreads();
    {
#pragma unroll
      for (int jj = 0; jj < 4; ++jj) {
        float s = DTB[jj];
#pragma unroll
        for (int r2 = 0; r2 < 6; ++r2) s += dt_s[derow][r2] * DTW[jj][r2];
        de_s[derow][dec0 + jj] = softp(s);
      }
    }
    __syncthreads();
#pragma unroll
    for (int i2 = 0; i2 < 16; ++i2) {
      float de = de_s[i2][dl];
      float xv = xv_s[i2][dl];
      float4 Bv = *(float4*)&bc_s[i2][nq * 4];
      float4 Cv = *(float4*)&bc_s[i2][16 + nq * 4];
      float db = de * xv;
      float p = 0.f;
#pragma unroll
      for (int j = 0; j < 4; ++j) {
        h[j] = h[j] * __expf(de * A[j]) + db * (&Bv.x)[j];
        p += h[j] * (&Cv.x)[j];
      }
      p += __shfl_down(p, 2, 4);
      p += __shfl_down(p, 1, 4);
      if (nq == 0) yp[(size_t)(lt + i2) * DIv] = p;
    }
  }
}

// K5+K6 fused: merge 4 directions + D*x skip, LayerNorm(DI), * silu(z) -> ygt
__global__ void k_comln(const float* __restrict__ ys, const float* __restrict__ xc,
                        const float* __restrict__ Ds, const float* __restrict__ z,
                        const float* __restrict__ g, const float* __restrict__ be,
                        float* __restrict__ out) {
  int bl = blockIdx.x;            // b*L + l
  int b = bl >> 12, l = bl & 4095;
  int t = threadIdx.x;            // 64
  int lT = ((l & 63) << 6) | (l >> 6);
  size_t base = (size_t)b * KKv * LL * DIv;
  const float* r0 = ys + base + (size_t)l * DIv;
  const float* r2 = ys + base + ((size_t)2 * LL + (LL - 1 - l)) * DIv;
  const float* r1 = ys + base + ((size_t)1 * LL + lT) * DIv;
  const float* r3 = ys + base + ((size_t)3 * LL + (LL - 1 - lT)) * DIv;
  const float* xr = xc + ((size_t)b * LL + l) * DIv;
  float v[3];
  float s = 0.f, q = 0.f;
#pragma unroll
  for (int cc = 0; cc < 3; ++cc) {
    int d = t + cc * 64;
    float sd = Ds[d] + Ds[DIv + d] + Ds[2 * DIv + d] + Ds[3 * DIv + d];
    float vv = r0[d] + r2[d] + r1[d] + r3[d] + sd * xr[d];
    v[cc] = vv; s += vv; q += vv * vv;
  }
#pragma unroll
  for (int o = 32; o > 0; o >>= 1) { s += __shfl_xor(s, o, 64); q += __shfl_xor(q, o, 64); }
  float m = s / DIv;
  float var = q / DIv - m * m;
  float rs = rsqrtf(var + 1e-5f);
  const float* zr = z + (size_t)bl * DIv;
  float* orow = out + (size_t)bl * DIv;
#pragma unroll
  for (int cc = 0; cc < 3; ++cc) {
    int d = t + cc * 64;
    float zz = zr[d];
    float val = (v[cc] - m) * rs * g[d] + be[d];
    orow[d] = val * zz * sigf(zz);
  }
}

// K7: out0 = ygated @ out_proj_w.T via ygtT/opwT. float2 rows, 4 cols/block.
__global__ void k_outproj3(const float* __restrict__ ygtT, const float* __restrict__ opwT,
                           float* __restrict__ out0) {
  int t = threadIdx.x;                    // 256
  int r2 = blockIdx.x * 256 + t;          // float2-row index
  int c0 = blockIdx.y * 4;
  const float2* x2 = (const float2*)ygtT;
  float2 acc[4];
#pragma unroll
  for (int c = 0; c < 4; ++c) acc[c] = make_float2(0.f, 0.f);
#pragma unroll 4
  for (int k = 0; k < DIv; ++k) {
    float2 xv = x2[(size_t)k * (NR / 2) + r2];
    const float* wr = opwT + k * DMv + c0;  // wave-uniform
#pragma unroll
    for (int c = 0; c < 4; ++c) {
      float w = wr[c];
      acc[c].x += w * xv.x; acc[c].y += w * xv.y;
    }
  }
#pragma unroll
  for (int li = 0; li < 2; ++li) {
    float4 v;
    v.x = (&acc[0].x)[li]; v.y = (&acc[1].x)[li];
    v.z = (&acc[2].x)[li]; v.w = (&acc[3].x)[li];
    *(float4*)(out0 + ((size_t)r2 * 2 + li) * DMv + c0) = v;
  }
}

// K8: hcl = silu(ygated @ ffn_in_w.T + b). float2 rows, 16 cols/block.
__global__ void k_ffnin3(const float* __restrict__ ygtT, const float* __restrict__ fiwT,
                         const float* __restrict__ bias, float* __restrict__ hcl) {
  int t = threadIdx.x;                    // 256
  int r2 = blockIdx.x * 256 + t;          // float2-row index
  int c0 = blockIdx.y * 16;
  const float2* x2 = (const float2*)ygtT;
  float2 acc[16];
#pragma unroll
  for (int c = 0; c < 16; ++c) acc[c] = make_float2(0.f, 0.f);
#pragma unroll 4
  for (int k = 0; k < DIv; ++k) {
    float2 xv = x2[(size_t)k * (NR / 2) + r2];
    const float* wr = fiwT + k * HIDv + c0;  // wave-uniform
#pragma unroll
    for (int c = 0; c < 16; ++c) {
      float w = wr[c];
      acc[c].x += w * xv.x; acc[c].y += w * xv.y;
    }
  }
#pragma unroll
  for (int li = 0; li < 2; ++li) {
    size_t row = (size_t)r2 * 2 + li;
#pragma unroll
    for (int cc = 0; cc < 4; ++cc) {
      float4 v;
#pragma unroll
      for (int j = 0; j < 4; ++j) {
        float s = (&acc[cc * 4 + j].x)[li] + bias[c0 + cc * 4 + j];
        (&v.x)[j] = s * sigf(s);
      }
      *(float4*)(hcl + row * HIDv + c0 + cc * 4) = v;
    }
  }
}

// K9 (tiled): hc2 = (1 + w1)*hc(center) + dwconv3(hc) + dwconv5(hc), fused 5x5 stencil.
constexpr int TS = 16, CG = 32, TW = TS + 4;  // TW=20
__global__ void k_ffnconv(const float* __restrict__ hcl, const float* __restrict__ w1,
                          const float* __restrict__ w3, const float* __restrict__ w5,
                          float* __restrict__ hc2) {
  int tile = blockIdx.x;            // 0..15 (4x4 spatial tiles)
  int cg = blockIdx.y, b = blockIdx.z;
  int t = threadIdx.x;              // 256
  int ti0 = (tile >> 2) * TS, tj0 = (tile & 3) * TS;
  __shared__ float sm[TW * TW * CG];

  for (int e = t; e < TW * TW * CG; e += 256) {
    int ec = e & 31;
    int sp = e >> 5;                // 0..399
    int hi = sp / TW, hj = sp % TW;
    int gi = ti0 + hi - 2, gj = tj0 + hj - 2;
    float v = 0.f;
    if ((unsigned)gi < (unsigned)HH && (unsigned)gj < (unsigned)WW)
      v = hcl[((size_t)b * LL + gi * WW + gj) * HIDv + cg * CG + ec];
    sm[e] = v;
  }

  int c = t & 31;
  int cglob = cg * CG + c;
  float wc[25];
#pragma unroll
  for (int di = 0; di < 5; ++di)
#pragma unroll
    for (int dj = 0; dj < 5; ++dj) {
      float w = w5[cglob * 25 + di * 5 + dj];
      if (di >= 1 && di <= 3 && dj >= 1 && dj <= 3)
        w += w3[cglob * 9 + (di - 1) * 3 + (dj - 1)];
      if (di == 2 && dj == 2) w += 1.f + w1[cglob];
      wc[di * 5 + dj] = w;
    }
  __syncthreads();

  int s0 = t >> 5;  // 0..7
  for (int i = 0; i < 32; ++i) {
    int p = s0 + (i << 3);          // 0..255
    int r = p >> 4, q = p & 15;
    float s = 0.f;
#pragma unroll
    for (int di = 0; di < 5; ++di)
#pragma unroll
      for (int dj = 0; dj < 5; ++dj)
        s += sm[((r + di) * TW + (q + dj)) * CG + c] * wc[di * 5 + dj];
    hc2[((size_t)b * LL + (ti0 + r) * WW + (tj0 + q)) * HIDv + cglob] = s;
  }
}

// K10: fused LayerNorm(HID) + transpose: hc2[NR][768] -> hnT[768][NR].
__global__ void k_ln2t(const float* __restrict__ hc2, const float* __restrict__ g,
                       const float* __restrict__ be, float* __restrict__ hnT) {
  int r0 = blockIdx.x * 32;
  int t = threadIdx.x;  // 256
  __shared__ float m_[32], rs_[32];
  __shared__ float tile[32][33];
  {
    int r = t >> 3, q = t & 7;
    const float4* row4 = (const float4*)(hc2 + (size_t)(r0 + r) * HIDv);
    float s = 0.f, qq = 0.f;
#pragma unroll
    for (int j = 0; j < 24; ++j) {
      float4 v = row4[q + j * 8];
      s += v.x + v.y + v.z + v.w;
      qq += v.x * v.x + v.y * v.y + v.z * v.z + v.w * v.w;
    }
    s += __shfl_down(s, 4, 8); qq += __shfl_down(qq, 4, 8);
    s += __shfl_down(s, 2, 8); qq += __shfl_down(qq, 2, 8);
    s += __shfl_down(s, 1, 8); qq += __shfl_down(qq, 1, 8);
    if (q == 0) {
      float m = s / HIDv;
      m_[r] = m;
      rs_[r] = rsqrtf(qq / HIDv - m * m + 1e-5f);
    }
  }
  __syncthreads();
  int tc = t & 31, tr = t >> 5;  // tr 0..7
  for (int ch = 0; ch < 24; ++ch) {
    int c0 = ch * 32;
    float gg = g[c0 + tc], bb = be[c0 + tc];
    __syncthreads();
#pragma unroll
    for (int i = 0; i < 4; ++i) {
      int r = tr + i * 8;
      float v = hc2[(size_t)(r0 + r) * HIDv + c0 + tc];
      tile[tc][r] = (v - m_[r]) * rs_[r] * gg + bb;
    }
    __syncthreads();
#pragma unroll
    for (int i = 0; i < 4; ++i) {
      int cr = tr + i * 8;
      hnT[(size_t)(c0 + cr) * NR + r0 + tc] = tile[cr][tc];
    }
  }
}

// K11a: split-K partial GEMM: part[ks][row][c] = sum_{k in seg} hnT*fowT.
__global__ void k_final3(const float* __restrict__ hnT, const float* __restrict__ fowT,
                         float* __restrict__ part) {
  int t = threadIdx.x;                    // 128
  int rq = blockIdx.x * 128 + t;          // f4-row
  int c0 = blockIdx.y * 8;
  int ks = blockIdx.z;                    // 4 segments of 192
  const float4* x4 = (const float4*)hnT;
  float4 acc[8];
#pragma unroll
  for (int c = 0; c < 8; ++c) acc[c] = make_float4(0.f, 0.f, 0.f, 0.f);
  int k0 = ks * 192;
#pragma unroll 4
  for (int k = k0; k < k0 + 192; ++k) {
    float4 xv = x4[(size_t)k * (NR / 4) + rq];
    const float* wr = fowT + k * DMv + c0;  // wave-uniform
#pragma unroll
    for (int c = 0; c < 8; ++c) {
      float w = wr[c];
      acc[c].x += w * xv.x; acc[c].y += w * xv.y;
      acc[c].z += w * xv.z; acc[c].w += w * xv.w;
    }
  }
  float* pb = part + (size_t)ks * NR * DMv;
#pragma unroll
  for (int li = 0; li < 4; ++li) {
    size_t row = (size_t)rq * 4 + li;
#pragma unroll
    for (int cc = 0; cc < 2; ++cc) {
      float4 v;
#pragma unroll
      for (int j = 0; j < 4; ++j) (&v.x)[j] = (&acc[cc * 4 + j].x)[li];
      *(float4*)(pb + row * DMv + c0 + cc * 4) = v;
    }
  }
}

// K11b: dout = out0 + skip*(sum_k part[k] + bias), float4 elementwise.
__global__ void k_finred(const float* __restrict__ part, const float* __restrict__ out0,
                         const float* __restrict__ bias, const float* __restrict__ skip,
                         float* __restrict__ dout) {
  size_t i = (size_t)blockIdx.x * 256 + threadIdx.x;   // f4 index over NR*DMv/4
  int cq = (int)(i % (DMv / 4));
  const float4* p4 = (const float4*)part;
  size_t npart = (size_t)NR * DMv / 4;
  float4 a = p4[i], b2 = p4[i + npart], c2 = p4[i + 2 * npart], d2 = p4[i + 3 * npart];
  float4 o = ((const float4*)out0)[i];
  float4 bi = ((const float4*)bias)[cq];
  float sk = skip[0];
  float4 r;
  r.x = o.x + sk * (a.x + b2.x + c2.x + d2.x + bi.x);
  r.y = o.y + sk * (a.y + b2.y + c2.y + d2.y + bi.y);
  r.z = o.z + sk * (a.z + b2.z + c2.z + d2.z + bi.z);
  r.w = o.w + sk * (a.w + b2.w + c2.w + d2.w + bi.w);
  ((float4*)dout)[i] = r;
}

extern "C" void kernel_launch(void* const* d_in, const int* in_sizes, int n_in,
                              void* d_out, int out_size, void* d_ws, size_t ws_size,
                              hipStream_t stream) {
  const float* x        = (const float*)d_in[0];
  const float* in_w     = (const float*)d_in[1];
  const float* conv_w   = (const float*)d_in[2];
  const float* conv_b   = (const float*)d_in[3];
  const float* xpw      = (const float*)d_in[4];
  const float* dtw      = (const float*)d_in[5];
  const float* dtb      = (const float*)d_in[6];
  const float* alogs    = (const float*)d_in[7];
  const float* Ds       = (const float*)d_in[8];
  const float* ong      = (const float*)d_in[9];
  const float* onb      = (const float*)d_in[10];
  const float* opw      = (const float*)d_in[11];
  const float* fiw      = (const float*)d_in[12];
  const float* fib      = (const float*)d_in[13];
  const float* dw1      = (const float*)d_in[14];
  const float* dw3      = (const float*)d_in[15];
  const float* dw5      = (const float*)d_in[16];
  const float* flg      = (const float*)d_in[17];
  const float* flb      = (const float*)d_in[18];
  const float* fow      = (const float*)d_in[19];
  const float* fob      = (const float*)d_in[20];
  const float* skip     = (const float*)d_in[21];

  // Workspace layout (aliased; ~150 MB)
  float* ws    = (float*)d_ws;
  float* xi    = ws;                 // -> S/P -> ygtT -> part (with z)
  float* z     = xi + S_xi;
  float* xc    = z + S_xi;           // -> ygt
  float* xdbl  = xc + S_xi;          // -> out0
  float* scr   = xdbl + S_xdbl;      // xt/wt scratch -> hcl -> hnT
  float* ys    = scr + S_big;        // xcT/xcTs scratch -> ys -> hc2
  float* wtiny = ys + S_big;         // persistent small weight transposes
  float* fiwT  = wtiny;              // 192*768 = 147456
  float* opwT  = fiwT + 147456;      // 192*96  = 18432
  float* fowT  = opwT + 18432;       // 768*96  = 73728
  float* wcatT = fowT + 73728;       // 2*192*76 = 29184

  // Small weight transposes (persist whole launch)
  k_transp<<<dim3(24, 6), 256, 0, stream>>>(fiw, fiwT, HIDv, DIv);   // 768x192 -> 192x768
  k_transp<<<dim3(3, 6), 256, 0, stream>>>(opw, opwT, DMv, DIv);     // 96x192  -> 192x96
  k_transp<<<dim3(3, 24), 256, 0, stream>>>(fow, fowT, DMv, HIDv);   // 96x768  -> 768x96
  k_wcat<<<114, 256, 0, stream>>>(xpw, wcatT);

  // In-proj via transposed operands (xt, wt in scr region)
  float* xt = scr;                         // 96*16384 floats
  float* wt = scr + 1600000;               // 36,864 floats (within S_big)
  k_wt<<<(96 * 384 + 255) / 256, 256, 0, stream>>>(in_w, wt);
  dim3 gxt(NR / 64, 3);
  k_xt<<<gxt, 256, 0, stream>>>(x, xt);
  dim3 gip(NR / 1024, 48);
  k_inproj<<<gip, 256, 0, stream>>>(xt, wt, xi, z);

  dim3 gdw(16, DIv / 32, BB);        // 16 tiles x 6 ch-groups x 4
  k_dwconv2<<<gdw, 256, 0, stream>>>(xi, conv_w, conv_b, xc);

  // x_dbl GEMM via transposed operands (xcT/xcTs in ys region, free until k_scan3)
  float* xcT  = ys;                  // 192*16384 = 3,145,728
  float* xcTs = ys + S_xi;           // 3,145,728 (6.3M < S_big)
  k_transp<<<dim3(512, 6), 256, 0, stream>>>(xc, xcT, NR, DIv);
  k_spt<<<DIv * BB, 256, 0, stream>>>(xcT, xcTs);
  dim3 gxd(4, 19, 8);                // rq-blocks x col-groups x (p*4+b)
  k_xdbl2<<<gxd, 256, 0, stream>>>(xcT, xcTs, wcatT, xdbl);

  // Chunked scan (delta fused in): S/P buffers alias xi region? No — alias xi is
  // needed for ygtT later; S/P use xi as before (dead until ygtT lands there)
  float* Sbuf = xi;                  // S_sp floats
  float* Pbuf = xi + S_sp;           // S_sp floats (S_sp*2 == S_xi exactly)
  dim3 gs13(NC * 3, KKv, BB);        // 1536 blocks, 64d x 4nq threads
  dim3 gs2(3, KKv, BB);              // 48 blocks (tiny)
  k_scan1<<<gs13, 256, 0, stream>>>(xdbl, xc, alogs, dtw, dtb, Sbuf, Pbuf);
  k_scan2<<<gs2, 256, 0, stream>>>(Sbuf, Pbuf);  // S <- Hin
  k_scan3<<<gs13, 256, 0, stream>>>(xdbl, xc, alogs, dtw, dtb, Sbuf, ys);

  // Fused combine + LayerNorm + silu-gate -> ygt
  float* ygt = xc;
  k_comln<<<BB * LL, 64, 0, stream>>>(ys, xc, Ds, z, ong, onb, ygt);

  // Transpose ygt (16384x192 -> 192x16384) into xi (S/P dead)
  float* ygtT = xi;
  k_transp<<<dim3(512, 6), 256, 0, stream>>>(ygt, ygtT, NR, DIv);

  float* out0 = xdbl;
  dim3 gop(NR / 512, DMv / 4);       // (32, 24) = 768 blocks
  k_outproj3<<<gop, 256, 0, stream>>>(ygtT, opwT, out0);
  float* hcl = scr;
  dim3 gfi(NR / 512, HIDv / 16);     // (32, 48) = 1536 blocks
  k_ffnin3<<<gfi, 256, 0, stream>>>(ygtT, fiwT, fib, hcl);
  float* hc2 = ys;
  dim3 gc(16, HIDv / CG, BB);        // 16 spatial tiles x 24 ch-groups x 4
  k_ffnconv<<<gc, 256, 0, stream>>>(hcl, dw1, dw3, dw5, hc2);

  // Fused LayerNorm + transpose: hc2 (ys) -> hnT (scr; hcl dead)
  float* hnT = scr;
  k_ln2t<<<NR / 32, 256, 0, stream>>>(hc2, flg, flb, hnT);

  // Split-K final GEMM: partials in xi+z region (ygtT dead after ffnin3)
  float* part = xi;                  // 4 * NR * 96 = 6,291,456 floats (= 2*S_xi)
  dim3 gfn(NR / 512, DMv / 8, 4);    // (32, 12, 4), block 128
  k_final3<<<gfn, 128, 0, stream>>>(hnT, fowT, part);
  k_finred<<<(NR * DMv / 4) / 256, 256, 0, stream>>>(part, out0, fob, skip, (float*)d_out);
}

// Round 14
// 513.637 us; speedup vs baseline: 3.5422x; 1.0801x over previous
//
#include <hip/hip_runtime.h>
#include <hip/hip_bf16.h>

constexpr int BB = 4, HH = 64, WW = 64, DMv = 96;
constexpr int DSn = 16, DIv = 192, DTRv = 6, KKv = 4, HIDv = 768;
constexpr int LL = 4096;
constexpr int NC = 32, CHK = LL / NC;       // 32 chunks of 128
constexpr int NR = BB * LL;                 // 16384 rows
constexpr int XDS = 40;                     // padded xdbl row stride (dt 0-5, B 8-23, C 24-39)

constexpr size_t S_xi   = (size_t)BB * LL * DIv;          // 3,145,728
constexpr size_t S_xdbl = (size_t)BB * KKv * LL * XDS;    // 2,621,440
constexpr size_t S_big  = (size_t)BB * KKv * LL * DIv;    // 12,582,912
constexpr size_t S_sp   = (size_t)BB * KKv * NC * DIv * DSn;  // 1,572,864 (= S_xi/2)

__device__ __forceinline__ float sigf(float x) { return 1.f / (1.f + __expf(-x)); }
__device__ __forceinline__ float softp(float x) {
  return (x > 20.f) ? x : __logf(1.f + __expf(x));
}

__device__ __forceinline__ int lmap(int k, int l) {
  int lr = (k & 2) ? (LL - 1 - l) : l;
  return (k & 1) ? (((lr & 63) << 6) | (lr >> 6)) : lr;
}

// Generic 32x32 LDS tile transpose: src[R][C] -> dst[C][R], both coalesced.
__global__ void k_transp(const float* __restrict__ src, float* __restrict__ dst,
                         int R, int C) {
  __shared__ float tile[32][33];
  int r0 = blockIdx.x * 32, c0 = blockIdx.y * 32;
  int t = threadIdx.x;            // 256
  int tc = t & 31, tr = t >> 5;   // tr 0..7
#pragma unroll
  for (int i = 0; i < 4; ++i) {
    int r = r0 + tr + i * 8;
    if (r < R && c0 + tc < C) tile[tr + i * 8][tc] = src[(size_t)r * C + c0 + tc];
  }
  __syncthreads();
#pragma unroll
  for (int i = 0; i < 4; ++i) {
    int c = c0 + tr + i * 8;
    int r = r0 + tc;
    if (c < C && r < R) dst[(size_t)c * R + r] = tile[tc][tr + i * 8];
  }
}

// K0: merged weight prep — 4 transposes + wcat, block-range dispatched. 384 blocks.
__global__ void k_wprep(const float* __restrict__ fiw, const float* __restrict__ opw,
                        const float* __restrict__ fow, const float* __restrict__ in_w,
                        const float* __restrict__ xpw,
                        float* __restrict__ fiwT, float* __restrict__ opwT,
                        float* __restrict__ fowT, float* __restrict__ wt,
                        float* __restrict__ wcatT) {
  int bx = blockIdx.x, t = threadIdx.x;
  if (bx >= 270) {  // wcatT[p][d][76]
    int idx = (bx - 270) * 256 + t;
    if (idx < 2 * 192 * 76) {
      int p = idx / (192 * 76);
      int rem = idx % (192 * 76);
      int d = rem / 76, j = rem % 76;
      int k = (j >= 38 ? 2 : 0) + p;
      int c = (j >= 38) ? j - 38 : j;
      wcatT[idx] = xpw[((size_t)(k * 38 + c)) * DIv + d];
    }
    return;
  }
  const float* src; float* dst; int R, C, r0, c0;
  if (bx < 144)      { src = fiw;  dst = fiwT; R = 768; C = 192; r0 = (bx / 6) * 32;         c0 = (bx % 6) * 32; }
  else if (bx < 162) { int i = bx - 144; src = opw; dst = opwT; R = 96;  C = 192; r0 = (i / 6) * 32;  c0 = (i % 6) * 32; }
  else if (bx < 234) { int i = bx - 162; src = fow; dst = fowT; R = 96;  C = 768; r0 = (i / 24) * 32; c0 = (i % 24) * 32; }
  else               { int i = bx - 234; src = in_w; dst = wt;  R = 384; C = 96;  r0 = (i / 3) * 32;  c0 = (i % 3) * 32; }
  __shared__ float tile[32][33];
  int tc = t & 31, tr = t >> 5;
#pragma unroll
  for (int i = 0; i < 4; ++i) {
    int r = r0 + tr + i * 8;
    if (r < R && c0 + tc < C) tile[tr + i * 8][tc] = src[(size_t)r * C + c0 + tc];
  }
  __syncthreads();
#pragma unroll
  for (int i = 0; i < 4; ++i) {
    int c = c0 + tr + i * 8;
    int r = r0 + tc;
    if (c < C && r < R) dst[(size_t)c * R + r] = tile[tc][tr + i * 8];
  }
}

// K0b: xt[k][row] = x[row][k]  (96 x 16384), 64x32 LDS tile transpose
__global__ void k_xt(const float* __restrict__ x, float* __restrict__ xt) {
  __shared__ float tile[32][65];
  int r0 = blockIdx.x * 64, k0 = blockIdx.y * 32;
  int t = threadIdx.x;  // 256
#pragma unroll
  for (int ii = 0; ii < 8; ++ii) {
    int i = (t >> 5) + ii * 8, j = t & 31;
    tile[j][i] = x[(size_t)(r0 + i) * 96 + k0 + j];
  }
  __syncthreads();
#pragma unroll
  for (int jj = 0; jj < 8; ++jj) {
    int j = (t >> 6) + jj * 4, i = t & 63;
    xt[(size_t)(k0 + j) * NR + r0 + i] = tile[j][i];
  }
}

// K1: xz = x @ in_proj_w.T via xt/wt. Lane = 4 rows (f4, coalesced), wave-uniform
// scalar weight loads.
__global__ void k_inproj(const float* __restrict__ xt, const float* __restrict__ wt,
                         float* __restrict__ xi, float* __restrict__ z) {
  int t = threadIdx.x;
  int wv = t >> 6, lane = t & 63;
  int rq = blockIdx.x * 256 + wv * 64 + lane;   // float4-row index (row = rq*4)
  int c0 = blockIdx.y * 8;
  const float4* xt4 = (const float4*)xt;
  float4 acc[8];
#pragma unroll
  for (int c = 0; c < 8; ++c) acc[c] = make_float4(0.f, 0.f, 0.f, 0.f);
  for (int k = 0; k < 96; ++k) {
    float4 xv = xt4[(size_t)k * (NR / 4) + rq];
    const float* wr = wt + k * 384 + c0;  // wave-uniform -> s_load
#pragma unroll
    for (int c = 0; c < 8; ++c) {
      float w = wr[c];
      acc[c].x += w * xv.x; acc[c].y += w * xv.y;
      acc[c].z += w * xv.z; acc[c].w += w * xv.w;
    }
  }
  float* dst; int cc;
  if (c0 < DIv) { dst = xi; cc = c0; } else { dst = z; cc = c0 - DIv; }
#pragma unroll
  for (int li = 0; li < 4; ++li) {
    size_t row = (size_t)rq * 4 + li;
    float4 v0, v1;
    v0.x = (&acc[0].x)[li]; v0.y = (&acc[1].x)[li];
    v0.z = (&acc[2].x)[li]; v0.w = (&acc[3].x)[li];
    v1.x = (&acc[4].x)[li]; v1.y = (&acc[5].x)[li];
    v1.z = (&acc[6].x)[li]; v1.w = (&acc[7].x)[li];
    float4* o4 = (float4*)(dst + row * DIv + cc);
    o4[0] = v0; o4[1] = v1;
  }
}

// K2 (tiled): xc = silu(dwconv3x3(xi) + conv_b). 16x16 tile x 32 ch, halo +-1.
constexpr int TW2 = 18;
__global__ void k_dwconv2(const float* __restrict__ xi, const float* __restrict__ cw,
                          const float* __restrict__ cb, float* __restrict__ xc) {
  int tile = blockIdx.x;            // 0..15 (4x4 spatial tiles)
  int cg = blockIdx.y, b = blockIdx.z;
  int t = threadIdx.x;              // 256
  int ti0 = (tile >> 2) * 16, tj0 = (tile & 3) * 16;
  __shared__ float sm[TW2 * TW2 * 32];

  for (int e = t; e < TW2 * TW2 * 32; e += 256) {
    int ec = e & 31;
    int sp = e >> 5;                // 0..323
    int hi = sp / TW2, hj = sp % TW2;
    int gi = ti0 + hi - 1, gj = tj0 + hj - 1;
    float v = 0.f;
    if ((unsigned)gi < (unsigned)HH && (unsigned)gj < (unsigned)WW)
      v = xi[((size_t)b * LL + gi * WW + gj) * DIv + cg * 32 + ec];
    sm[e] = v;
  }

  int c = t & 31;
  int cglob = cg * 32 + c;
  float wc[9];
#pragma unroll
  for (int j = 0; j < 9; ++j) wc[j] = cw[cglob * 9 + j];
  float bv = cb[cglob];
  __syncthreads();

  int s0 = t >> 5;  // 0..7
  for (int i = 0; i < 32; ++i) {
    int p = s0 + (i << 3);          // 0..255
    int r = p >> 4, q = p & 15;
    float s = bv;
#pragma unroll
    for (int di = 0; di < 3; ++di)
#pragma unroll
      for (int dj = 0; dj < 3; ++dj)
        s += sm[((r + di) * TW2 + (q + dj)) * 32 + c] * wc[di * 3 + dj];
    xc[((size_t)b * LL + (ti0 + r) * WW + (tj0 + q)) * DIv + cglob] = s * sigf(s);
  }
}

// K3pre-a: spatial transpose per (d,b): xcTs[d][b][j*64+i] = xcT[d][b][i*64+j]
__global__ void k_spt(const float* __restrict__ xcT, float* __restrict__ xcTs) {
  __shared__ float tile[64][65];
  int d = blockIdx.x >> 2, b = blockIdx.x & 3;
  int t = threadIdx.x;  // 256
  const float* src = xcT + (size_t)d * NR + b * LL;
  float* dst = xcTs + (size_t)d * NR + b * LL;
#pragma unroll
  for (int it = 0; it < 16; ++it) {
    int idx = it * 256 + t;
    tile[idx >> 6][idx & 63] = src[idx];
  }
  __syncthreads();
#pragma unroll
  for (int it = 0; it < 16; ++it) {
    int idx = it * 256 + t;
    dst[idx] = tile[idx & 63][idx >> 6];
  }
}

// K3a: x_dbl via transposed operands; stride-40 layout, zeroes pad cols 6,7.
__global__ void k_xdbl2(const float* __restrict__ xcT, const float* __restrict__ xcTs,
                        const float* __restrict__ wcatT, float* __restrict__ xdbl) {
  int t = threadIdx.x;                  // 256
  int rq = blockIdx.x * 256 + t;        // 0..1023 f4-row within b
  int jg = blockIdx.y;                  // 0..18 -> cols jg*4..jg*4+3
  int pb = blockIdx.z;                  // p*4 + b
  int p = pb >> 2, b = pb & 3;
  const float4* A = (const float4*)(p ? xcTs : xcT);
  const float* wbase = wcatT + (size_t)p * 192 * 76 + jg * 4;
  float4 acc[4];
#pragma unroll
  for (int j = 0; j < 4; ++j) acc[j] = make_float4(0.f, 0.f, 0.f, 0.f);
  for (int d = 0; d < 192; ++d) {
    float4 xv = A[(size_t)d * (NR / 4) + b * 1024 + rq];
    const float* wr = wbase + d * 76;   // wave-uniform -> s_load
#pragma unroll
    for (int j = 0; j < 4; ++j) {
      float w = wr[j];
      acc[j].x += w * xv.x; acc[j].y += w * xv.y;
      acc[j].z += w * xv.z; acc[j].w += w * xv.w;
    }
  }
#pragma unroll
  for (int li = 0; li < 4; ++li) {
    int r = rq * 4 + li;
#pragma unroll
    for (int j = 0; j < 4; ++j) {
      int col = jg * 4 + j;
      int kk = (col >= 38) ? (2 + p) : p;
      int c = (col >= 38) ? col - 38 : col;
      int l = (col >= 38) ? (LL - 1 - r) : r;
      int phys = c + (c >= 6 ? 2 : 0);
      size_t ro = (((size_t)(b * KKv + kk)) * LL + l) * XDS;
      xdbl[ro + phys] = (&acc[j].x)[li];
      if (col == 5) { xdbl[ro + 6] = 0.f; xdbl[ro + 7] = 0.f; }
    }
  }
}

// K4a: chunked scan pass 1. Delta computed in-kernel from staged dt cols.
__global__ void k_scan1(const float* __restrict__ xdbl, const float* __restrict__ xc,
                        const float* __restrict__ alogs, const float* __restrict__ dtw,
                        const float* __restrict__ dtb,
                        float* __restrict__ S, float* __restrict__ P) {
  int bx = blockIdx.x;
  int c = bx / 3, dblk = bx % 3;
  int k = blockIdx.y, b = blockIdx.z;
  int t = threadIdx.x, dl = t >> 2, nq = t & 3;
  int d = dblk * 64 + dl;
  __shared__ float de_s[16][64], xv_s[16][64], bc_s[16][32], dt_s[16][8];
  float A[4];
#pragma unroll
  for (int j = 0; j < 4; ++j)
    A[j] = -__expf(alogs[(size_t)(k * DIv + d) * DSn + nq * 4 + j]);
  int derow = t >> 4, dec0 = (t & 15) * 4;
  float DTW[4][6], DTB[4];
#pragma unroll
  for (int jj = 0; jj < 4; ++jj) {
    int dd = k * DIv + dblk * 64 + dec0 + jj;
    DTB[jj] = dtb[dd];
#pragma unroll
    for (int r2 = 0; r2 < 6; ++r2) DTW[jj][r2] = dtw[(size_t)dd * 6 + r2];
  }
  size_t bkL = (size_t)(b * KKv + k) * LL;
  const float* xq = xdbl + bkL * XDS;
  const float* xcb = xc + (size_t)b * LL * DIv;
  float h[4] = {0.f, 0.f, 0.f, 0.f}, sA[4] = {0.f, 0.f, 0.f, 0.f};
  int l0 = c * CHK;
  for (int tile = 0; tile < CHK / 16; ++tile) {
    int lt = l0 + tile * 16;
    __syncthreads();
    {
      int r = t >> 4, q = t & 15;
      int lc = lmap(k, lt + r);
      *(float4*)&xv_s[r][q * 4] = *(const float4*)(xcb + (size_t)lc * DIv + dblk * 64 + q * 4);
      if (t < 128) {
        int r2 = t >> 3, q2 = t & 7;
        *(float4*)&bc_s[r2][q2 * 4] = *(const float4*)(xq + (size_t)(lt + r2) * XDS + 8 + q2 * 4);
      } else if (t < 160) {
        int i3 = t - 128, r3 = i3 >> 1, half = i3 & 1;
        *(float4*)&dt_s[r3][half * 4] = *(const float4*)(xq + (size_t)(lt + r3) * XDS + half * 4);
      }
    }
    __syncthreads();
    {
#pragma unroll
      for (int jj = 0; jj < 4; ++jj) {
        float s = DTB[jj];
#pragma unroll
        for (int r2 = 0; r2 < 6; ++r2) s += dt_s[derow][r2] * DTW[jj][r2];
        de_s[derow][dec0 + jj] = softp(s);
      }
    }
    __syncthreads();
#pragma unroll
    for (int i2 = 0; i2 < 16; ++i2) {
      float de = de_s[i2][dl];
      float xv = xv_s[i2][dl];
      float4 Bv = *(float4*)&bc_s[i2][nq * 4];
      float db = de * xv;
#pragma unroll
      for (int j = 0; j < 4; ++j) {
        float u = de * A[j];
        sA[j] += u;
        h[j] = h[j] * __expf(u) + db * (&Bv.x)[j];
      }
    }
  }
  size_t o = ((((size_t)(b * KKv + k) * NC + c) * 3 + dblk) * 1024) + (size_t)t * 4;
  float4 hs, ps;
#pragma unroll
  for (int j = 0; j < 4; ++j) { (&hs.x)[j] = h[j]; (&ps.x)[j] = __expf(sA[j]); }
  *(float4*)(S + o) = hs;
  *(float4*)(P + o) = ps;
}

// K4b: sequential chunk combine (float4 per thread). Rewrites S[c] <- Hin[c].
__global__ void k_scan2(float* __restrict__ S, const float* __restrict__ P) {
  int dblk = blockIdx.x, k = blockIdx.y, b = blockIdx.z;
  int t = threadIdx.x;  // 256
  size_t base = (((size_t)(b * KKv + k) * NC) * 3 + dblk) * 1024 + (size_t)t * 4;
  float4 h = make_float4(0.f, 0.f, 0.f, 0.f);
  for (int c = 0; c < NC; ++c) {
    size_t o = base + (size_t)c * 3 * 1024;
    float4 s = *(float4*)(S + o), p = *(float4*)(P + o);
    *(float4*)(S + o) = h;  // Hin for chunk c
    h.x = s.x + p.x * h.x; h.y = s.y + p.y * h.y;
    h.z = s.z + p.z * h.z; h.w = s.w + p.w * h.w;
  }
}

// K4c: chunked scan pass 3 — delta in-kernel; width-4 shuffle for y.
__global__ void k_scan3(const float* __restrict__ xdbl, const float* __restrict__ xc,
                        const float* __restrict__ alogs, const float* __restrict__ dtw,
                        const float* __restrict__ dtb,
                        const float* __restrict__ Hin, float* __restrict__ ys) {
  int bx = blockIdx.x;
  int c = bx / 3, dblk = bx % 3;
  int k = blockIdx.y, b = blockIdx.z;
  int t = threadIdx.x, dl = t >> 2, nq = t & 3;
  int d = dblk * 64 + dl;
  __shared__ float de_s[16][64], xv_s[16][64], bc_s[16][32], dt_s[16][8];
  float A[4];
#pragma unroll
  for (int j = 0; j < 4; ++j)
    A[j] = -__expf(alogs[(size_t)(k * DIv + d) * DSn + nq * 4 + j]);
  int derow = t >> 4, dec0 = (t & 15) * 4;
  float DTW[4][6], DTB[4];
#pragma unroll
  for (int jj = 0; jj < 4; ++jj) {
    int dd = k * DIv + dblk * 64 + dec0 + jj;
    DTB[jj] = dtb[dd];
#pragma unroll
    for (int r2 = 0; r2 < 6; ++r2) DTW[jj][r2] = dtw[(size_t)dd * 6 + r2];
  }
  size_t bkL = (size_t)(b * KKv + k) * LL;
  const float* xq = xdbl + bkL * XDS;
  const float* xcb = xc + (size_t)b * LL * DIv;
  float* yp = ys + bkL * DIv + d;
  size_t o = ((((size_t)(b * KKv + k) * NC + c) * 3 + dblk) * 1024) + (size_t)t * 4;
  float4 h4 = *(const float4*)(Hin + o);
  float h[4] = {h4.x, h4.y, h4.z, h4.w};
  int l0 = c * CHK;
  for (int tile = 0; tile < CHK / 16; ++tile) {
    int lt = l0 + tile * 16;
    __syncthreads();
    {
      int r = t >> 4, q = t & 15;
      int lc = lmap(k, lt + r);
      *(float4*)&xv_s[r][q * 4] = *(const float4*)(xcb + (size_t)lc * DIv + dblk * 64 + q * 4);
      if (t < 128) {
        int r2 = t >> 3, q2 = t & 7;
        *(float4*)&bc_s[r2][q2 * 4] = *(const float4*)(xq + (size_t)(lt + r2) * XDS + 8 + q2 * 4);
      } else if (t < 160) {
        int i3 = t - 128, r3 = i3 >> 1, half = i3 & 1;
        *(float4*)&dt_s[r3][half * 4] = *(const float4*)(xq + (size_t)(lt + r3) * XDS + half * 4);
      }
    }
    __syncthreads();
    {
#pragma unroll
      for (int jj = 0; jj < 4; ++jj) {
        float s = DTB[jj];
#pragma unroll
        for (int r2 = 0; r2 < 6; ++r2) s += dt_s[derow][r2] * DTW[jj][r2];
        de_s[derow][dec0 + jj] = softp(s);
      }
    }
    __syncthreads();
#pragma unroll
    for (int i2 = 0; i2 < 16; ++i2) {
      float de = de_s[i2][dl];
      float xv = xv_s[i2][dl];
      float4 Bv = *(float4*)&bc_s[i2][nq * 4];
      float4 Cv = *(float4*)&bc_s[i2][16 + nq * 4];
      float db = de * xv;
      float p = 0.f;
#pragma unroll
      for (int j = 0; j < 4; ++j) {
        h[j] = h[j] * __expf(de * A[j]) + db * (&Bv.x)[j];
        p += h[j] * (&Cv.x)[j];
      }
      p += __shfl_down(p, 2, 4);
      p += __shfl_down(p, 1, 4);
      if (nq == 0) yp[(size_t)(lt + i2) * DIv] = p;
    }
  }
}

// K5+K6 fused: merge 4 directions + D*x skip, LayerNorm(DI), * silu(z) -> ygt
__global__ void k_comln(const float* __restrict__ ys, const float* __restrict__ xc,
                        const float* __restrict__ Ds, const float* __restrict__ z,
                        const float* __restrict__ g, const float* __restrict__ be,
                        float* __restrict__ out) {
  int bl = blockIdx.x;            // b*L + l
  int b = bl >> 12, l = bl & 4095;
  int t = threadIdx.x;            // 64
  int lT = ((l & 63) << 6) | (l >> 6);
  size_t base = (size_t)b * KKv * LL * DIv;
  const float* r0 = ys + base + (size_t)l * DIv;
  const float* r2 = ys + base + ((size_t)2 * LL + (LL - 1 - l)) * DIv;
  const float* r1 = ys + base + ((size_t)1 * LL + lT) * DIv;
  const float* r3 = ys + base + ((size_t)3 * LL + (LL - 1 - lT)) * DIv;
  const float* xr = xc + ((size_t)b * LL + l) * DIv;
  float v[3];
  float s = 0.f, q = 0.f;
#pragma unroll
  for (int cc = 0; cc < 3; ++cc) {
    int d = t + cc * 64;
    float sd = Ds[d] + Ds[DIv + d] + Ds[2 * DIv + d] + Ds[3 * DIv + d];
    float vv = r0[d] + r2[d] + r1[d] + r3[d] + sd * xr[d];
    v[cc] = vv; s += vv; q += vv * vv;
  }
#pragma unroll
  for (int o = 32; o > 0; o >>= 1) { s += __shfl_xor(s, o, 64); q += __shfl_xor(q, o, 64); }
  float m = s / DIv;
  float var = q / DIv - m * m;
  float rs = rsqrtf(var + 1e-5f);
  const float* zr = z + (size_t)bl * DIv;
  float* orow = out + (size_t)bl * DIv;
#pragma unroll
  for (int cc = 0; cc < 3; ++cc) {
    int d = t + cc * 64;
    float zz = zr[d];
    float val = (v[cc] - m) * rs * g[d] + be[d];
    orow[d] = val * zz * sigf(zz);
  }
}

// K7+K8 fused GEMM off ygtT: y<48 -> ffn_in (16 cols, silu); y>=48 -> out_proj (4 cols).
__global__ void k_fgemm(const float* __restrict__ ygtT, const float* __restrict__ fiwT,
                        const float* __restrict__ bias, const float* __restrict__ opwT,
                        float* __restrict__ hcl, float* __restrict__ out0) {
  int t = threadIdx.x;                    // 256
  int r2 = blockIdx.x * 256 + t;          // float2-row index
  int y = blockIdx.y;
  const float2* x2 = (const float2*)ygtT;
  if (y < 48) {
    int c0 = y * 16;
    float2 acc[16];
#pragma unroll
    for (int c = 0; c < 16; ++c) acc[c] = make_float2(0.f, 0.f);
#pragma unroll 4
    for (int k = 0; k < DIv; ++k) {
      float2 xv = x2[(size_t)k * (NR / 2) + r2];
      const float* wr = fiwT + k * HIDv + c0;  // wave-uniform
#pragma unroll
      for (int c = 0; c < 16; ++c) {
        float w = wr[c];
        acc[c].x += w * xv.x; acc[c].y += w * xv.y;
      }
    }
#pragma unroll
    for (int li = 0; li < 2; ++li) {
      size_t row = (size_t)r2 * 2 + li;
#pragma unroll
      for (int cc = 0; cc < 4; ++cc) {
        float4 v;
#pragma unroll
        for (int j = 0; j < 4; ++j) {
          float s = (&acc[cc * 4 + j].x)[li] + bias[c0 + cc * 4 + j];
          (&v.x)[j] = s * sigf(s);
        }
        *(float4*)(hcl + row * HIDv + c0 + cc * 4) = v;
      }
    }
  } else {
    int c0 = (y - 48) * 4;
    float2 acc[4];
#pragma unroll
    for (int c = 0; c < 4; ++c) acc[c] = make_float2(0.f, 0.f);
#pragma unroll 4
    for (int k = 0; k < DIv; ++k) {
      float2 xv = x2[(size_t)k * (NR / 2) + r2];
      const float* wr = opwT + k * DMv + c0;  // wave-uniform
#pragma unroll
      for (int c = 0; c < 4; ++c) {
        float w = wr[c];
        acc[c].x += w * xv.x; acc[c].y += w * xv.y;
      }
    }
#pragma unroll
    for (int li = 0; li < 2; ++li) {
      float4 v;
      v.x = (&acc[0].x)[li]; v.y = (&acc[1].x)[li];
      v.z = (&acc[2].x)[li]; v.w = (&acc[3].x)[li];
      *(float4*)(out0 + ((size_t)r2 * 2 + li) * DMv + c0) = v;
    }
  }
}

// K9: fused 5x5 stencil with sliding 5-row register window (6.25 LDS reads/point).
constexpr int TS = 16, CG = 32, TW = TS + 4;  // TW=20
__global__ void k_ffnconv2(const float* __restrict__ hcl, const float* __restrict__ w1,
                           const float* __restrict__ w3, const float* __restrict__ w5,
                           float* __restrict__ hc2) {
  int tile = blockIdx.x;            // 0..15 (4x4 spatial tiles)
  int cg = blockIdx.y, b = blockIdx.z;
  int t = threadIdx.x;              // 256
  int ti0 = (tile >> 2) * TS, tj0 = (tile & 3) * TS;
  __shared__ float sm[TW * TW * CG];

  for (int e = t; e < TW * TW * CG; e += 256) {
    int ec = e & 31;
    int sp = e >> 5;                // 0..399
    int hi = sp / TW, hj = sp % TW;
    int gi = ti0 + hi - 2, gj = tj0 + hj - 2;
    float v = 0.f;
    if ((unsigned)gi < (unsigned)HH && (unsigned)gj < (unsigned)WW)
      v = hcl[((size_t)b * LL + gi * WW + gj) * HIDv + cg * CG + ec];
    sm[e] = v;
  }

  int c = t & 31;
  int cglob = cg * CG + c;
  float wc[25];
#pragma unroll
  for (int di = 0; di < 5; ++di)
#pragma unroll
    for (int dj = 0; dj < 5; ++dj) {
      float w = w5[cglob * 25 + di * 5 + dj];
      if (di >= 1 && di <= 3 && dj >= 1 && dj <= 3)
        w += w3[cglob * 9 + (di - 1) * 3 + (dj - 1)];
      if (di == 2 && dj == 2) w += 1.f + w1[cglob];
      wc[di * 5 + dj] = w;
    }
  __syncthreads();

  int q2 = t >> 5;  // 0..7; thread walks columns q2 and q2+8
#pragma unroll
  for (int half = 0; half < 2; ++half) {
    int q = q2 + half * 8;
    float win[5][5];
#pragma unroll
    for (int di = 0; di < 4; ++di)
#pragma unroll
      for (int dj = 0; dj < 5; ++dj)
        win[di][dj] = sm[(di * TW + (q + dj)) * CG + c];
#pragma unroll
    for (int r = 0; r < 16; ++r) {
      int slot = (r + 4) % 5;
#pragma unroll
      for (int dj = 0; dj < 5; ++dj)
        win[slot][dj] = sm[(((r + 4) * TW) + (q + dj)) * CG + c];
      float s = 0.f;
#pragma unroll
      for (int di = 0; di < 5; ++di) {
        int wsl = (r + di) % 5;
#pragma unroll
        for (int dj = 0; dj < 5; ++dj)
          s += win[wsl][dj] * wc[di * 5 + dj];
      }
      hc2[((size_t)b * LL + (ti0 + r) * WW + (tj0 + q)) * HIDv + cglob] = s;
    }
  }
}

// K10: fused LayerNorm(HID) + transpose: hc2[NR][768] -> hnT[768][NR].
__global__ void k_ln2t(const float* __restrict__ hc2, const float* __restrict__ g,
                       const float* __restrict__ be, float* __restrict__ hnT) {
  int r0 = blockIdx.x * 32;
  int t = threadIdx.x;  // 256
  __shared__ float m_[32], rs_[32];
  __shared__ float tile[32][33];
  {
    int r = t >> 3, q = t & 7;
    const float4* row4 = (const float4*)(hc2 + (size_t)(r0 + r) * HIDv);
    float s = 0.f, qq = 0.f;
#pragma unroll
    for (int j = 0; j < 24; ++j) {
      float4 v = row4[q + j * 8];
      s += v.x + v.y + v.z + v.w;
      qq += v.x * v.x + v.y * v.y + v.z * v.z + v.w * v.w;
    }
    s += __shfl_down(s, 4, 8); qq += __shfl_down(qq, 4, 8);
    s += __shfl_down(s, 2, 8); qq += __shfl_down(qq, 2, 8);
    s += __shfl_down(s, 1, 8); qq += __shfl_down(qq, 1, 8);
    if (q == 0) {
      float m = s / HIDv;
      m_[r] = m;
      rs_[r] = rsqrtf(qq / HIDv - m * m + 1e-5f);
    }
  }
  __syncthreads();
  int tc = t & 31, tr = t >> 5;  // tr 0..7
  for (int ch = 0; ch < 24; ++ch) {
    int c0 = ch * 32;
    float gg = g[c0 + tc], bb = be[c0 + tc];
    __syncthreads();
#pragma unroll
    for (int i = 0; i < 4; ++i) {
      int r = tr + i * 8;
      float v = hc2[(size_t)(r0 + r) * HIDv + c0 + tc];
      tile[tc][r] = (v - m_[r]) * rs_[r] * gg + bb;
    }
    __syncthreads();
#pragma unroll
    for (int i = 0; i < 4; ++i) {
      int cr = tr + i * 8;
      hnT[(size_t)(c0 + cr) * NR + r0 + tc] = tile[cr][tc];
    }
  }
}

// K11a: split-K partial GEMM: part[ks][row][c] = sum_{k in seg} hnT*fowT.
__global__ void k_final3(const float* __restrict__ hnT, const float* __restrict__ fowT,
                         float* __restrict__ part) {
  int t = threadIdx.x;                    // 128
  int rq = blockIdx.x * 128 + t;          // f4-row
  int c0 = blockIdx.y * 8;
  int ks = blockIdx.z;                    // 4 segments of 192
  const float4* x4 = (const float4*)hnT;
  float4 acc[8];
#pragma unroll
  for (int c = 0; c < 8; ++c) acc[c] = make_float4(0.f, 0.f, 0.f, 0.f);
  int k0 = ks * 192;
#pragma unroll 4
  for (int k = k0; k < k0 + 192; ++k) {
    float4 xv = x4[(size_t)k * (NR / 4) + rq];
    const float* wr = fowT + k * DMv + c0;  // wave-uniform
#pragma unroll
    for (int c = 0; c < 8; ++c) {
      float w = wr[c];
      acc[c].x += w * xv.x; acc[c].y += w * xv.y;
      acc[c].z += w * xv.z; acc[c].w += w * xv.w;
    }
  }
  float* pb = part + (size_t)ks * NR * DMv;
#pragma unroll
  for (int li = 0; li < 4; ++li) {
    size_t row = (size_t)rq * 4 + li;
#pragma unroll
    for (int cc = 0; cc < 2; ++cc) {
      float4 v;
#pragma unroll
      for (int j = 0; j < 4; ++j) (&v.x)[j] = (&acc[cc * 4 + j].x)[li];
      *(float4*)(pb + row * DMv + c0 + cc * 4) = v;
    }
  }
}

// K11b: dout = out0 + skip*(sum_k part[k] + bias), float4 elementwise.
__global__ void k_finred(const float* __restrict__ part, const float* __restrict__ out0,
                         const float* __restrict__ bias, const float* __restrict__ skip,
                         float* __restrict__ dout) {
  size_t i = (size_t)blockIdx.x * 256 + threadIdx.x;   // f4 index over NR*DMv/4
  int cq = (int)(i % (DMv / 4));
  const float4* p4 = (const float4*)part;
  size_t npart = (size_t)NR * DMv / 4;
  float4 a = p4[i], b2 = p4[i + npart], c2 = p4[i + 2 * npart], d2 = p4[i + 3 * npart];
  float4 o = ((const float4*)out0)[i];
  float4 bi = ((const float4*)bias)[cq];
  float sk = skip[0];
  float4 r;
  r.x = o.x + sk * (a.x + b2.x + c2.x + d2.x + bi.x);
  r.y = o.y + sk * (a.y + b2.y + c2.y + d2.y + bi.y);
  r.z = o.z + sk * (a.z + b2.z + c2.z + d2.z + bi.z);
  r.w = o.w + sk * (a.w + b2.w + c2.w + d2.w + bi.w);
  ((float4*)dout)[i] = r;
}

extern "C" void kernel_launch(void* const* d_in, const int* in_sizes, int n_in,
                              void* d_out, int out_size, void* d_ws, size_t ws_size,
                              hipStream_t stream) {
  const float* x        = (const float*)d_in[0];
  const float* in_w     = (const float*)d_in[1];
  const float* conv_w   = (const float*)d_in[2];
  const float* conv_b   = (const float*)d_in[3];
  const float* xpw      = (const float*)d_in[4];
  const float* dtw      = (const float*)d_in[5];
  const float* dtb      = (const float*)d_in[6];
  const float* alogs    = (const float*)d_in[7];
  const float* Ds       = (const float*)d_in[8];
  const float* ong      = (const float*)d_in[9];
  const float* onb      = (const float*)d_in[10];
  const float* opw      = (const float*)d_in[11];
  const float* fiw      = (const float*)d_in[12];
  const float* fib      = (const float*)d_in[13];
  const float* dw1      = (const float*)d_in[14];
  const float* dw3      = (const float*)d_in[15];
  const float* dw5      = (const float*)d_in[16];
  const float* flg      = (const float*)d_in[17];
  const float* flb      = (const float*)d_in[18];
  const float* fow      = (const float*)d_in[19];
  const float* fob      = (const float*)d_in[20];
  const float* skip     = (const float*)d_in[21];

  // Workspace layout (aliased; ~150 MB)
  float* ws    = (float*)d_ws;
  float* xi    = ws;                 // -> S/P -> ygtT -> part (with z)
  float* z     = xi + S_xi;
  float* xc    = z + S_xi;           // -> ygt
  float* xdbl  = xc + S_xi;          // -> out0
  float* scr   = xdbl + S_xdbl;      // xt/wt scratch -> hcl -> hnT
  float* ys    = scr + S_big;        // xcT/xcTs scratch -> ys -> hc2
  float* wtiny = ys + S_big;         // persistent small weight transposes
  float* fiwT  = wtiny;              // 192*768 = 147456
  float* opwT  = fiwT + 147456;      // 192*96  = 18432
  float* fowT  = opwT + 18432;       // 768*96  = 73728
  float* wcatT = fowT + 73728;       // 2*192*76 = 29184
  float* wt    = wcatT + 29184;      // 96*384  = 36864

  // Merged weight prep: fiwT/opwT/fowT/wt transposes + wcat (1 dispatch)
  k_wprep<<<384, 256, 0, stream>>>(fiw, opw, fow, in_w, xpw,
                                   fiwT, opwT, fowT, wt, wcatT);

  // In-proj via transposed operands (xt in scr region)
  float* xt = scr;                         // 96*16384 floats
  dim3 gxt(NR / 64, 3);
  k_xt<<<gxt, 256, 0, stream>>>(x, xt);
  dim3 gip(NR / 1024, 48);
  k_inproj<<<gip, 256, 0, stream>>>(xt, wt, xi, z);

  dim3 gdw(16, DIv / 32, BB);        // 16 tiles x 6 ch-groups x 4
  k_dwconv2<<<gdw, 256, 0, stream>>>(xi, conv_w, conv_b, xc);

  // x_dbl GEMM via transposed operands (xcT/xcTs in ys region, free until k_scan3)
  float* xcT  = ys;                  // 192*16384 = 3,145,728
  float* xcTs = ys + S_xi;           // 3,145,728 (6.3M < S_big)
  k_transp<<<dim3(512, 6), 256, 0, stream>>>(xc, xcT, NR, DIv);
  k_spt<<<DIv * BB, 256, 0, stream>>>(xcT, xcTs);
  dim3 gxd(4, 19, 8);                // rq-blocks x col-groups x (p*4+b)
  k_xdbl2<<<gxd, 256, 0, stream>>>(xcT, xcTs, wcatT, xdbl);

  // Chunked scan (delta fused in): S/P alias xi (dead until ygtT lands there)
  float* Sbuf = xi;                  // S_sp floats
  float* Pbuf = xi + S_sp;           // S_sp floats (S_sp*2 == S_xi exactly)
  dim3 gs13(NC * 3, KKv, BB);        // 1536 blocks, 64d x 4nq threads
  dim3 gs2(3, KKv, BB);              // 48 blocks (tiny)
  k_scan1<<<gs13, 256, 0, stream>>>(xdbl, xc, alogs, dtw, dtb, Sbuf, Pbuf);
  k_scan2<<<gs2, 256, 0, stream>>>(Sbuf, Pbuf);  // S <- Hin
  k_scan3<<<gs13, 256, 0, stream>>>(xdbl, xc, alogs, dtw, dtb, Sbuf, ys);

  // Fused combine + LayerNorm + silu-gate -> ygt
  float* ygt = xc;
  k_comln<<<BB * LL, 64, 0, stream>>>(ys, xc, Ds, z, ong, onb, ygt);

  // Transpose ygt (16384x192 -> 192x16384) into xi (S/P dead)
  float* ygtT = xi;
  k_transp<<<dim3(512, 6), 256, 0, stream>>>(ygt, ygtT, NR, DIv);

  // Fused ffn_in + out_proj GEMM off ygtT
  float* out0 = xdbl;
  float* hcl = scr;
  dim3 gfg(NR / 512, 72);            // (32, 72) = 2304 blocks
  k_fgemm<<<gfg, 256, 0, stream>>>(ygtT, fiwT, fib, opwT, hcl, out0);

  float* hc2 = ys;
  dim3 gc(16, HIDv / CG, BB);        // 16 spatial tiles x 24 ch-groups x 4
  k_ffnconv2<<<gc, 256, 0, stream>>>(hcl, dw1, dw3, dw5, hc2);

  // Fused LayerNorm + transpose: hc2 (ys) -> hnT (scr; hcl dead)
  float* hnT = scr;
  k_ln2t<<<NR / 32, 256, 0, stream>>>(hc2, flg, flb, hnT);

  // Split-K final GEMM: partials in xi+z region (ygtT dead after k_fgemm)
  float* part = xi;                  // 4 * NR * 96 = 6,291,456 floats (= 2*S_xi)
  dim3 gfn(NR / 512, DMv / 8, 4);    // (32, 12, 4), block 128
  k_final3<<<gfn, 128, 0, stream>>>(hnT, fowT, part);
  k_finred<<<(NR * DMv / 4) / 256, 256, 0, stream>>>(part, out0, fob, skip, (float*)d_out);
}